// Round 4
// baseline (613.314 us; speedup 1.0000x reference)
//
#include <hip/hip_runtime.h>
#include <cstdint>
#include <cstddef>

#define TPB 256

namespace {

constexpr int B_SZ = 2;
constexpr int C    = 128;
constexpr int HALF = 64;
constexpr int L    = 4096;   // 64*64
constexpr int N    = 16;
constexpr int HH   = 64;
constexpr int WW   = 64;

__device__ __forceinline__ float softplusf(float x) {
  return fmaxf(x, 0.f) + log1pf(expf(-fabsf(x)));
}
__device__ __forceinline__ float sigm(float x) { return 1.f / (1.f + expf(-x)); }

// ---------- per-pixel channel stats (mean, rsqrt(var+eps)) ----------
__global__ void k_pixstats(const float* __restrict__ X, int bsX, int Cn, float eps,
                           float* __restrict__ mean, float* __restrict__ rinv) {
  const int lp = threadIdx.x & 63;
  const int wv = threadIdx.x >> 6;
  const int p  = blockIdx.x * 64 + lp;
  const int b = p / L, l = p % L;
  const int Cq = Cn >> 2;
  const float* Xp = X + (size_t)b * bsX + l;
  float s = 0.f, s2 = 0.f;
#pragma unroll 8
  for (int i = 0; i < Cq; ++i) {
    float v = Xp[(size_t)(wv * Cq + i) * L];
    s += v; s2 += v * v;
  }
  __shared__ float r1[4][64], r2[4][64];
  r1[wv][lp] = s; r2[wv][lp] = s2;
  __syncthreads();
  if (wv == 0) {
    float st  = r1[0][lp] + r1[1][lp] + r1[2][lp] + r1[3][lp];
    float s2t = r2[0][lp] + r2[1][lp] + r2[2][lp] + r2[3][lp];
    float m = st / Cn;
    float var = s2t / Cn - m * m;
    mean[p] = m;
    rinv[p] = rsqrtf(var + eps);
  }
}

// ---------- per-pixel stats over concat([yf, reverse(yb)]) ----------
__global__ void k_pixstats_cat(const float* __restrict__ yf, const float* __restrict__ yb,
                               float* __restrict__ mean, float* __restrict__ rinv) {
  const int lp = threadIdx.x & 63;
  const int wv = threadIdx.x >> 6;
  const int p  = blockIdx.x * 64 + lp;
  const int b = p / L, l = p % L;
  const float* src = (wv < 2) ? (yf + (size_t)b * HALF * L + l)
                              : (yb + (size_t)b * HALF * L + (L - 1 - l));
  const int c0 = (wv & 1) * 32;
  float s = 0.f, s2 = 0.f;
#pragma unroll 8
  for (int i = 0; i < 32; ++i) {
    float v = src[(size_t)(c0 + i) * L];
    s += v; s2 += v * v;
  }
  __shared__ float r1[4][64], r2[4][64];
  r1[wv][lp] = s; r2[wv][lp] = s2;
  __syncthreads();
  if (wv == 0) {
    float st  = r1[0][lp] + r1[1][lp] + r1[2][lp] + r1[3][lp];
    float s2t = r2[0][lp] + r2[1][lp] + r2[2][lp] + r2[3][lp];
    float m = st / C;
    float var = s2t / C - m * m;
    mean[p] = m;
    rinv[p] = rsqrtf(var + 1e-6f);
  }
}

// ---------- inproj: 1x1 conv with on-the-fly LN of input ----------
template <int O_PB>
__global__ void k_conv_ln(const float* __restrict__ X, int bsX,
                          const float* __restrict__ mean, const float* __restrict__ rinv,
                          const float* __restrict__ lnw, const float* __restrict__ lnb,
                          const float* __restrict__ W, const float* __restrict__ bias,
                          float* __restrict__ Y, int I, int O) {
  __shared__ float Wl[O_PB * 128];
  __shared__ float aw[128], ab[128];
  const int o0 = blockIdx.y * O_PB;
  const int b  = blockIdx.z;
  for (int t = threadIdx.x; t < O_PB * I; t += TPB) {
    int i = t / O_PB, k = t % O_PB;
    Wl[t] = W[(size_t)(o0 + k) * I + i];
  }
  for (int t = threadIdx.x; t < I; t += TPB) { aw[t] = lnw[t]; ab[t] = lnb[t]; }
  __syncthreads();
  const int l = blockIdx.x * TPB + threadIdx.x;
  const float m = mean[b * L + l], r = rinv[b * L + l];
  const float* Xb = X + (size_t)b * bsX + l;
  float acc[O_PB];
#pragma unroll
  for (int k = 0; k < O_PB; ++k) acc[k] = bias[o0 + k];
#pragma unroll 4
  for (int i = 0; i < I; ++i) {
    float xv = (Xb[(size_t)i * L] - m) * r * aw[i] + ab[i];
#pragma unroll
    for (int k = 0; k < O_PB; ++k) acc[k] += Wl[i * O_PB + k] * xv;
  }
#pragma unroll
  for (int k = 0; k < O_PB; ++k)
    Y[((size_t)b * O + o0 + k) * L + l] = acc[k];
}

// ---------- batched depthwise 3x3 + SiLU; mode0 applies LN on the fly ----------
__global__ void k_dwconv_b(const float* __restrict__ xp,
                           const float* __restrict__ mean1, const float* __restrict__ rinv1,
                           const float* __restrict__ lnw, const float* __restrict__ lnb,
                           const float* __restrict__ Wm, const float* __restrict__ bm,
                           const float* __restrict__ Wr, const float* __restrict__ br,
                           float* __restrict__ xm, float* __restrict__ xr) {
  const int c = blockIdx.y;
  const int z = blockIdx.z;
  const int b = z & 1, mode = z >> 1;     // mode 0: mamba (LN), 1: res
  const int l = blockIdx.x * TPB + threadIdx.x;
  const int h = l / WW, w = l % WW;
  const float* Xc = xp + ((size_t)b * 2 * C + (mode ? C + c : c)) * L;
  const float* W9 = (mode ? Wr : Wm) + c * 9;
  const float  lw = mode ? 0.f : lnw[c];
  const float  lb = mode ? 0.f : lnb[c];
  float acc = mode ? br[c] : bm[c];
#pragma unroll
  for (int kh = 0; kh < 3; ++kh) {
    int hh = h + kh - 1;
    if (hh < 0 || hh >= HH) continue;
#pragma unroll
    for (int kw = 0; kw < 3; ++kw) {
      int ww2 = w + kw - 1;
      if (ww2 < 0 || ww2 >= WW) continue;
      int li = hh * WW + ww2;
      float v = Xc[li];
      if (mode == 0) v = (v - mean1[b * L + li]) * rinv1[b * L + li] * lw + lb;
      acc += v * W9[kh * 3 + kw];
    }
  }
  float* Y = mode ? xr : xm;
  Y[((size_t)b * C + c) * L + l] = acc * sigm(acc);
}

// ---------- uncertainty per pixel ----------
__global__ void k_unc(const float* __restrict__ xm, float* __restrict__ unc) {
  const int lp = threadIdx.x & 63;
  const int wv = threadIdx.x >> 6;
  const int p  = blockIdx.x * 64 + lp;
  const int b = p / L, l = p % L;
  const float* Xp = xm + (size_t)b * C * L + l;
  float s = 0.f;
#pragma unroll 8
  for (int i = 0; i < 32; ++i) s += Xp[(size_t)(wv * 32 + i) * L];
  __shared__ float r1[4][64];
  r1[wv][lp] = s;
  __syncthreads();
  if (wv == 0) {
    float st = r1[0][lp] + r1[1][lp] + r1[2][lp] + r1[3][lp];
    float sg = sigm(st / C);
    unc[p] = -(sg * logf(sg + 1e-6f));
  }
}

// ---------- stable argsort(-unc): register/shfl bitonic ----------
__global__ void k_sort(const float* __restrict__ unc, int* __restrict__ idx,
                       int* __restrict__ inv) {
  __shared__ unsigned long long S[L];
  const int b = blockIdx.x;
  const int tid = threadIdx.x;          // 0..1023
  const int e0 = tid * 4;

  unsigned long long v[4];
  {
    float4 u4 = ((const float4*)(unc + b * L))[tid];
    float uv[4] = {u4.x, u4.y, u4.z, u4.w};
#pragma unroll
    for (int r = 0; r < 4; ++r) {
      unsigned u = __float_as_uint(uv[r]);
      u = (u & 0x80000000u) ? ~u : (u | 0x80000000u);
      v[r] = ((unsigned long long)(~u) << 32) | (unsigned)(e0 + r);
    }
  }
  for (int k = 2; k <= 256; k <<= 1) {
    for (int j = k >> 1; j > 0; j >>= 1) {
      if (j >= 4) {
        int m = j >> 2;
#pragma unroll
        for (int r = 0; r < 4; ++r) {
          unsigned long long p = __shfl_xor(v[r], m);
          int e = e0 + r;
          bool keepmin = (((e & k) == 0) == ((e & j) == 0));
          v[r] = keepmin ? (v[r] < p ? v[r] : p) : (v[r] > p ? v[r] : p);
        }
      } else {
#pragma unroll
        for (int r = 0; r < 4; ++r) {
          int rp = r ^ j;
          if (rp > r) {
            int e = e0 + r;
            bool up = ((e & k) == 0);
            unsigned long long a = v[r], bb = v[rp];
            if ((a > bb) == up) { v[r] = bb; v[rp] = a; }
          }
        }
      }
    }
  }
#pragma unroll
  for (int r = 0; r < 4; ++r) S[e0 + r] = v[r];
  __syncthreads();

  for (int k = 512; k <= L; k <<= 1) {
    for (int j = k >> 1; j >= 256; j >>= 1) {
      for (int q = tid; q < L / 2; q += 1024) {
        int i = ((q & ~(j - 1)) << 1) | (q & (j - 1));
        int ixj = i | j;
        unsigned long long a = S[i], bb = S[ixj];
        bool up = ((i & k) == 0);
        if ((a > bb) == up) { S[i] = bb; S[ixj] = a; }
      }
      __syncthreads();
    }
#pragma unroll
    for (int r = 0; r < 4; ++r) v[r] = S[e0 + r];
    const bool up = ((e0 & k) == 0);
    for (int j = 128; j >= 4; j >>= 1) {
      int m = j >> 2;
#pragma unroll
      for (int r = 0; r < 4; ++r) {
        unsigned long long p = __shfl_xor(v[r], m);
        int e = e0 + r;
        bool keepmin = (up == ((e & j) == 0));
        v[r] = keepmin ? (v[r] < p ? v[r] : p) : (v[r] > p ? v[r] : p);
      }
    }
#pragma unroll
    for (int j = 2; j > 0; j >>= 1) {
#pragma unroll
      for (int r = 0; r < 4; ++r) {
        int rp = r ^ j;
        if (rp > r) {
          unsigned long long a = v[r], bb = v[rp];
          if ((a > bb) == up) { v[r] = bb; v[rp] = a; }
        }
      }
    }
#pragma unroll
    for (int r = 0; r < 4; ++r) S[e0 + r] = v[r];
    __syncthreads();
  }
  for (int i = tid; i < L; i += 1024) {
    int orig = (int)(S[i] & 0xffffffffu);
    idx[b * L + i] = orig;
    inv[b * L + orig] = i;
  }
}

// ---------- gather / unsort ----------
__global__ void k_gather(const float* __restrict__ xm, const int* __restrict__ idx,
                         float* __restrict__ xs) {
  int t = blockIdx.x * TPB + threadIdx.x;
  int k = t % L, c = (t / L) % C, b = t / (C * L);
  xs[t] = xm[((size_t)b * C + c) * L + idx[b * L + k]];
}

__global__ void k_unsort(const float* __restrict__ yus, const int* __restrict__ inv,
                         float* __restrict__ yu) {
  int t = blockIdx.x * TPB + threadIdx.x;
  int l = t % L, c = (t / L) % C, b = t / (C * L);
  yu[t] = yus[((size_t)b * C + c) * L + inv[b * L + l]];
}

// ---------- x-projection conv for scans; z = dir*B + b; dir1 reads reversed ----------
template <int O_PB>
__global__ void k_convx(const float* __restrict__ U, int ubs, int choffPerDir,
                        const float* __restrict__ W0, const float* __restrict__ b0,
                        const float* __restrict__ W1, const float* __restrict__ b1,
                        float* __restrict__ XD, int I, int O) {
  __shared__ float Wl[O_PB * 128];
  const int z = blockIdx.z;
  const int dir = z >> 1, b = z & 1;
  const float* W = dir ? W1 : W0;
  const float* bi = dir ? b1 : b0;
  const int o0 = blockIdx.y * O_PB;
  for (int t = threadIdx.x; t < O_PB * I; t += TPB) {
    int i = t / O_PB, k = t % O_PB;
    Wl[t] = W[(size_t)(o0 + k) * I + i];
  }
  __syncthreads();
  const int l = blockIdx.x * TPB + threadIdx.x;
  const int ls = dir ? (L - 1 - l) : l;
  const float* Xb = U + (size_t)b * ubs + (size_t)(dir * choffPerDir) * L + ls;
  float acc[O_PB];
#pragma unroll
  for (int k = 0; k < O_PB; ++k) acc[k] = bi[o0 + k];
#pragma unroll 4
  for (int i = 0; i < I; ++i) {
    float xv = Xb[(size_t)i * L];
#pragma unroll
    for (int k = 0; k < O_PB; ++k) acc[k] += Wl[i * O_PB + k] * xv;
  }
  float* yp = XD + ((size_t)z * L + l) * O + o0;
#pragma unroll
  for (int k = 0; k < O_PB; ++k) yp[k] = acc[k];
}

// ---------- dt (scrambled reshape, double bias, softplus) + Bm/Cm transpose ----------
template <int CsT, int RT, int OT>
__global__ void k_dtbc(const float* __restrict__ xdbl,
                       const float* __restrict__ Wdt0, const float* __restrict__ bdt0,
                       const float* __restrict__ Wdt1, const float* __restrict__ bdt1,
                       const float* __restrict__ U, int ubs, int choffPerDir,
                       float* __restrict__ dts, float* __restrict__ dtu,
                       float* __restrict__ BmT, float* __restrict__ CmT) {
  const int z = blockIdx.z;
  const int dir = z >> 1, b = z & 1;
  const float* Wdt = dir ? Wdt1 : Wdt0;
  const float* bdt = dir ? bdt1 : bdt0;
  const int c2 = blockIdx.y;
  const int l2 = blockIdx.x * TPB + threadIdx.x;
  int f = c2 * L + l2;
  int lsrc = f / CsT, csrc = f % CsT;
  const float* xr = xdbl + ((size_t)z * L + lsrc) * OT;
  float acc = bdt[csrc] + bdt[c2];
#pragma unroll
  for (int r = 0; r < RT; ++r) acc += Wdt[csrc * RT + r] * xr[r];
  float d = softplusf(acc);
  int ls = dir ? (L - 1 - l2) : l2;
  float uv = U[(size_t)b * ubs + (size_t)(dir * choffPerDir + c2) * L + ls];
  size_t o = ((size_t)z * CsT + c2) * L + l2;
  dts[o] = d;
  dtu[o] = d * uv;
  if (c2 < N) {     // uniform per block: whole block does bc when c2<16
    int f2 = c2 * L + l2;
    int lb = f2 >> 4, cb = f2 & 15;
    const float* xr2 = xdbl + ((size_t)z * L + lb) * OT + RT + cb;
    size_t ob = ((size_t)z * L + l2) * N + c2;
    BmT[ob] = xr2[0];
    CmT[ob] = xr2[N];
  }
}

// ---------- fused selective scan: one block per (z, c) row ----------
// 256 thr = 16 n x 16 chunks of 256. Phase A chunk-scan, LDS cross-chunk scan,
// phase C replay with y = sum_n h*C + (dtu/dt)*D.
template <int CsT>
__global__ void k_scan(const float* __restrict__ dts, const float* __restrict__ dtu,
                       const float* __restrict__ BmT, const float* __restrict__ CmT,
                       const float* __restrict__ A0, const float* __restrict__ A1,
                       const float* __restrict__ D0, const float* __restrict__ D1,
                       float* __restrict__ Y0, float* __restrict__ Y1) {
  constexpr int SC = L / 16;   // 256
  const int blk = blockIdx.x;
  const int c = blk % CsT;
  const int zb = blk / CsT;
  const int b = zb & 1, dir = zb >> 1;
  const float* Alog = dir ? A1 : A0;
  const float* Dv   = dir ? D1 : D0;
  const int n = threadIdx.x & 15;
  const int k = threadIdx.x >> 4;
  const float a = -expf(Alog[c * N + n]);
  const size_t row = ((size_t)zb * CsT + c) * L;
  const size_t koff = (size_t)k * SC;
  const float4* dp4 = (const float4*)(dts + row + koff);
  const float4* up4 = (const float4*)(dtu + row + koff);
  const float* bp = BmT + ((size_t)zb * L + koff) * N + n;
  const float* cp = CmT + ((size_t)zb * L + koff) * N + n;

  // phase A
  float ap = 1.f, h = 0.f;
#pragma unroll 4
  for (int j = 0; j < SC / 4; ++j) {
    float4 d4 = dp4[j], du4 = up4[j];
    float dv[4] = {d4.x, d4.y, d4.z, d4.w};
    float uv[4] = {du4.x, du4.y, du4.z, du4.w};
#pragma unroll
    for (int jj = 0; jj < 4; ++jj) {
      int s = 4 * j + jj;
      float bn = bp[(size_t)s * N];
      float dA = expf(dv[jj] * a);
      ap *= dA;
      h = h * dA + uv[jj] * bn;
    }
  }
  // phase B: cross-chunk exclusive scan in LDS
  __shared__ float sAp[N][17], sHp[N][17];
  sAp[n][k] = ap; sHp[n][k] = h;
  __syncthreads();
  float hs = 0.f;
  for (int j = 0; j < k; ++j) hs = sAp[n][j] * hs + sHp[n][j];

  // phase C: replay
  h = hs;
  const float Dc = Dv[c];
  float ybuf[16];
#pragma unroll 4
  for (int j = 0; j < SC / 4; ++j) {
    float4 d4 = dp4[j], du4 = up4[j];
    float dv[4] = {d4.x, d4.y, d4.z, d4.w};
    float uv[4] = {du4.x, du4.y, du4.z, du4.w};
#pragma unroll
    for (int jj = 0; jj < 4; ++jj) {
      int s = 4 * j + jj;
      float bn = bp[(size_t)s * N];
      float cn = cp[(size_t)s * N];
      float dA = expf(dv[jj] * a);
      h = h * dA + uv[jj] * bn;
      float p = h * cn;
      p += __shfl_xor(p, 1);
      p += __shfl_xor(p, 2);
      p += __shfl_xor(p, 4);
      p += __shfl_xor(p, 8);
      if ((s & 15) == n) {
        float urec = uv[jj] / fmaxf(dv[jj], 1e-37f);
        ybuf[s >> 4] = p + urec * Dc;
      }
    }
  }
  float* Y = (dir ? Y1 : Y0) + ((size_t)b * CsT + c) * L + koff;
#pragma unroll
  for (int q = 0; q < 16; ++q) Y[16 * q + n] = ybuf[q];
}

// ---------- BN train-mode stats ----------
__global__ void k_bn_stats(const float* __restrict__ X, const float* __restrict__ g,
                           const float* __restrict__ bb, float* __restrict__ scale,
                           float* __restrict__ shift) {
  int c = blockIdx.x;
  float s = 0.f, s2 = 0.f;
  for (int t = threadIdx.x; t < B_SZ * L; t += TPB) {
    int b = t / L, l = t % L;
    float v = X[((size_t)b * C + c) * L + l];
    s += v; s2 += v * v;
  }
  __shared__ float r1[TPB], r2[TPB];
  r1[threadIdx.x] = s; r2[threadIdx.x] = s2;
  __syncthreads();
  for (int off = TPB / 2; off > 0; off >>= 1) {
    if (threadIdx.x < off) {
      r1[threadIdx.x] += r1[threadIdx.x + off];
      r2[threadIdx.x] += r2[threadIdx.x + off];
    }
    __syncthreads();
  }
  if (threadIdx.x == 0) {
    float mean = r1[0] / (B_SZ * L);
    float var  = r2[0] / (B_SZ * L) - mean * mean;
    float sc = g[c] * rsqrtf(var + 1e-5f);
    scale[c] = sc;
    shift[c] = bb[c] - mean * sc;
  }
}

// ---------- gate1: conv over [LN-cat(yf,yb_rev) ; yu] ----------
template <int O_PB>
__global__ void k_gate1(const float* __restrict__ yf, const float* __restrict__ yb,
                        const float* __restrict__ mean2, const float* __restrict__ rinv2,
                        const float* __restrict__ lncw, const float* __restrict__ lncb,
                        const float* __restrict__ yu,
                        const float* __restrict__ W, const float* __restrict__ bias,
                        float* __restrict__ g1) {
  __shared__ float Wl[O_PB * 256];
  __shared__ float cw[128], cb2[128];
  const int o0 = blockIdx.y * O_PB;
  const int b  = blockIdx.z;
  for (int t = threadIdx.x; t < O_PB * 256; t += TPB) {
    int i = t / O_PB, k = t % O_PB;
    Wl[t] = W[(size_t)(o0 + k) * 256 + i];
  }
  for (int t = threadIdx.x; t < 128; t += TPB) { cw[t] = lncw[t]; cb2[t] = lncb[t]; }
  __syncthreads();
  const int l = blockIdx.x * TPB + threadIdx.x;
  const float m = mean2[b * L + l], r = rinv2[b * L + l];
  const float* f0 = yf + (size_t)b * HALF * L + l;
  const float* b0 = yb + (size_t)b * HALF * L + (L - 1 - l);
  const float* u0 = yu + (size_t)b * C * L + l;
  float acc[O_PB];
#pragma unroll
  for (int k = 0; k < O_PB; ++k) acc[k] = bias[o0 + k];
#pragma unroll 4
  for (int i = 0; i < 64; ++i) {
    float cv = (f0[(size_t)i * L] - m) * r * cw[i] + cb2[i];
#pragma unroll
    for (int k = 0; k < O_PB; ++k) acc[k] += Wl[i * O_PB + k] * cv;
  }
#pragma unroll 4
  for (int i = 0; i < 64; ++i) {
    float cv = (b0[(size_t)i * L] - m) * r * cw[64 + i] + cb2[64 + i];
#pragma unroll
    for (int k = 0; k < O_PB; ++k) acc[k] += Wl[(64 + i) * O_PB + k] * cv;
  }
#pragma unroll 4
  for (int i = 0; i < 128; ++i) {
    float xv = u0[(size_t)i * L];
#pragma unroll
    for (int k = 0; k < O_PB; ++k) acc[k] += Wl[(128 + i) * O_PB + k] * xv;
  }
#pragma unroll
  for (int k = 0; k < O_PB; ++k)
    g1[((size_t)b * C + o0 + k) * L + l] = acc[k];
}

// ---------- gate2: conv with BN+relu on input loads; epilogue sigmoid+fuse ----------
template <int O_PB>
__global__ void k_gate2_fuse(const float* __restrict__ g1,
                             const float* __restrict__ scale, const float* __restrict__ shift,
                             const float* __restrict__ W, const float* __restrict__ bias,
                             const float* __restrict__ yu,
                             const float* __restrict__ yf, const float* __restrict__ yb,
                             const float* __restrict__ mean2, const float* __restrict__ rinv2,
                             const float* __restrict__ lncw, const float* __restrict__ lncb,
                             float* __restrict__ fused) {
  __shared__ float Wl[O_PB * 128];
  __shared__ float sc[128], sh[128];
  __shared__ float cwo[O_PB], cbo[O_PB];
  const int o0 = blockIdx.y * O_PB;
  const int b  = blockIdx.z;
  for (int t = threadIdx.x; t < O_PB * 128; t += TPB) {
    int i = t / O_PB, k = t % O_PB;
    Wl[t] = W[(size_t)(o0 + k) * 128 + i];
  }
  for (int t = threadIdx.x; t < 128; t += TPB) { sc[t] = scale[t]; sh[t] = shift[t]; }
  if (threadIdx.x < O_PB) { cwo[threadIdx.x] = lncw[o0 + threadIdx.x]; cbo[threadIdx.x] = lncb[o0 + threadIdx.x]; }
  __syncthreads();
  const int l = blockIdx.x * TPB + threadIdx.x;
  const float m = mean2[b * L + l], r = rinv2[b * L + l];
  const float* Xb = g1 + (size_t)b * C * L + l;
  float acc[O_PB];
#pragma unroll
  for (int k = 0; k < O_PB; ++k) acc[k] = bias[o0 + k];
#pragma unroll 4
  for (int i = 0; i < 128; ++i) {
    float v = fmaxf(Xb[(size_t)i * L] * sc[i] + sh[i], 0.f);
#pragma unroll
    for (int k = 0; k < O_PB; ++k) acc[k] += Wl[i * O_PB + k] * v;
  }
#pragma unroll
  for (int k = 0; k < O_PB; ++k) {
    int o = o0 + k;
    float g = sigm(acc[k]);
    float yuv = yu[((size_t)b * C + o) * L + l];
    float yv = (o < 64) ? yf[((size_t)b * HALF + o) * L + l]
                        : yb[((size_t)b * HALF + (o - 64)) * L + (L - 1 - l)];
    float cv = (yv - m) * r * cwo[k] + cbo[k];
    fused[((size_t)b * C + o) * L + l] = g * yuv + (1.f - g) * cv;
  }
}

// ---------- outproj: 1x1 conv over concat([fused, xr]) ----------
template <int O_PB>
__global__ void k_conv1x1_cat2(const float* __restrict__ X1, const float* __restrict__ X2,
                               const float* __restrict__ W, const float* __restrict__ bias,
                               float* __restrict__ Y, int O) {
  __shared__ float Wl[O_PB * 256];
  const int o0 = blockIdx.y * O_PB;
  const int b  = blockIdx.z;
  for (int t = threadIdx.x; t < O_PB * 256; t += TPB) {
    int i = t / O_PB, k = t % O_PB;
    Wl[t] = W[(size_t)(o0 + k) * 256 + i];
  }
  __syncthreads();
  const int l = blockIdx.x * TPB + threadIdx.x;
  const float* Xb1 = X1 + (size_t)b * C * L + l;
  const float* Xb2 = X2 + (size_t)b * C * L + l;
  float acc[O_PB];
#pragma unroll
  for (int k = 0; k < O_PB; ++k) acc[k] = bias[o0 + k];
#pragma unroll 4
  for (int i = 0; i < 128; ++i) {
    float xv = Xb1[(size_t)i * L];
#pragma unroll
    for (int k = 0; k < O_PB; ++k) acc[k] += Wl[i * O_PB + k] * xv;
  }
#pragma unroll 4
  for (int i = 0; i < 128; ++i) {
    float xv = Xb2[(size_t)i * L];
#pragma unroll
    for (int k = 0; k < O_PB; ++k) acc[k] += Wl[(128 + i) * O_PB + k] * xv;
  }
#pragma unroll
  for (int k = 0; k < O_PB; ++k)
    Y[((size_t)b * O + o0 + k) * L + l] = acc[k];
}

// ---------- final channel LN (two-pass in one kernel) ----------
__global__ void k_ln_cf(const float* __restrict__ X,
                        const float* __restrict__ w, const float* __restrict__ bchan,
                        float* __restrict__ Y) {
  const int lp = threadIdx.x & 63;
  const int wv = threadIdx.x >> 6;
  const int p  = blockIdx.x * 64 + lp;
  const int b = p / L, l = p % L;
  const float* Xp = X + (size_t)b * C * L + l;
  float s = 0.f, s2 = 0.f;
#pragma unroll 8
  for (int i = 0; i < 32; ++i) {
    float v = Xp[(size_t)(wv * 32 + i) * L];
    s += v; s2 += v * v;
  }
  __shared__ float r1[4][64], r2[4][64];
  r1[wv][lp] = s; r2[wv][lp] = s2;
  __syncthreads();
  float st  = r1[0][lp] + r1[1][lp] + r1[2][lp] + r1[3][lp];
  float s2t = r2[0][lp] + r2[1][lp] + r2[2][lp] + r2[3][lp];
  float mean = st / C;
  float rinv = rsqrtf(s2t / C - mean * mean + 1e-6f);
  float* Yp = Y + (size_t)b * C * L + l;
#pragma unroll 8
  for (int i = 0; i < 32; ++i) {
    int c = wv * 32 + i;
    float v = Xp[(size_t)c * L];
    Yp[(size_t)c * L] = w[c] * (v - mean) * rinv + bchan[c];
  }
}

} // namespace

extern "C" void kernel_launch(void* const* d_in, const int* in_sizes, int n_in,
                              void* d_out, int out_size, void* d_ws, size_t ws_size,
                              hipStream_t stream) {
  const float* x         = (const float*)d_in[0];
  const float* ln_in_w   = (const float*)d_in[1];
  const float* ln_in_b   = (const float*)d_in[2];
  const float* inproj_w  = (const float*)d_in[3];
  const float* inproj_b  = (const float*)d_in[4];
  const float* ln_m_w    = (const float*)d_in[5];
  const float* ln_m_b    = (const float*)d_in[6];
  const float* convm_w   = (const float*)d_in[7];
  const float* convm_b   = (const float*)d_in[8];
  const float* convr_w   = (const float*)d_in[9];
  const float* convr_b   = (const float*)d_in[10];
  const float* ln_cat_w  = (const float*)d_in[11];
  const float* ln_cat_b  = (const float*)d_in[12];
  const float* xpf_w     = (const float*)d_in[13];
  const float* xpf_b     = (const float*)d_in[14];
  const float* dtf_w     = (const float*)d_in[15];
  const float* dtf_b     = (const float*)d_in[16];
  const float* Alog_f    = (const float*)d_in[17];
  const float* D_f       = (const float*)d_in[18];
  const float* xpb_w     = (const float*)d_in[19];
  const float* xpb_b     = (const float*)d_in[20];
  const float* dtb_w     = (const float*)d_in[21];
  const float* dtb_b     = (const float*)d_in[22];
  const float* Alog_b    = (const float*)d_in[23];
  const float* D_b       = (const float*)d_in[24];
  const float* xpu_w     = (const float*)d_in[25];
  const float* xpu_b     = (const float*)d_in[26];
  const float* dtu_w     = (const float*)d_in[27];
  const float* dtu_b     = (const float*)d_in[28];
  const float* Alog_u    = (const float*)d_in[29];
  const float* D_u       = (const float*)d_in[30];
  const float* gate1_w   = (const float*)d_in[31];
  const float* gate1_b   = (const float*)d_in[32];
  const float* bn_g      = (const float*)d_in[33];
  const float* bn_b      = (const float*)d_in[34];
  const float* gate2_w   = (const float*)d_in[35];
  const float* gate2_b   = (const float*)d_in[36];
  const float* outproj_w = (const float*)d_in[37];
  const float* outproj_b = (const float*)d_in[38];
  const float* outln_w   = (const float*)d_in[39];
  const float* outln_b   = (const float*)d_in[40];

  float* ws = (float*)d_ws;
  size_t off = 0;
  auto alloc = [&](size_t n) { float* p = ws + off; off += n; return p; };

  const size_t BL = (size_t)B_SZ * L;
  float* st0m  = alloc(BL);
  float* st0r  = alloc(BL);
  float* xp    = alloc((size_t)B_SZ * 2 * C * L);
  float* st1m  = alloc(BL);
  float* st1r  = alloc(BL);
  float* xm    = alloc((size_t)B_SZ * C * L);
  float* xr    = alloc((size_t)B_SZ * C * L);
  float* unc   = alloc(BL);
  int*   idx   = (int*)alloc(BL);
  int*   inv   = (int*)alloc(BL);
  float* xs    = alloc((size_t)B_SZ * C * L);
  float* xdblF = alloc((size_t)4 * L * 36);     // [dir*B+b][l][36]
  float* dtsF  = alloc((size_t)4 * HALF * L);
  float* dtuF  = alloc((size_t)4 * HALF * L);
  float* BmTF  = alloc((size_t)4 * L * N);
  float* CmTF  = alloc((size_t)4 * L * N);
  float* xdblU = alloc((size_t)2 * L * 40);
  float* dtsU  = alloc((size_t)2 * C * L);
  float* dtuU  = alloc((size_t)2 * C * L);
  float* BmTU  = alloc((size_t)2 * L * N);
  float* CmTU  = alloc((size_t)2 * L * N);
  float* yf    = alloc((size_t)B_SZ * HALF * L);
  float* yb    = alloc((size_t)B_SZ * HALF * L);
  float* yus   = alloc((size_t)B_SZ * C * L);
  float* yu    = alloc((size_t)B_SZ * C * L);
  float* st2m  = alloc(BL);
  float* st2r  = alloc(BL);
  float* g1    = alloc((size_t)B_SZ * C * L);
  float* bnsc  = alloc(256);
  float* fused = alloc((size_t)B_SZ * C * L);
  float* outp  = alloc((size_t)B_SZ * C * L);
  (void)ws_size; (void)in_sizes; (void)n_in; (void)out_size;

  const int pixB = B_SZ * L / 64;          // 128 blocks (256 thr, 4 waves/64px)
  const int elemB = B_SZ * C * L / TPB;    // 4096

  // 1) stats of x; 2) inproj with inline LN
  k_pixstats<<<pixB, TPB, 0, stream>>>(x, C * L, C, 1e-6f, st0m, st0r);
  k_conv_ln<16><<<dim3(L / TPB, 16, B_SZ), TPB, 0, stream>>>(
      x, C * L, st0m, st0r, ln_in_w, ln_in_b, inproj_w, inproj_b, xp, 128, 256);
  // 3) stats of xp[:,:128]; 4) batched dwconv (mamba w/ inline LN, res plain)
  k_pixstats<<<pixB, TPB, 0, stream>>>(xp, 2 * C * L, C, 1e-6f, st1m, st1r);
  k_dwconv_b<<<dim3(L / TPB, C, 2 * B_SZ), TPB, 0, stream>>>(
      xp, st1m, st1r, ln_m_w, ln_m_b, convm_w, convm_b, convr_w, convr_b, xm, xr);
  // 5) unc, sort, gather
  k_unc<<<pixB, TPB, 0, stream>>>(xm, unc);
  k_sort<<<B_SZ, 1024, 0, stream>>>(unc, idx, inv);
  k_gather<<<elemB, TPB, 0, stream>>>(xm, idx, xs);

  // ---- f+b scans (batched over z = dir*B+b) ----
  k_convx<4><<<dim3(L / TPB, 9, 4), TPB, 0, stream>>>(
      xm, C * L, HALF, xpf_w, xpf_b, xpb_w, xpb_b, xdblF, HALF, 36);
  k_dtbc<HALF, 4, 36><<<dim3(L / TPB, HALF, 4), TPB, 0, stream>>>(
      xdblF, dtf_w, dtf_b, dtb_w, dtb_b, xm, C * L, HALF, dtsF, dtuF, BmTF, CmTF);
  k_scan<HALF><<<4 * HALF, TPB, 0, stream>>>(
      dtsF, dtuF, BmTF, CmTF, Alog_f, Alog_b, D_f, D_b, yf, yb);

  // ---- u scan ----
  k_convx<4><<<dim3(L / TPB, 10, 2), TPB, 0, stream>>>(
      xs, C * L, 0, xpu_w, xpu_b, xpu_w, xpu_b, xdblU, C, 40);
  k_dtbc<C, 8, 40><<<dim3(L / TPB, C, 2), TPB, 0, stream>>>(
      xdblU, dtu_w, dtu_b, dtu_w, dtu_b, xs, C * L, 0, dtsU, dtuU, BmTU, CmTU);
  k_scan<C><<<2 * C, TPB, 0, stream>>>(
      dtsU, dtuU, BmTU, CmTU, Alog_u, Alog_u, D_u, D_u, yus, yus);

  // ---- epilogue ----
  k_unsort<<<elemB, TPB, 0, stream>>>(yus, inv, yu);
  k_pixstats_cat<<<pixB, TPB, 0, stream>>>(yf, yb, st2m, st2r);
  k_gate1<16><<<dim3(L / TPB, 8, B_SZ), TPB, 0, stream>>>(
      yf, yb, st2m, st2r, ln_cat_w, ln_cat_b, yu, gate1_w, gate1_b, g1);
  k_bn_stats<<<C, TPB, 0, stream>>>(g1, bn_g, bn_b, bnsc, bnsc + 128);
  k_gate2_fuse<16><<<dim3(L / TPB, 8, B_SZ), TPB, 0, stream>>>(
      g1, bnsc, bnsc + 128, gate2_w, gate2_b, yu, yf, yb, st2m, st2r,
      ln_cat_w, ln_cat_b, fused);
  k_conv1x1_cat2<16><<<dim3(L / TPB, 8, B_SZ), TPB, 0, stream>>>(
      fused, xr, outproj_w, outproj_b, outp, 128);
  k_ln_cf<<<pixB, TPB, 0, stream>>>(outp, outln_w, outln_b, (float*)d_out);
}

// Round 5
// 442.743 us; speedup vs baseline: 1.3853x; 1.3853x over previous
//
#include <hip/hip_runtime.h>
#include <cstdint>
#include <cstddef>

#define TPB 256

namespace {

constexpr int B_SZ = 2;
constexpr int C    = 128;
constexpr int HALF = 64;
constexpr int L    = 4096;   // 64*64
constexpr int N    = 16;
constexpr int HH   = 64;
constexpr int WW   = 64;

__device__ __forceinline__ float softplusf(float x) {
  return fmaxf(x, 0.f) + log1pf(expf(-fabsf(x)));
}
__device__ __forceinline__ float sigm(float x) { return 1.f / (1.f + expf(-x)); }

// ---------- per-pixel channel stats (mean, rsqrt(var+eps)) ----------
__global__ void k_pixstats(const float* __restrict__ X, int bsX, int Cn, float eps,
                           float* __restrict__ mean, float* __restrict__ rinv) {
  const int lp = threadIdx.x & 63;
  const int wv = threadIdx.x >> 6;
  const int p  = blockIdx.x * 64 + lp;
  const int b = p / L, l = p % L;
  const int Cq = Cn >> 2;
  const float* Xp = X + (size_t)b * bsX + l;
  float s = 0.f, s2 = 0.f;
#pragma unroll 8
  for (int i = 0; i < Cq; ++i) {
    float v = Xp[(size_t)(wv * Cq + i) * L];
    s += v; s2 += v * v;
  }
  __shared__ float r1[4][64], r2[4][64];
  r1[wv][lp] = s; r2[wv][lp] = s2;
  __syncthreads();
  if (wv == 0) {
    float st  = r1[0][lp] + r1[1][lp] + r1[2][lp] + r1[3][lp];
    float s2t = r2[0][lp] + r2[1][lp] + r2[2][lp] + r2[3][lp];
    float m = st / Cn;
    float var = s2t / Cn - m * m;
    mean[p] = m;
    rinv[p] = rsqrtf(var + eps);
  }
}

// ---------- per-pixel stats over concat([yf, reverse(yb)]) ----------
__global__ void k_pixstats_cat(const float* __restrict__ yf, const float* __restrict__ yb,
                               float* __restrict__ mean, float* __restrict__ rinv) {
  const int lp = threadIdx.x & 63;
  const int wv = threadIdx.x >> 6;
  const int p  = blockIdx.x * 64 + lp;
  const int b = p / L, l = p % L;
  const float* src = (wv < 2) ? (yf + (size_t)b * HALF * L + l)
                              : (yb + (size_t)b * HALF * L + (L - 1 - l));
  const int c0 = (wv & 1) * 32;
  float s = 0.f, s2 = 0.f;
#pragma unroll 8
  for (int i = 0; i < 32; ++i) {
    float v = src[(size_t)(c0 + i) * L];
    s += v; s2 += v * v;
  }
  __shared__ float r1[4][64], r2[4][64];
  r1[wv][lp] = s; r2[wv][lp] = s2;
  __syncthreads();
  if (wv == 0) {
    float st  = r1[0][lp] + r1[1][lp] + r1[2][lp] + r1[3][lp];
    float s2t = r2[0][lp] + r2[1][lp] + r2[2][lp] + r2[3][lp];
    float m = st / C;
    float var = s2t / C - m * m;
    mean[p] = m;
    rinv[p] = rsqrtf(var + 1e-6f);
  }
}

// ---------- inproj: 1x1 conv with on-the-fly LN of input ----------
template <int O_PB>
__global__ void k_conv_ln(const float* __restrict__ X, int bsX,
                          const float* __restrict__ mean, const float* __restrict__ rinv,
                          const float* __restrict__ lnw, const float* __restrict__ lnb,
                          const float* __restrict__ W, const float* __restrict__ bias,
                          float* __restrict__ Y, int I, int O) {
  __shared__ float Wl[O_PB * 128];
  __shared__ float aw[128], ab[128];
  const int o0 = blockIdx.y * O_PB;
  const int b  = blockIdx.z;
  for (int t = threadIdx.x; t < O_PB * I; t += TPB) {
    int i = t / O_PB, k = t % O_PB;
    Wl[t] = W[(size_t)(o0 + k) * I + i];
  }
  for (int t = threadIdx.x; t < I; t += TPB) { aw[t] = lnw[t]; ab[t] = lnb[t]; }
  __syncthreads();
  const int l = blockIdx.x * TPB + threadIdx.x;
  const float m = mean[b * L + l], r = rinv[b * L + l];
  const float* Xb = X + (size_t)b * bsX + l;
  float acc[O_PB];
#pragma unroll
  for (int k = 0; k < O_PB; ++k) acc[k] = bias[o0 + k];
#pragma unroll 4
  for (int i = 0; i < I; ++i) {
    float xv = (Xb[(size_t)i * L] - m) * r * aw[i] + ab[i];
#pragma unroll
    for (int k = 0; k < O_PB; ++k) acc[k] += Wl[i * O_PB + k] * xv;
  }
#pragma unroll
  for (int k = 0; k < O_PB; ++k)
    Y[((size_t)b * O + o0 + k) * L + l] = acc[k];
}

// ---------- batched depthwise 3x3 + SiLU; mode0 applies LN on the fly ----------
__global__ void k_dwconv_b(const float* __restrict__ xp,
                           const float* __restrict__ mean1, const float* __restrict__ rinv1,
                           const float* __restrict__ lnw, const float* __restrict__ lnb,
                           const float* __restrict__ Wm, const float* __restrict__ bm,
                           const float* __restrict__ Wr, const float* __restrict__ br,
                           float* __restrict__ xm, float* __restrict__ xr) {
  const int c = blockIdx.y;
  const int z = blockIdx.z;
  const int b = z & 1, mode = z >> 1;     // mode 0: mamba (LN), 1: res
  const int l = blockIdx.x * TPB + threadIdx.x;
  const int h = l / WW, w = l % WW;
  const float* Xc = xp + ((size_t)b * 2 * C + (mode ? C + c : c)) * L;
  const float* W9 = (mode ? Wr : Wm) + c * 9;
  const float  lw = mode ? 0.f : lnw[c];
  const float  lb = mode ? 0.f : lnb[c];
  float acc = mode ? br[c] : bm[c];
#pragma unroll
  for (int kh = 0; kh < 3; ++kh) {
    int hh = h + kh - 1;
    if (hh < 0 || hh >= HH) continue;
#pragma unroll
    for (int kw = 0; kw < 3; ++kw) {
      int ww2 = w + kw - 1;
      if (ww2 < 0 || ww2 >= WW) continue;
      int li = hh * WW + ww2;
      float v = Xc[li];
      if (mode == 0) v = (v - mean1[b * L + li]) * rinv1[b * L + li] * lw + lb;
      acc += v * W9[kh * 3 + kw];
    }
  }
  float* Y = mode ? xr : xm;
  Y[((size_t)b * C + c) * L + l] = acc * sigm(acc);
}

// ---------- uncertainty per pixel ----------
__global__ void k_unc(const float* __restrict__ xm, float* __restrict__ unc) {
  const int lp = threadIdx.x & 63;
  const int wv = threadIdx.x >> 6;
  const int p  = blockIdx.x * 64 + lp;
  const int b = p / L, l = p % L;
  const float* Xp = xm + (size_t)b * C * L + l;
  float s = 0.f;
#pragma unroll 8
  for (int i = 0; i < 32; ++i) s += Xp[(size_t)(wv * 32 + i) * L];
  __shared__ float r1[4][64];
  r1[wv][lp] = s;
  __syncthreads();
  if (wv == 0) {
    float st = r1[0][lp] + r1[1][lp] + r1[2][lp] + r1[3][lp];
    float sg = sigm(st / C);
    unc[p] = -(sg * logf(sg + 1e-6f));
  }
}

// ---------- stable argsort(-unc): register/shfl bitonic ----------
__global__ void k_sort(const float* __restrict__ unc, int* __restrict__ idx,
                       int* __restrict__ inv) {
  __shared__ unsigned long long S[L];
  const int b = blockIdx.x;
  const int tid = threadIdx.x;          // 0..1023
  const int e0 = tid * 4;

  unsigned long long v[4];
  {
    float4 u4 = ((const float4*)(unc + b * L))[tid];
    float uv[4] = {u4.x, u4.y, u4.z, u4.w};
#pragma unroll
    for (int r = 0; r < 4; ++r) {
      unsigned u = __float_as_uint(uv[r]);
      u = (u & 0x80000000u) ? ~u : (u | 0x80000000u);
      v[r] = ((unsigned long long)(~u) << 32) | (unsigned)(e0 + r);
    }
  }
  for (int k = 2; k <= 256; k <<= 1) {
    for (int j = k >> 1; j > 0; j >>= 1) {
      if (j >= 4) {
        int m = j >> 2;
#pragma unroll
        for (int r = 0; r < 4; ++r) {
          unsigned long long p = __shfl_xor(v[r], m);
          int e = e0 + r;
          bool keepmin = (((e & k) == 0) == ((e & j) == 0));
          v[r] = keepmin ? (v[r] < p ? v[r] : p) : (v[r] > p ? v[r] : p);
        }
      } else {
#pragma unroll
        for (int r = 0; r < 4; ++r) {
          int rp = r ^ j;
          if (rp > r) {
            int e = e0 + r;
            bool up = ((e & k) == 0);
            unsigned long long a = v[r], bb = v[rp];
            if ((a > bb) == up) { v[r] = bb; v[rp] = a; }
          }
        }
      }
    }
  }
#pragma unroll
  for (int r = 0; r < 4; ++r) S[e0 + r] = v[r];
  __syncthreads();

  for (int k = 512; k <= L; k <<= 1) {
    for (int j = k >> 1; j >= 256; j >>= 1) {
      for (int q = tid; q < L / 2; q += 1024) {
        int i = ((q & ~(j - 1)) << 1) | (q & (j - 1));
        int ixj = i | j;
        unsigned long long a = S[i], bb = S[ixj];
        bool up = ((i & k) == 0);
        if ((a > bb) == up) { S[i] = bb; S[ixj] = a; }
      }
      __syncthreads();
    }
#pragma unroll
    for (int r = 0; r < 4; ++r) v[r] = S[e0 + r];
    const bool up = ((e0 & k) == 0);
    for (int j = 128; j >= 4; j >>= 1) {
      int m = j >> 2;
#pragma unroll
      for (int r = 0; r < 4; ++r) {
        unsigned long long p = __shfl_xor(v[r], m);
        int e = e0 + r;
        bool keepmin = (up == ((e & j) == 0));
        v[r] = keepmin ? (v[r] < p ? v[r] : p) : (v[r] > p ? v[r] : p);
      }
    }
#pragma unroll
    for (int j = 2; j > 0; j >>= 1) {
#pragma unroll
      for (int r = 0; r < 4; ++r) {
        int rp = r ^ j;
        if (rp > r) {
          unsigned long long a = v[r], bb = v[rp];
          if ((a > bb) == up) { v[r] = bb; v[rp] = a; }
        }
      }
    }
#pragma unroll
    for (int r = 0; r < 4; ++r) S[e0 + r] = v[r];
    __syncthreads();
  }
  for (int i = tid; i < L; i += 1024) {
    int orig = (int)(S[i] & 0xffffffffu);
    idx[b * L + i] = orig;
    inv[b * L + orig] = i;
  }
}

// ---------- gather / unsort ----------
__global__ void k_gather(const float* __restrict__ xm, const int* __restrict__ idx,
                         float* __restrict__ xs) {
  int t = blockIdx.x * TPB + threadIdx.x;
  int k = t % L, c = (t / L) % C, b = t / (C * L);
  xs[t] = xm[((size_t)b * C + c) * L + idx[b * L + k]];
}

__global__ void k_unsort(const float* __restrict__ yus, const int* __restrict__ inv,
                         float* __restrict__ yu) {
  int t = blockIdx.x * TPB + threadIdx.x;
  int l = t % L, c = (t / L) % C, b = t / (C * L);
  yu[t] = yus[((size_t)b * C + c) * L + inv[b * L + l]];
}

// ---------- x-projection conv for scans; z = dir*B + b; dir1 reads reversed ----------
template <int O_PB>
__global__ void k_convx(const float* __restrict__ U, int ubs, int choffPerDir,
                        const float* __restrict__ W0, const float* __restrict__ b0,
                        const float* __restrict__ W1, const float* __restrict__ b1,
                        float* __restrict__ XD, int I, int O) {
  __shared__ float Wl[O_PB * 128];
  const int z = blockIdx.z;
  const int dir = z >> 1, b = z & 1;
  const float* W = dir ? W1 : W0;
  const float* bi = dir ? b1 : b0;
  const int o0 = blockIdx.y * O_PB;
  for (int t = threadIdx.x; t < O_PB * I; t += TPB) {
    int i = t / O_PB, k = t % O_PB;
    Wl[t] = W[(size_t)(o0 + k) * I + i];
  }
  __syncthreads();
  const int l = blockIdx.x * TPB + threadIdx.x;
  const int ls = dir ? (L - 1 - l) : l;
  const float* Xb = U + (size_t)b * ubs + (size_t)(dir * choffPerDir) * L + ls;
  float acc[O_PB];
#pragma unroll
  for (int k = 0; k < O_PB; ++k) acc[k] = bi[o0 + k];
#pragma unroll 4
  for (int i = 0; i < I; ++i) {
    float xv = Xb[(size_t)i * L];
#pragma unroll
    for (int k = 0; k < O_PB; ++k) acc[k] += Wl[i * O_PB + k] * xv;
  }
  float* yp = XD + ((size_t)z * L + l) * O + o0;
#pragma unroll
  for (int k = 0; k < O_PB; ++k) yp[k] = acc[k];
}

// ---------- dt (scrambled reshape, double bias, softplus) + Bm/Cm transpose ----------
template <int CsT, int RT, int OT>
__global__ void k_dtbc(const float* __restrict__ xdbl,
                       const float* __restrict__ Wdt0, const float* __restrict__ bdt0,
                       const float* __restrict__ Wdt1, const float* __restrict__ bdt1,
                       const float* __restrict__ U, int ubs, int choffPerDir,
                       float* __restrict__ dts, float* __restrict__ dtu,
                       float* __restrict__ BmT, float* __restrict__ CmT) {
  const int z = blockIdx.z;
  const int dir = z >> 1, b = z & 1;
  const float* Wdt = dir ? Wdt1 : Wdt0;
  const float* bdt = dir ? bdt1 : bdt0;
  const int c2 = blockIdx.y;
  const int l2 = blockIdx.x * TPB + threadIdx.x;
  int f = c2 * L + l2;
  int lsrc = f / CsT, csrc = f % CsT;
  const float* xr = xdbl + ((size_t)z * L + lsrc) * OT;
  float acc = bdt[csrc] + bdt[c2];
#pragma unroll
  for (int r = 0; r < RT; ++r) acc += Wdt[csrc * RT + r] * xr[r];
  float d = softplusf(acc);
  int ls = dir ? (L - 1 - l2) : l2;
  float uv = U[(size_t)b * ubs + (size_t)(dir * choffPerDir + c2) * L + ls];
  size_t o = ((size_t)z * CsT + c2) * L + l2;
  dts[o] = d;
  dtu[o] = d * uv;
  if (c2 < N) {     // uniform per block
    int f2 = c2 * L + l2;
    int lb = f2 >> 4, cb = f2 & 15;
    const float* xr2 = xdbl + ((size_t)z * L + lb) * OT + RT + cb;
    size_t ob = ((size_t)z * L + l2) * N + c2;
    BmT[ob] = xr2[0];
    CmT[ob] = xr2[N];
  }
}

// ---------- fused selective scan: 1024 thr/block, one block per (z, c) row ----------
// thread = (n = tid&15, chunk = tid>>4 in [0,64)); 64 steps per chunk.
// Phase A chunk-scan -> LDS -> phase B wave-parallel log-scan over the 64
// chunks (wave w owns n=w) -> phase C replay with y = sum_n h*C + (dtu/dt)*D.
template <int CsT>
__global__ __launch_bounds__(1024) void
k_scan(const float* __restrict__ dts, const float* __restrict__ dtu,
       const float* __restrict__ BmT, const float* __restrict__ CmT,
       const float* __restrict__ A0, const float* __restrict__ A1,
       const float* __restrict__ D0, const float* __restrict__ D1,
       float* __restrict__ Y0, float* __restrict__ Y1) {
  constexpr int CS = 64;    // steps per chunk
  const int blk = blockIdx.x;
  const int c = blk % CsT;
  const int zb = blk / CsT;
  const int b = zb & 1, dir = zb >> 1;
  const float* Alog = dir ? A1 : A0;
  const float* Dv   = dir ? D1 : D0;
  const int n = threadIdx.x & 15;
  const int chunk = threadIdx.x >> 4;   // 0..63
  const float a = -expf(Alog[c * N + n]);
  const size_t row = ((size_t)zb * CsT + c) * L;
  const size_t koff = (size_t)chunk * CS;
  const float4* dp4 = (const float4*)(dts + row + koff);
  const float4* up4 = (const float4*)(dtu + row + koff);
  const float* bp = BmT + ((size_t)zb * L + koff) * N + n;
  const float* cp = CmT + ((size_t)zb * L + koff) * N + n;

  // phase A: 64-step chunk scan
  float ap = 1.f, h = 0.f;
#pragma unroll
  for (int j = 0; j < CS / 4; ++j) {
    float4 d4 = dp4[j], du4 = up4[j];
    float dv[4] = {d4.x, d4.y, d4.z, d4.w};
    float uv[4] = {du4.x, du4.y, du4.z, du4.w};
#pragma unroll
    for (int jj = 0; jj < 4; ++jj) {
      int s = 4 * j + jj;
      float bn = bp[(size_t)s * N];
      float dA = expf(dv[jj] * a);
      ap *= dA;
      h = h * dA + uv[jj] * bn;
    }
  }

  // phase B: cross-chunk exclusive scan; wave w handles n=w, lane k=chunk.
  __shared__ float sA[N][65], sH[N][65];
  sA[n][chunk] = ap; sH[n][chunk] = h;
  __syncthreads();
  {
    const int w = threadIdx.x >> 6;     // 0..15 = n owned by this wave
    const int k = threadIdx.x & 63;     // chunk
    float A = sA[w][k];
    float Bv = sH[w][k];
#pragma unroll
    for (int j = 1; j < 64; j <<= 1) {
      float pa = __shfl_up(A, j);
      float pb = __shfl_up(Bv, j);
      if (k >= j) { Bv = pb * A + Bv; A = pa * A; }
    }
    float hprev = __shfl_up(Bv, 1);
    sH[w][k] = (k == 0) ? 0.f : hprev;  // exclusive scan result
  }
  __syncthreads();
  h = sH[n][chunk];

  // phase C: replay with corrected start state
  const float Dc = Dv[c];
  float ybuf[4];
#pragma unroll
  for (int j = 0; j < CS / 4; ++j) {
    float4 d4 = dp4[j], du4 = up4[j];
    float dv[4] = {d4.x, d4.y, d4.z, d4.w};
    float uv[4] = {du4.x, du4.y, du4.z, du4.w};
#pragma unroll
    for (int jj = 0; jj < 4; ++jj) {
      int s = 4 * j + jj;
      float bn = bp[(size_t)s * N];
      float cn = cp[(size_t)s * N];
      float dA = expf(dv[jj] * a);
      h = h * dA + uv[jj] * bn;
      float p = h * cn;
      p += __shfl_xor(p, 1);
      p += __shfl_xor(p, 2);
      p += __shfl_xor(p, 4);
      p += __shfl_xor(p, 8);
      if ((s & 15) == n) {
        float urec = uv[jj] / fmaxf(dv[jj], 1e-37f);
        ybuf[s >> 4] = p + urec * Dc;
      }
    }
  }
  float* Y = (dir ? Y1 : Y0) + ((size_t)b * CsT + c) * L + koff;
#pragma unroll
  for (int q = 0; q < 4; ++q) Y[16 * q + n] = ybuf[q];
}

// ---------- BN train-mode stats ----------
__global__ void k_bn_stats(const float* __restrict__ X, const float* __restrict__ g,
                           const float* __restrict__ bb, float* __restrict__ scale,
                           float* __restrict__ shift) {
  int c = blockIdx.x;
  float s = 0.f, s2 = 0.f;
  for (int t = threadIdx.x; t < B_SZ * L; t += TPB) {
    int b = t / L, l = t % L;
    float v = X[((size_t)b * C + c) * L + l];
    s += v; s2 += v * v;
  }
  __shared__ float r1[TPB], r2[TPB];
  r1[threadIdx.x] = s; r2[threadIdx.x] = s2;
  __syncthreads();
  for (int off = TPB / 2; off > 0; off >>= 1) {
    if (threadIdx.x < off) {
      r1[threadIdx.x] += r1[threadIdx.x + off];
      r2[threadIdx.x] += r2[threadIdx.x + off];
    }
    __syncthreads();
  }
  if (threadIdx.x == 0) {
    float mean = r1[0] / (B_SZ * L);
    float var  = r2[0] / (B_SZ * L) - mean * mean;
    float sc = g[c] * rsqrtf(var + 1e-5f);
    scale[c] = sc;
    shift[c] = bb[c] - mean * sc;
  }
}

// ---------- gate1: conv over [LN-cat(yf,yb_rev) ; yu] ----------
template <int O_PB>
__global__ void k_gate1(const float* __restrict__ yf, const float* __restrict__ yb,
                        const float* __restrict__ mean2, const float* __restrict__ rinv2,
                        const float* __restrict__ lncw, const float* __restrict__ lncb,
                        const float* __restrict__ yu,
                        const float* __restrict__ W, const float* __restrict__ bias,
                        float* __restrict__ g1) {
  __shared__ float Wl[O_PB * 256];
  __shared__ float cw[128], cb2[128];
  const int o0 = blockIdx.y * O_PB;
  const int b  = blockIdx.z;
  for (int t = threadIdx.x; t < O_PB * 256; t += TPB) {
    int i = t / O_PB, k = t % O_PB;
    Wl[t] = W[(size_t)(o0 + k) * 256 + i];
  }
  for (int t = threadIdx.x; t < 128; t += TPB) { cw[t] = lncw[t]; cb2[t] = lncb[t]; }
  __syncthreads();
  const int l = blockIdx.x * TPB + threadIdx.x;
  const float m = mean2[b * L + l], r = rinv2[b * L + l];
  const float* f0 = yf + (size_t)b * HALF * L + l;
  const float* b0 = yb + (size_t)b * HALF * L + (L - 1 - l);
  const float* u0 = yu + (size_t)b * C * L + l;
  float acc[O_PB];
#pragma unroll
  for (int k = 0; k < O_PB; ++k) acc[k] = bias[o0 + k];
#pragma unroll 4
  for (int i = 0; i < 64; ++i) {
    float cv = (f0[(size_t)i * L] - m) * r * cw[i] + cb2[i];
#pragma unroll
    for (int k = 0; k < O_PB; ++k) acc[k] += Wl[i * O_PB + k] * cv;
  }
#pragma unroll 4
  for (int i = 0; i < 64; ++i) {
    float cv = (b0[(size_t)i * L] - m) * r * cw[64 + i] + cb2[64 + i];
#pragma unroll
    for (int k = 0; k < O_PB; ++k) acc[k] += Wl[(64 + i) * O_PB + k] * cv;
  }
#pragma unroll 4
  for (int i = 0; i < 128; ++i) {
    float xv = u0[(size_t)i * L];
#pragma unroll
    for (int k = 0; k < O_PB; ++k) acc[k] += Wl[(128 + i) * O_PB + k] * xv;
  }
#pragma unroll
  for (int k = 0; k < O_PB; ++k)
    g1[((size_t)b * C + o0 + k) * L + l] = acc[k];
}

// ---------- gate2: conv with BN+relu on input loads; epilogue sigmoid+fuse ----------
template <int O_PB>
__global__ void k_gate2_fuse(const float* __restrict__ g1,
                             const float* __restrict__ scale, const float* __restrict__ shift,
                             const float* __restrict__ W, const float* __restrict__ bias,
                             const float* __restrict__ yu,
                             const float* __restrict__ yf, const float* __restrict__ yb,
                             const float* __restrict__ mean2, const float* __restrict__ rinv2,
                             const float* __restrict__ lncw, const float* __restrict__ lncb,
                             float* __restrict__ fused) {
  __shared__ float Wl[O_PB * 128];
  __shared__ float sc[128], sh[128];
  __shared__ float cwo[O_PB], cbo[O_PB];
  const int o0 = blockIdx.y * O_PB;
  const int b  = blockIdx.z;
  for (int t = threadIdx.x; t < O_PB * 128; t += TPB) {
    int i = t / O_PB, k = t % O_PB;
    Wl[t] = W[(size_t)(o0 + k) * 128 + i];
  }
  for (int t = threadIdx.x; t < 128; t += TPB) { sc[t] = scale[t]; sh[t] = shift[t]; }
  if (threadIdx.x < O_PB) { cwo[threadIdx.x] = lncw[o0 + threadIdx.x]; cbo[threadIdx.x] = lncb[o0 + threadIdx.x]; }
  __syncthreads();
  const int l = blockIdx.x * TPB + threadIdx.x;
  const float m = mean2[b * L + l], r = rinv2[b * L + l];
  const float* Xb = g1 + (size_t)b * C * L + l;
  float acc[O_PB];
#pragma unroll
  for (int k = 0; k < O_PB; ++k) acc[k] = bias[o0 + k];
#pragma unroll 4
  for (int i = 0; i < 128; ++i) {
    float v = fmaxf(Xb[(size_t)i * L] * sc[i] + sh[i], 0.f);
#pragma unroll
    for (int k = 0; k < O_PB; ++k) acc[k] += Wl[i * O_PB + k] * v;
  }
#pragma unroll
  for (int k = 0; k < O_PB; ++k) {
    int o = o0 + k;
    float g = sigm(acc[k]);
    float yuv = yu[((size_t)b * C + o) * L + l];
    float yv = (o < 64) ? yf[((size_t)b * HALF + o) * L + l]
                        : yb[((size_t)b * HALF + (o - 64)) * L + (L - 1 - l)];
    float cv = (yv - m) * r * cwo[k] + cbo[k];
    fused[((size_t)b * C + o) * L + l] = g * yuv + (1.f - g) * cv;
  }
}

// ---------- outproj: 1x1 conv over concat([fused, xr]) ----------
template <int O_PB>
__global__ void k_conv1x1_cat2(const float* __restrict__ X1, const float* __restrict__ X2,
                               const float* __restrict__ W, const float* __restrict__ bias,
                               float* __restrict__ Y, int O) {
  __shared__ float Wl[O_PB * 256];
  const int o0 = blockIdx.y * O_PB;
  const int b  = blockIdx.z;
  for (int t = threadIdx.x; t < O_PB * 256; t += TPB) {
    int i = t / O_PB, k = t % O_PB;
    Wl[t] = W[(size_t)(o0 + k) * 256 + i];
  }
  __syncthreads();
  const int l = blockIdx.x * TPB + threadIdx.x;
  const float* Xb1 = X1 + (size_t)b * C * L + l;
  const float* Xb2 = X2 + (size_t)b * C * L + l;
  float acc[O_PB];
#pragma unroll
  for (int k = 0; k < O_PB; ++k) acc[k] = bias[o0 + k];
#pragma unroll 4
  for (int i = 0; i < 128; ++i) {
    float xv = Xb1[(size_t)i * L];
#pragma unroll
    for (int k = 0; k < O_PB; ++k) acc[k] += Wl[i * O_PB + k] * xv;
  }
#pragma unroll 4
  for (int i = 0; i < 128; ++i) {
    float xv = Xb2[(size_t)i * L];
#pragma unroll
    for (int k = 0; k < O_PB; ++k) acc[k] += Wl[(128 + i) * O_PB + k] * xv;
  }
#pragma unroll
  for (int k = 0; k < O_PB; ++k)
    Y[((size_t)b * O + o0 + k) * L + l] = acc[k];
}

// ---------- final channel LN ----------
__global__ void k_ln_cf(const float* __restrict__ X,
                        const float* __restrict__ w, const float* __restrict__ bchan,
                        float* __restrict__ Y) {
  const int lp = threadIdx.x & 63;
  const int wv = threadIdx.x >> 6;
  const int p  = blockIdx.x * 64 + lp;
  const int b = p / L, l = p % L;
  const float* Xp = X + (size_t)b * C * L + l;
  float s = 0.f, s2 = 0.f;
#pragma unroll 8
  for (int i = 0; i < 32; ++i) {
    float v = Xp[(size_t)(wv * 32 + i) * L];
    s += v; s2 += v * v;
  }
  __shared__ float r1[4][64], r2[4][64];
  r1[wv][lp] = s; r2[wv][lp] = s2;
  __syncthreads();
  float st  = r1[0][lp] + r1[1][lp] + r1[2][lp] + r1[3][lp];
  float s2t = r2[0][lp] + r2[1][lp] + r2[2][lp] + r2[3][lp];
  float mean = st / C;
  float rinv = rsqrtf(s2t / C - mean * mean + 1e-6f);
  float* Yp = Y + (size_t)b * C * L + l;
#pragma unroll 8
  for (int i = 0; i < 32; ++i) {
    int c = wv * 32 + i;
    float v = Xp[(size_t)c * L];
    Yp[(size_t)c * L] = w[c] * (v - mean) * rinv + bchan[c];
  }
}

} // namespace

extern "C" void kernel_launch(void* const* d_in, const int* in_sizes, int n_in,
                              void* d_out, int out_size, void* d_ws, size_t ws_size,
                              hipStream_t stream) {
  const float* x         = (const float*)d_in[0];
  const float* ln_in_w   = (const float*)d_in[1];
  const float* ln_in_b   = (const float*)d_in[2];
  const float* inproj_w  = (const float*)d_in[3];
  const float* inproj_b  = (const float*)d_in[4];
  const float* ln_m_w    = (const float*)d_in[5];
  const float* ln_m_b    = (const float*)d_in[6];
  const float* convm_w   = (const float*)d_in[7];
  const float* convm_b   = (const float*)d_in[8];
  const float* convr_w   = (const float*)d_in[9];
  const float* convr_b   = (const float*)d_in[10];
  const float* ln_cat_w  = (const float*)d_in[11];
  const float* ln_cat_b  = (const float*)d_in[12];
  const float* xpf_w     = (const float*)d_in[13];
  const float* xpf_b     = (const float*)d_in[14];
  const float* dtf_w     = (const float*)d_in[15];
  const float* dtf_b     = (const float*)d_in[16];
  const float* Alog_f    = (const float*)d_in[17];
  const float* D_f       = (const float*)d_in[18];
  const float* xpb_w     = (const float*)d_in[19];
  const float* xpb_b     = (const float*)d_in[20];
  const float* dtb_w     = (const float*)d_in[21];
  const float* dtb_b     = (const float*)d_in[22];
  const float* Alog_b    = (const float*)d_in[23];
  const float* D_b       = (const float*)d_in[24];
  const float* xpu_w     = (const float*)d_in[25];
  const float* xpu_b     = (const float*)d_in[26];
  const float* dtu_w     = (const float*)d_in[27];
  const float* dtu_b     = (const float*)d_in[28];
  const float* Alog_u    = (const float*)d_in[29];
  const float* D_u       = (const float*)d_in[30];
  const float* gate1_w   = (const float*)d_in[31];
  const float* gate1_b   = (const float*)d_in[32];
  const float* bn_g      = (const float*)d_in[33];
  const float* bn_b      = (const float*)d_in[34];
  const float* gate2_w   = (const float*)d_in[35];
  const float* gate2_b   = (const float*)d_in[36];
  const float* outproj_w = (const float*)d_in[37];
  const float* outproj_b = (const float*)d_in[38];
  const float* outln_w   = (const float*)d_in[39];
  const float* outln_b   = (const float*)d_in[40];

  float* ws = (float*)d_ws;
  size_t off = 0;
  auto alloc = [&](size_t n) { float* p = ws + off; off += n; return p; };

  const size_t BL = (size_t)B_SZ * L;
  float* st0m  = alloc(BL);
  float* st0r  = alloc(BL);
  float* xp    = alloc((size_t)B_SZ * 2 * C * L);
  float* st1m  = alloc(BL);
  float* st1r  = alloc(BL);
  float* xm    = alloc((size_t)B_SZ * C * L);
  float* xr    = alloc((size_t)B_SZ * C * L);
  float* unc   = alloc(BL);
  int*   idx   = (int*)alloc(BL);
  int*   inv   = (int*)alloc(BL);
  float* xs    = alloc((size_t)B_SZ * C * L);
  float* xdblF = alloc((size_t)4 * L * 36);     // [dir*B+b][l][36]
  float* dtsF  = alloc((size_t)4 * HALF * L);
  float* dtuF  = alloc((size_t)4 * HALF * L);
  float* BmTF  = alloc((size_t)4 * L * N);
  float* CmTF  = alloc((size_t)4 * L * N);
  float* xdblU = alloc((size_t)2 * L * 40);
  float* dtsU  = alloc((size_t)2 * C * L);
  float* dtuU  = alloc((size_t)2 * C * L);
  float* BmTU  = alloc((size_t)2 * L * N);
  float* CmTU  = alloc((size_t)2 * L * N);
  float* yf    = alloc((size_t)B_SZ * HALF * L);
  float* yb    = alloc((size_t)B_SZ * HALF * L);
  float* yus   = alloc((size_t)B_SZ * C * L);
  float* yu    = alloc((size_t)B_SZ * C * L);
  float* st2m  = alloc(BL);
  float* st2r  = alloc(BL);
  float* g1    = alloc((size_t)B_SZ * C * L);
  float* bnsc  = alloc(256);
  float* fused = alloc((size_t)B_SZ * C * L);
  float* outp  = alloc((size_t)B_SZ * C * L);
  (void)ws_size; (void)in_sizes; (void)n_in; (void)out_size;

  const int pixB = B_SZ * L / 64;          // 128 blocks (256 thr, 4 waves/64px)
  const int elemB = B_SZ * C * L / TPB;    // 4096

  // 1) stats of x; 2) inproj with inline LN
  k_pixstats<<<pixB, TPB, 0, stream>>>(x, C * L, C, 1e-6f, st0m, st0r);
  k_conv_ln<16><<<dim3(L / TPB, 16, B_SZ), TPB, 0, stream>>>(
      x, C * L, st0m, st0r, ln_in_w, ln_in_b, inproj_w, inproj_b, xp, 128, 256);
  // 3) stats of xp[:,:128]; 4) batched dwconv (mamba w/ inline LN, res plain)
  k_pixstats<<<pixB, TPB, 0, stream>>>(xp, 2 * C * L, C, 1e-6f, st1m, st1r);
  k_dwconv_b<<<dim3(L / TPB, C, 2 * B_SZ), TPB, 0, stream>>>(
      xp, st1m, st1r, ln_m_w, ln_m_b, convm_w, convm_b, convr_w, convr_b, xm, xr);
  // 5) unc, sort, gather
  k_unc<<<pixB, TPB, 0, stream>>>(xm, unc);
  k_sort<<<B_SZ, 1024, 0, stream>>>(unc, idx, inv);
  k_gather<<<elemB, TPB, 0, stream>>>(xm, idx, xs);

  // ---- f+b scans (batched over z = dir*B+b) ----
  k_convx<4><<<dim3(L / TPB, 9, 4), TPB, 0, stream>>>(
      xm, C * L, HALF, xpf_w, xpf_b, xpb_w, xpb_b, xdblF, HALF, 36);
  k_dtbc<HALF, 4, 36><<<dim3(L / TPB, HALF, 4), TPB, 0, stream>>>(
      xdblF, dtf_w, dtf_b, dtb_w, dtb_b, xm, C * L, HALF, dtsF, dtuF, BmTF, CmTF);
  k_scan<HALF><<<4 * HALF, 1024, 0, stream>>>(
      dtsF, dtuF, BmTF, CmTF, Alog_f, Alog_b, D_f, D_b, yf, yb);

  // ---- u scan ----
  k_convx<4><<<dim3(L / TPB, 10, 2), TPB, 0, stream>>>(
      xs, C * L, 0, xpu_w, xpu_b, xpu_w, xpu_b, xdblU, C, 40);
  k_dtbc<C, 8, 40><<<dim3(L / TPB, C, 2), TPB, 0, stream>>>(
      xdblU, dtu_w, dtu_b, dtu_w, dtu_b, xs, C * L, 0, dtsU, dtuU, BmTU, CmTU);
  k_scan<C><<<2 * C, 1024, 0, stream>>>(
      dtsU, dtuU, BmTU, CmTU, Alog_u, Alog_u, D_u, D_u, yus, yus);

  // ---- epilogue ----
  k_unsort<<<elemB, TPB, 0, stream>>>(yus, inv, yu);
  k_pixstats_cat<<<pixB, TPB, 0, stream>>>(yf, yb, st2m, st2r);
  k_gate1<16><<<dim3(L / TPB, 8, B_SZ), TPB, 0, stream>>>(
      yf, yb, st2m, st2r, ln_cat_w, ln_cat_b, yu, gate1_w, gate1_b, g1);
  k_bn_stats<<<C, TPB, 0, stream>>>(g1, bn_g, bn_b, bnsc, bnsc + 128);
  k_gate2_fuse<16><<<dim3(L / TPB, 8, B_SZ), TPB, 0, stream>>>(
      g1, bnsc, bnsc + 128, gate2_w, gate2_b, yu, yf, yb, st2m, st2r,
      ln_cat_w, ln_cat_b, fused);
  k_conv1x1_cat2<16><<<dim3(L / TPB, 8, B_SZ), TPB, 0, stream>>>(
      fused, xr, outproj_w, outproj_b, outp, 128);
  k_ln_cf<<<pixB, TPB, 0, stream>>>(outp, outln_w, outln_b, (float*)d_out);
}

// Round 6
// 436.633 us; speedup vs baseline: 1.4046x; 1.0140x over previous
//
#include <hip/hip_runtime.h>
#include <cstdint>
#include <cstddef>

#define TPB 256

namespace {

constexpr int B_SZ = 2;
constexpr int C    = 128;
constexpr int HALF = 64;
constexpr int L    = 4096;   // 64*64
constexpr int N    = 16;
constexpr int HH   = 64;
constexpr int WW   = 64;

__device__ __forceinline__ float softplusf(float x) {
  return fmaxf(x, 0.f) + log1pf(expf(-fabsf(x)));
}
__device__ __forceinline__ float sigm(float x) { return 1.f / (1.f + expf(-x)); }

// ---------- per-pixel channel stats (mean, rsqrt(var+eps)) ----------
__global__ void k_pixstats(const float* __restrict__ X, int bsX, int Cn, float eps,
                           float* __restrict__ mean, float* __restrict__ rinv) {
  const int lp = threadIdx.x & 63;
  const int wv = threadIdx.x >> 6;
  const int p  = blockIdx.x * 64 + lp;
  const int b = p / L, l = p % L;
  const int Cq = Cn >> 2;
  const float* Xp = X + (size_t)b * bsX + l;
  float s = 0.f, s2 = 0.f;
#pragma unroll 8
  for (int i = 0; i < Cq; ++i) {
    float v = Xp[(size_t)(wv * Cq + i) * L];
    s += v; s2 += v * v;
  }
  __shared__ float r1[4][64], r2[4][64];
  r1[wv][lp] = s; r2[wv][lp] = s2;
  __syncthreads();
  if (wv == 0) {
    float st  = r1[0][lp] + r1[1][lp] + r1[2][lp] + r1[3][lp];
    float s2t = r2[0][lp] + r2[1][lp] + r2[2][lp] + r2[3][lp];
    float m = st / Cn;
    float var = s2t / Cn - m * m;
    mean[p] = m;
    rinv[p] = rsqrtf(var + eps);
  }
}

// ---------- per-pixel stats over concat([yf, reverse(yb)]) ----------
__global__ void k_pixstats_cat(const float* __restrict__ yf, const float* __restrict__ yb,
                               float* __restrict__ mean, float* __restrict__ rinv) {
  const int lp = threadIdx.x & 63;
  const int wv = threadIdx.x >> 6;
  const int p  = blockIdx.x * 64 + lp;
  const int b = p / L, l = p % L;
  const float* src = (wv < 2) ? (yf + (size_t)b * HALF * L + l)
                              : (yb + (size_t)b * HALF * L + (L - 1 - l));
  const int c0 = (wv & 1) * 32;
  float s = 0.f, s2 = 0.f;
#pragma unroll 8
  for (int i = 0; i < 32; ++i) {
    float v = src[(size_t)(c0 + i) * L];
    s += v; s2 += v * v;
  }
  __shared__ float r1[4][64], r2[4][64];
  r1[wv][lp] = s; r2[wv][lp] = s2;
  __syncthreads();
  if (wv == 0) {
    float st  = r1[0][lp] + r1[1][lp] + r1[2][lp] + r1[3][lp];
    float s2t = r2[0][lp] + r2[1][lp] + r2[2][lp] + r2[3][lp];
    float m = st / C;
    float var = s2t / C - m * m;
    mean[p] = m;
    rinv[p] = rsqrtf(var + 1e-6f);
  }
}

// ---------- inproj: 1x1 conv with INLINE per-pixel LN (stats computed here) ----------
// 2 pixels per thread; grid (L/(2*TPB), O/O_PB, B)
template <int O_PB>
__global__ void k_conv_ln(const float* __restrict__ X, int bsX,
                          const float* __restrict__ lnw, const float* __restrict__ lnb,
                          const float* __restrict__ W, const float* __restrict__ bias,
                          float* __restrict__ Y, int I, int O) {
  __shared__ float Wl[O_PB * 128];
  __shared__ float aw[128], ab[128];
  const int o0 = blockIdx.y * O_PB;
  const int b  = blockIdx.z;
  for (int t = threadIdx.x; t < O_PB * I; t += TPB) {
    int i = t / O_PB, k = t % O_PB;
    Wl[t] = W[(size_t)(o0 + k) * I + i];
  }
  for (int t = threadIdx.x; t < I; t += TPB) { aw[t] = lnw[t]; ab[t] = lnb[t]; }
  __syncthreads();
  const int l0 = blockIdx.x * (2 * TPB) + threadIdx.x;
  const int l1 = l0 + TPB;
  const float* X0 = X + (size_t)b * bsX + l0;
  const float* X1 = X + (size_t)b * bsX + l1;
  // inline LN stats (data L1-warms for the conv pass)
  float s0 = 0.f, q0 = 0.f, s1 = 0.f, q1 = 0.f;
#pragma unroll 8
  for (int i = 0; i < I; ++i) {
    float v0 = X0[(size_t)i * L], v1 = X1[(size_t)i * L];
    s0 += v0; q0 += v0 * v0; s1 += v1; q1 += v1 * v1;
  }
  const float m0 = s0 / I, m1 = s1 / I;
  const float r0 = rsqrtf(q0 / I - m0 * m0 + 1e-6f);
  const float r1 = rsqrtf(q1 / I - m1 * m1 + 1e-6f);
  float acc0[O_PB], acc1[O_PB];
#pragma unroll
  for (int k = 0; k < O_PB; ++k) { acc0[k] = bias[o0 + k]; acc1[k] = acc0[k]; }
#pragma unroll 4
  for (int i = 0; i < I; ++i) {
    float xv0 = (X0[(size_t)i * L] - m0) * r0 * aw[i] + ab[i];
    float xv1 = (X1[(size_t)i * L] - m1) * r1 * aw[i] + ab[i];
#pragma unroll
    for (int k = 0; k < O_PB; ++k) {
      acc0[k] += Wl[i * O_PB + k] * xv0;
      acc1[k] += Wl[i * O_PB + k] * xv1;
    }
  }
#pragma unroll
  for (int k = 0; k < O_PB; ++k) {
    Y[((size_t)b * O + o0 + k) * L + l0] = acc0[k];
    Y[((size_t)b * O + o0 + k) * L + l1] = acc1[k];
  }
}

// ---------- batched depthwise 3x3 + SiLU; mode0 applies LN on the fly ----------
__global__ void k_dwconv_b(const float* __restrict__ xp,
                           const float* __restrict__ mean1, const float* __restrict__ rinv1,
                           const float* __restrict__ lnw, const float* __restrict__ lnb,
                           const float* __restrict__ Wm, const float* __restrict__ bm,
                           const float* __restrict__ Wr, const float* __restrict__ br,
                           float* __restrict__ xm, float* __restrict__ xr) {
  const int c = blockIdx.y;
  const int z = blockIdx.z;
  const int b = z & 1, mode = z >> 1;     // mode 0: mamba (LN), 1: res
  const int l = blockIdx.x * TPB + threadIdx.x;
  const int h = l / WW, w = l % WW;
  const float* Xc = xp + ((size_t)b * 2 * C + (mode ? C + c : c)) * L;
  const float* W9 = (mode ? Wr : Wm) + c * 9;
  const float  lw = mode ? 0.f : lnw[c];
  const float  lb = mode ? 0.f : lnb[c];
  float acc = mode ? br[c] : bm[c];
#pragma unroll
  for (int kh = 0; kh < 3; ++kh) {
    int hh = h + kh - 1;
    if (hh < 0 || hh >= HH) continue;
#pragma unroll
    for (int kw = 0; kw < 3; ++kw) {
      int ww2 = w + kw - 1;
      if (ww2 < 0 || ww2 >= WW) continue;
      int li = hh * WW + ww2;
      float v = Xc[li];
      if (mode == 0) v = (v - mean1[b * L + li]) * rinv1[b * L + li] * lw + lb;
      acc += v * W9[kh * 3 + kw];
    }
  }
  float* Y = mode ? xr : xm;
  Y[((size_t)b * C + c) * L + l] = acc * sigm(acc);
}

// ---------- uncertainty per pixel ----------
__global__ void k_unc(const float* __restrict__ xm, float* __restrict__ unc) {
  const int lp = threadIdx.x & 63;
  const int wv = threadIdx.x >> 6;
  const int p  = blockIdx.x * 64 + lp;
  const int b = p / L, l = p % L;
  const float* Xp = xm + (size_t)b * C * L + l;
  float s = 0.f;
#pragma unroll 8
  for (int i = 0; i < 32; ++i) s += Xp[(size_t)(wv * 32 + i) * L];
  __shared__ float r1[4][64];
  r1[wv][lp] = s;
  __syncthreads();
  if (wv == 0) {
    float st = r1[0][lp] + r1[1][lp] + r1[2][lp] + r1[3][lp];
    float sg = sigm(st / C);
    unc[p] = -(sg * logf(sg + 1e-6f));
  }
}

// ---------- stable argsort(-unc): register/shfl bitonic ----------
__global__ void k_sort(const float* __restrict__ unc, int* __restrict__ idx,
                       int* __restrict__ inv) {
  __shared__ unsigned long long S[L];
  const int b = blockIdx.x;
  const int tid = threadIdx.x;          // 0..1023
  const int e0 = tid * 4;

  unsigned long long v[4];
  {
    float4 u4 = ((const float4*)(unc + b * L))[tid];
    float uv[4] = {u4.x, u4.y, u4.z, u4.w};
#pragma unroll
    for (int r = 0; r < 4; ++r) {
      unsigned u = __float_as_uint(uv[r]);
      u = (u & 0x80000000u) ? ~u : (u | 0x80000000u);
      v[r] = ((unsigned long long)(~u) << 32) | (unsigned)(e0 + r);
    }
  }
  for (int k = 2; k <= 256; k <<= 1) {
    for (int j = k >> 1; j > 0; j >>= 1) {
      if (j >= 4) {
        int m = j >> 2;
#pragma unroll
        for (int r = 0; r < 4; ++r) {
          unsigned long long p = __shfl_xor(v[r], m);
          int e = e0 + r;
          bool keepmin = (((e & k) == 0) == ((e & j) == 0));
          v[r] = keepmin ? (v[r] < p ? v[r] : p) : (v[r] > p ? v[r] : p);
        }
      } else {
#pragma unroll
        for (int r = 0; r < 4; ++r) {
          int rp = r ^ j;
          if (rp > r) {
            int e = e0 + r;
            bool up = ((e & k) == 0);
            unsigned long long a = v[r], bb = v[rp];
            if ((a > bb) == up) { v[r] = bb; v[rp] = a; }
          }
        }
      }
    }
  }
#pragma unroll
  for (int r = 0; r < 4; ++r) S[e0 + r] = v[r];
  __syncthreads();

  for (int k = 512; k <= L; k <<= 1) {
    for (int j = k >> 1; j >= 256; j >>= 1) {
      for (int q = tid; q < L / 2; q += 1024) {
        int i = ((q & ~(j - 1)) << 1) | (q & (j - 1));
        int ixj = i | j;
        unsigned long long a = S[i], bb = S[ixj];
        bool up = ((i & k) == 0);
        if ((a > bb) == up) { S[i] = bb; S[ixj] = a; }
      }
      __syncthreads();
    }
#pragma unroll
    for (int r = 0; r < 4; ++r) v[r] = S[e0 + r];
    const bool up = ((e0 & k) == 0);
    for (int j = 128; j >= 4; j >>= 1) {
      int m = j >> 2;
#pragma unroll
      for (int r = 0; r < 4; ++r) {
        unsigned long long p = __shfl_xor(v[r], m);
        int e = e0 + r;
        bool keepmin = (up == ((e & j) == 0));
        v[r] = keepmin ? (v[r] < p ? v[r] : p) : (v[r] > p ? v[r] : p);
      }
    }
#pragma unroll
    for (int j = 2; j > 0; j >>= 1) {
#pragma unroll
      for (int r = 0; r < 4; ++r) {
        int rp = r ^ j;
        if (rp > r) {
          unsigned long long a = v[r], bb = v[rp];
          if ((a > bb) == up) { v[r] = bb; v[rp] = a; }
        }
      }
    }
#pragma unroll
    for (int r = 0; r < 4; ++r) S[e0 + r] = v[r];
    __syncthreads();
  }
  for (int i = tid; i < L; i += 1024) {
    int orig = (int)(S[i] & 0xffffffffu);
    idx[b * L + i] = orig;
    inv[b * L + orig] = i;
  }
}

// ---------- gather / unsort ----------
__global__ void k_gather(const float* __restrict__ xm, const int* __restrict__ idx,
                         float* __restrict__ xs) {
  int t = blockIdx.x * TPB + threadIdx.x;
  int k = t % L, c = (t / L) % C, b = t / (C * L);
  xs[t] = xm[((size_t)b * C + c) * L + idx[b * L + k]];
}

__global__ void k_unsort(const float* __restrict__ yus, const int* __restrict__ inv,
                         float* __restrict__ yu) {
  int t = blockIdx.x * TPB + threadIdx.x;
  int l = t % L, c = (t / L) % C, b = t / (C * L);
  yu[t] = yus[((size_t)b * C + c) * L + inv[b * L + l]];
}

// ---------- x-projection conv for scans; z = dir*B + b; dir1 reads reversed ----------
template <int O_PB, int MPT>
__global__ void k_convx(const float* __restrict__ U, int ubs, int choffPerDir,
                        const float* __restrict__ W0, const float* __restrict__ b0v,
                        const float* __restrict__ W1, const float* __restrict__ b1v,
                        float* __restrict__ XD, int I, int O) {
  __shared__ float Wl[O_PB * 128];
  const int z = blockIdx.z;
  const int dir = z >> 1, b = z & 1;
  const float* W = dir ? W1 : W0;
  const float* bi = dir ? b1v : b0v;
  const int o0 = blockIdx.y * O_PB;
  for (int t = threadIdx.x; t < O_PB * I; t += TPB) {
    int i = t / O_PB, k = t % O_PB;
    Wl[t] = W[(size_t)(o0 + k) * I + i];
  }
  __syncthreads();
  int l[MPT], ls[MPT];
#pragma unroll
  for (int m = 0; m < MPT; ++m) {
    l[m] = blockIdx.x * (MPT * TPB) + m * TPB + threadIdx.x;
    ls[m] = dir ? (L - 1 - l[m]) : l[m];
  }
  const float* Xb = U + (size_t)b * ubs + (size_t)(dir * choffPerDir) * L;
  float acc[MPT][O_PB];
#pragma unroll
  for (int m = 0; m < MPT; ++m)
#pragma unroll
    for (int k = 0; k < O_PB; ++k) acc[m][k] = bi[o0 + k];
#pragma unroll 4
  for (int i = 0; i < I; ++i) {
    float xv[MPT];
#pragma unroll
    for (int m = 0; m < MPT; ++m) xv[m] = Xb[(size_t)i * L + ls[m]];
#pragma unroll
    for (int k = 0; k < O_PB; ++k) {
      float wv = Wl[i * O_PB + k];
#pragma unroll
      for (int m = 0; m < MPT; ++m) acc[m][k] += wv * xv[m];
    }
  }
#pragma unroll
  for (int m = 0; m < MPT; ++m) {
    float* yp = XD + ((size_t)z * L + l[m]) * O + o0;
#pragma unroll
    for (int k = 0; k < O_PB; ++k) yp[k] = acc[m][k];
  }
}

// ---------- B/C scrambled transpose: xdbl -> (z, l, n) layout ----------
template <int RT, int OT>
__global__ void k_bc(const float* __restrict__ xdbl,
                     float* __restrict__ BmT, float* __restrict__ CmT) {
  const int z = blockIdx.z;
  const int n = blockIdx.y;
  const int l2 = blockIdx.x * TPB + threadIdx.x;
  int f2 = n * L + l2;
  int lb = f2 >> 4, cb = f2 & 15;
  const float* xr2 = xdbl + ((size_t)z * L + lb) * OT + RT + cb;
  size_t ob = ((size_t)z * L + l2) * N + n;
  BmT[ob] = xr2[0];
  CmT[ob] = xr2[N];
}

// ---------- fused selective scan with INLINE dt/u generation ----------
// 1024 thr/block, one block per (z, c) row. Stage 1 computes dt (softplus of
// the scrambled projection) and u straight into LDS; phases A/B/C as before.
template <int CsT, int RT, int OT>
__global__ __launch_bounds__(1024) void
k_scan(const float* __restrict__ xdbl,
       const float* __restrict__ Wdt0, const float* __restrict__ bdt0,
       const float* __restrict__ Wdt1, const float* __restrict__ bdt1,
       const float* __restrict__ U, int ubs, int choff,
       const float* __restrict__ BmT, const float* __restrict__ CmT,
       const float* __restrict__ A0, const float* __restrict__ A1,
       const float* __restrict__ D0, const float* __restrict__ D1,
       float* __restrict__ Y0, float* __restrict__ Y1) {
  const int blk = blockIdx.x;
  const int c = blk % CsT;
  const int zb = blk / CsT;
  const int b = zb & 1, dir = zb >> 1;
  const float* Wdt = dir ? Wdt1 : Wdt0;
  const float* bdt = dir ? bdt1 : bdt0;
  const float* Alog = dir ? A1 : A0;
  const float* Dv   = dir ? D1 : D0;
  const int tid = threadIdx.x;

  __shared__ float sW[CsT * RT];
  __shared__ float sb[CsT];
  __shared__ float dtL[64][65];
  __shared__ float uL[64][65];
  __shared__ float sA[N][65], sH[N][65];

  for (int t = tid; t < CsT * RT; t += 1024) sW[t] = Wdt[t];
  for (int t = tid; t < CsT; t += 1024) sb[t] = bdt[t];
  __syncthreads();

  // ---- stage 1: dt + u into LDS. thread covers (chunk_d, 4 s-values) ----
  {
    const int chunk_d = tid >> 4;
    const int sq = (tid & 15) * 4;
    const int lsrc = c * (L / CsT) + (chunk_d * 64) / CsT;
    const float* xrp = xdbl + ((size_t)zb * L + lsrc) * OT;
    float xr[RT];
#pragma unroll
    for (int r = 0; r < RT; ++r) xr[r] = xrp[r];
    const float bcc = sb[c];
    const float* Ub = U + (size_t)b * ubs + (size_t)(dir * choff + c) * L;
#pragma unroll
    for (int j = 0; j < 4; ++j) {
      int s = sq + j;
      int csrc = ((chunk_d & (CsT / 64 - 1)) << 6) + s;
      float acc = sb[csrc] + bcc;
#pragma unroll
      for (int r = 0; r < RT; ++r) acc += sW[csrc * RT + r] * xr[r];
      int l = (chunk_d << 6) + s;
      int lsu = dir ? (L - 1 - l) : l;
      dtL[chunk_d][s] = softplusf(acc);
      uL[chunk_d][s] = Ub[lsu];
    }
  }
  __syncthreads();

  const int n = tid & 15;
  const int chunk = tid >> 4;   // 0..63
  const float a = -expf(Alog[c * N + n]);
  const float* bp = BmT + ((size_t)zb * L + (chunk << 6)) * N + n;
  const float* cp = CmT + ((size_t)zb * L + (chunk << 6)) * N + n;

  // phase A: 64-step chunk scan
  float ap = 1.f, h = 0.f;
#pragma unroll 4
  for (int s = 0; s < 64; ++s) {
    float d = dtL[chunk][s];
    float uv = uL[chunk][s];
    float bn = bp[(size_t)s * N];
    float dA = expf(d * a);
    ap *= dA;
    h = h * dA + d * uv * bn;
  }
  sA[n][chunk] = ap; sH[n][chunk] = h;
  __syncthreads();
  // phase B: cross-chunk exclusive scan; wave w owns n=w, lane k = chunk
  {
    const int w = tid >> 6;
    const int k = tid & 63;
    float A = sA[w][k];
    float Bv = sH[w][k];
#pragma unroll
    for (int j = 1; j < 64; j <<= 1) {
      float pa = __shfl_up(A, j);
      float pb = __shfl_up(Bv, j);
      if (k >= j) { Bv = pb * A + Bv; A = pa * A; }
    }
    float hprev = __shfl_up(Bv, 1);
    sH[w][k] = (k == 0) ? 0.f : hprev;
  }
  __syncthreads();
  h = sH[n][chunk];

  // phase C: replay; y = sum_n h*C + u*D
  const float Dc = Dv[c];
  float ybuf[4];
#pragma unroll 4
  for (int s = 0; s < 64; ++s) {
    float d = dtL[chunk][s];
    float uv = uL[chunk][s];
    float bn = bp[(size_t)s * N];
    float cn = cp[(size_t)s * N];
    float dA = expf(d * a);
    h = h * dA + d * uv * bn;
    float p = h * cn;
    p += __shfl_xor(p, 1);
    p += __shfl_xor(p, 2);
    p += __shfl_xor(p, 4);
    p += __shfl_xor(p, 8);
    if ((s & 15) == n) ybuf[s >> 4] = p + uv * Dc;
  }
  float* Y = (dir ? Y1 : Y0) + ((size_t)b * CsT + c) * L + (chunk << 6);
#pragma unroll
  for (int q = 0; q < 4; ++q) Y[16 * q + n] = ybuf[q];
}

// ---------- BN train-mode stats ----------
__global__ void k_bn_stats(const float* __restrict__ X, const float* __restrict__ g,
                           const float* __restrict__ bb, float* __restrict__ scale,
                           float* __restrict__ shift) {
  int c = blockIdx.x;
  float s = 0.f, s2 = 0.f;
  for (int t = threadIdx.x; t < B_SZ * L; t += TPB) {
    int b = t / L, l = t % L;
    float v = X[((size_t)b * C + c) * L + l];
    s += v; s2 += v * v;
  }
  __shared__ float r1[TPB], r2[TPB];
  r1[threadIdx.x] = s; r2[threadIdx.x] = s2;
  __syncthreads();
  for (int off = TPB / 2; off > 0; off >>= 1) {
    if (threadIdx.x < off) {
      r1[threadIdx.x] += r1[threadIdx.x + off];
      r2[threadIdx.x] += r2[threadIdx.x + off];
    }
    __syncthreads();
  }
  if (threadIdx.x == 0) {
    float mean = r1[0] / (B_SZ * L);
    float var  = r2[0] / (B_SZ * L) - mean * mean;
    float sc = g[c] * rsqrtf(var + 1e-5f);
    scale[c] = sc;
    shift[c] = bb[c] - mean * sc;
  }
}

// ---------- gate1: conv over [LN-cat(yf,yb_rev) ; yu] ----------
template <int O_PB>
__global__ void k_gate1(const float* __restrict__ yf, const float* __restrict__ yb,
                        const float* __restrict__ mean2, const float* __restrict__ rinv2,
                        const float* __restrict__ lncw, const float* __restrict__ lncb,
                        const float* __restrict__ yu,
                        const float* __restrict__ W, const float* __restrict__ bias,
                        float* __restrict__ g1) {
  __shared__ float Wl[O_PB * 256];
  __shared__ float cw[128], cb2[128];
  const int o0 = blockIdx.y * O_PB;
  const int b  = blockIdx.z;
  for (int t = threadIdx.x; t < O_PB * 256; t += TPB) {
    int i = t / O_PB, k = t % O_PB;
    Wl[t] = W[(size_t)(o0 + k) * 256 + i];
  }
  for (int t = threadIdx.x; t < 128; t += TPB) { cw[t] = lncw[t]; cb2[t] = lncb[t]; }
  __syncthreads();
  const int l = blockIdx.x * TPB + threadIdx.x;
  const float m = mean2[b * L + l], r = rinv2[b * L + l];
  const float* f0 = yf + (size_t)b * HALF * L + l;
  const float* b0 = yb + (size_t)b * HALF * L + (L - 1 - l);
  const float* u0 = yu + (size_t)b * C * L + l;
  float acc[O_PB];
#pragma unroll
  for (int k = 0; k < O_PB; ++k) acc[k] = bias[o0 + k];
#pragma unroll 4
  for (int i = 0; i < 64; ++i) {
    float cv = (f0[(size_t)i * L] - m) * r * cw[i] + cb2[i];
#pragma unroll
    for (int k = 0; k < O_PB; ++k) acc[k] += Wl[i * O_PB + k] * cv;
  }
#pragma unroll 4
  for (int i = 0; i < 64; ++i) {
    float cv = (b0[(size_t)i * L] - m) * r * cw[64 + i] + cb2[64 + i];
#pragma unroll
    for (int k = 0; k < O_PB; ++k) acc[k] += Wl[(64 + i) * O_PB + k] * cv;
  }
#pragma unroll 4
  for (int i = 0; i < 128; ++i) {
    float xv = u0[(size_t)i * L];
#pragma unroll
    for (int k = 0; k < O_PB; ++k) acc[k] += Wl[(128 + i) * O_PB + k] * xv;
  }
#pragma unroll
  for (int k = 0; k < O_PB; ++k)
    g1[((size_t)b * C + o0 + k) * L + l] = acc[k];
}

// ---------- gate2: conv with BN+relu on input loads; epilogue sigmoid+fuse ----------
template <int O_PB>
__global__ void k_gate2_fuse(const float* __restrict__ g1,
                             const float* __restrict__ scale, const float* __restrict__ shift,
                             const float* __restrict__ W, const float* __restrict__ bias,
                             const float* __restrict__ yu,
                             const float* __restrict__ yf, const float* __restrict__ yb,
                             const float* __restrict__ mean2, const float* __restrict__ rinv2,
                             const float* __restrict__ lncw, const float* __restrict__ lncb,
                             float* __restrict__ fused) {
  __shared__ float Wl[O_PB * 128];
  __shared__ float sc[128], sh[128];
  __shared__ float cwo[O_PB], cbo[O_PB];
  const int o0 = blockIdx.y * O_PB;
  const int b  = blockIdx.z;
  for (int t = threadIdx.x; t < O_PB * 128; t += TPB) {
    int i = t / O_PB, k = t % O_PB;
    Wl[t] = W[(size_t)(o0 + k) * 128 + i];
  }
  for (int t = threadIdx.x; t < 128; t += TPB) { sc[t] = scale[t]; sh[t] = shift[t]; }
  if (threadIdx.x < O_PB) { cwo[threadIdx.x] = lncw[o0 + threadIdx.x]; cbo[threadIdx.x] = lncb[o0 + threadIdx.x]; }
  __syncthreads();
  const int l = blockIdx.x * TPB + threadIdx.x;
  const float m = mean2[b * L + l], r = rinv2[b * L + l];
  const float* Xb = g1 + (size_t)b * C * L + l;
  float acc[O_PB];
#pragma unroll
  for (int k = 0; k < O_PB; ++k) acc[k] = bias[o0 + k];
#pragma unroll 4
  for (int i = 0; i < 128; ++i) {
    float v = fmaxf(Xb[(size_t)i * L] * sc[i] + sh[i], 0.f);
#pragma unroll
    for (int k = 0; k < O_PB; ++k) acc[k] += Wl[i * O_PB + k] * v;
  }
#pragma unroll
  for (int k = 0; k < O_PB; ++k) {
    int o = o0 + k;
    float g = sigm(acc[k]);
    float yuv = yu[((size_t)b * C + o) * L + l];
    float yv = (o < 64) ? yf[((size_t)b * HALF + o) * L + l]
                        : yb[((size_t)b * HALF + (o - 64)) * L + (L - 1 - l)];
    float cv = (yv - m) * r * cwo[k] + cbo[k];
    fused[((size_t)b * C + o) * L + l] = g * yuv + (1.f - g) * cv;
  }
}

// ---------- outproj: 1x1 conv over concat([fused, xr]) ----------
template <int O_PB>
__global__ void k_conv1x1_cat2(const float* __restrict__ X1, const float* __restrict__ X2,
                               const float* __restrict__ W, const float* __restrict__ bias,
                               float* __restrict__ Y, int O) {
  __shared__ float Wl[O_PB * 256];
  const int o0 = blockIdx.y * O_PB;
  const int b  = blockIdx.z;
  for (int t = threadIdx.x; t < O_PB * 256; t += TPB) {
    int i = t / O_PB, k = t % O_PB;
    Wl[t] = W[(size_t)(o0 + k) * 256 + i];
  }
  __syncthreads();
  const int l = blockIdx.x * TPB + threadIdx.x;
  const float* Xb1 = X1 + (size_t)b * C * L + l;
  const float* Xb2 = X2 + (size_t)b * C * L + l;
  float acc[O_PB];
#pragma unroll
  for (int k = 0; k < O_PB; ++k) acc[k] = bias[o0 + k];
#pragma unroll 4
  for (int i = 0; i < 128; ++i) {
    float xv = Xb1[(size_t)i * L];
#pragma unroll
    for (int k = 0; k < O_PB; ++k) acc[k] += Wl[i * O_PB + k] * xv;
  }
#pragma unroll 4
  for (int i = 0; i < 128; ++i) {
    float xv = Xb2[(size_t)i * L];
#pragma unroll
    for (int k = 0; k < O_PB; ++k) acc[k] += Wl[(128 + i) * O_PB + k] * xv;
  }
#pragma unroll
  for (int k = 0; k < O_PB; ++k)
    Y[((size_t)b * O + o0 + k) * L + l] = acc[k];
}

// ---------- final channel LN ----------
__global__ void k_ln_cf(const float* __restrict__ X,
                        const float* __restrict__ w, const float* __restrict__ bchan,
                        float* __restrict__ Y) {
  const int lp = threadIdx.x & 63;
  const int wv = threadIdx.x >> 6;
  const int p  = blockIdx.x * 64 + lp;
  const int b = p / L, l = p % L;
  const float* Xp = X + (size_t)b * C * L + l;
  float s = 0.f, s2 = 0.f;
#pragma unroll 8
  for (int i = 0; i < 32; ++i) {
    float v = Xp[(size_t)(wv * 32 + i) * L];
    s += v; s2 += v * v;
  }
  __shared__ float r1[4][64], r2[4][64];
  r1[wv][lp] = s; r2[wv][lp] = s2;
  __syncthreads();
  float st  = r1[0][lp] + r1[1][lp] + r1[2][lp] + r1[3][lp];
  float s2t = r2[0][lp] + r2[1][lp] + r2[2][lp] + r2[3][lp];
  float mean = st / C;
  float rinv = rsqrtf(s2t / C - mean * mean + 1e-6f);
  float* Yp = Y + (size_t)b * C * L + l;
#pragma unroll 8
  for (int i = 0; i < 32; ++i) {
    int c = wv * 32 + i;
    float v = Xp[(size_t)c * L];
    Yp[(size_t)c * L] = w[c] * (v - mean) * rinv + bchan[c];
  }
}

} // namespace

extern "C" void kernel_launch(void* const* d_in, const int* in_sizes, int n_in,
                              void* d_out, int out_size, void* d_ws, size_t ws_size,
                              hipStream_t stream) {
  const float* x         = (const float*)d_in[0];
  const float* ln_in_w   = (const float*)d_in[1];
  const float* ln_in_b   = (const float*)d_in[2];
  const float* inproj_w  = (const float*)d_in[3];
  const float* inproj_b  = (const float*)d_in[4];
  const float* ln_m_w    = (const float*)d_in[5];
  const float* ln_m_b    = (const float*)d_in[6];
  const float* convm_w   = (const float*)d_in[7];
  const float* convm_b   = (const float*)d_in[8];
  const float* convr_w   = (const float*)d_in[9];
  const float* convr_b   = (const float*)d_in[10];
  const float* ln_cat_w  = (const float*)d_in[11];
  const float* ln_cat_b  = (const float*)d_in[12];
  const float* xpf_w     = (const float*)d_in[13];
  const float* xpf_b     = (const float*)d_in[14];
  const float* dtf_w     = (const float*)d_in[15];
  const float* dtf_b     = (const float*)d_in[16];
  const float* Alog_f    = (const float*)d_in[17];
  const float* D_f       = (const float*)d_in[18];
  const float* xpb_w     = (const float*)d_in[19];
  const float* xpb_b     = (const float*)d_in[20];
  const float* dtb_w     = (const float*)d_in[21];
  const float* dtb_b     = (const float*)d_in[22];
  const float* Alog_b    = (const float*)d_in[23];
  const float* D_b       = (const float*)d_in[24];
  const float* xpu_w     = (const float*)d_in[25];
  const float* xpu_b     = (const float*)d_in[26];
  const float* dtu_w     = (const float*)d_in[27];
  const float* dtu_b     = (const float*)d_in[28];
  const float* Alog_u    = (const float*)d_in[29];
  const float* D_u       = (const float*)d_in[30];
  const float* gate1_w   = (const float*)d_in[31];
  const float* gate1_b   = (const float*)d_in[32];
  const float* bn_g      = (const float*)d_in[33];
  const float* bn_b      = (const float*)d_in[34];
  const float* gate2_w   = (const float*)d_in[35];
  const float* gate2_b   = (const float*)d_in[36];
  const float* outproj_w = (const float*)d_in[37];
  const float* outproj_b = (const float*)d_in[38];
  const float* outln_w   = (const float*)d_in[39];
  const float* outln_b   = (const float*)d_in[40];

  float* ws = (float*)d_ws;
  size_t off = 0;
  auto alloc = [&](size_t n) { float* p = ws + off; off += n; return p; };

  const size_t BL = (size_t)B_SZ * L;
  float* xp    = alloc((size_t)B_SZ * 2 * C * L);
  float* st1m  = alloc(BL);
  float* st1r  = alloc(BL);
  float* xm    = alloc((size_t)B_SZ * C * L);
  float* xr    = alloc((size_t)B_SZ * C * L);
  float* unc   = alloc(BL);
  int*   idx   = (int*)alloc(BL);
  int*   inv   = (int*)alloc(BL);
  float* xs    = alloc((size_t)B_SZ * C * L);
  float* xdblF = alloc((size_t)4 * L * 36);     // [dir*B+b][l][36]
  float* BmTF  = alloc((size_t)4 * L * N);
  float* CmTF  = alloc((size_t)4 * L * N);
  float* xdblU = alloc((size_t)2 * L * 40);
  float* BmTU  = alloc((size_t)2 * L * N);
  float* CmTU  = alloc((size_t)2 * L * N);
  float* yf    = alloc((size_t)B_SZ * HALF * L);
  float* yb    = alloc((size_t)B_SZ * HALF * L);
  float* yus   = alloc((size_t)B_SZ * C * L);
  float* yu    = alloc((size_t)B_SZ * C * L);
  float* st2m  = alloc(BL);
  float* st2r  = alloc(BL);
  float* g1    = alloc((size_t)B_SZ * C * L);
  float* bnsc  = alloc(256);
  float* fused = alloc((size_t)B_SZ * C * L);
  float* outp  = alloc((size_t)B_SZ * C * L);
  (void)ws_size; (void)in_sizes; (void)n_in; (void)out_size;

  const int pixB = B_SZ * L / 64;          // 128 blocks (256 thr, 4 waves/64px)
  const int elemB = B_SZ * C * L / TPB;    // 4096

  // 1) inproj with inline LN (stats computed in-kernel)
  k_conv_ln<16><<<dim3(L / (2 * TPB), 16, B_SZ), TPB, 0, stream>>>(
      x, C * L, ln_in_w, ln_in_b, inproj_w, inproj_b, xp, 128, 256);
  // 2) stats of xp[:,:128]; 3) batched dwconv (mamba w/ inline LN, res plain)
  k_pixstats<<<pixB, TPB, 0, stream>>>(xp, 2 * C * L, C, 1e-6f, st1m, st1r);
  k_dwconv_b<<<dim3(L / TPB, C, 2 * B_SZ), TPB, 0, stream>>>(
      xp, st1m, st1r, ln_m_w, ln_m_b, convm_w, convm_b, convr_w, convr_b, xm, xr);
  // 4) unc, sort, gather
  k_unc<<<pixB, TPB, 0, stream>>>(xm, unc);
  k_sort<<<B_SZ, 1024, 0, stream>>>(unc, idx, inv);
  k_gather<<<elemB, TPB, 0, stream>>>(xm, idx, xs);

  // ---- f+b scans (batched over z = dir*B+b) ----
  k_convx<4, 2><<<dim3(L / (2 * TPB), 9, 4), TPB, 0, stream>>>(
      xm, C * L, HALF, xpf_w, xpf_b, xpb_w, xpb_b, xdblF, HALF, 36);
  k_bc<4, 36><<<dim3(L / TPB, N, 4), TPB, 0, stream>>>(xdblF, BmTF, CmTF);
  k_scan<HALF, 4, 36><<<4 * HALF, 1024, 0, stream>>>(
      xdblF, dtf_w, dtf_b, dtb_w, dtb_b, xm, C * L, HALF,
      BmTF, CmTF, Alog_f, Alog_b, D_f, D_b, yf, yb);

  // ---- u scan ----
  k_convx<4, 1><<<dim3(L / TPB, 10, 2), TPB, 0, stream>>>(
      xs, C * L, 0, xpu_w, xpu_b, xpu_w, xpu_b, xdblU, C, 40);
  k_bc<8, 40><<<dim3(L / TPB, N, 2), TPB, 0, stream>>>(xdblU, BmTU, CmTU);
  k_scan<C, 8, 40><<<2 * C, 1024, 0, stream>>>(
      xdblU, dtu_w, dtu_b, dtu_w, dtu_b, xs, C * L, 0,
      BmTU, CmTU, Alog_u, Alog_u, D_u, D_u, yus, yus);

  // ---- epilogue ----
  k_unsort<<<elemB, TPB, 0, stream>>>(yus, inv, yu);
  k_pixstats_cat<<<pixB, TPB, 0, stream>>>(yf, yb, st2m, st2r);
  k_gate1<16><<<dim3(L / TPB, 8, B_SZ), TPB, 0, stream>>>(
      yf, yb, st2m, st2r, ln_cat_w, ln_cat_b, yu, gate1_w, gate1_b, g1);
  k_bn_stats<<<C, TPB, 0, stream>>>(g1, bn_g, bn_b, bnsc, bnsc + 128);
  k_gate2_fuse<16><<<dim3(L / TPB, 8, B_SZ), TPB, 0, stream>>>(
      g1, bnsc, bnsc + 128, gate2_w, gate2_b, yu, yf, yb, st2m, st2r,
      ln_cat_w, ln_cat_b, fused);
  k_conv1x1_cat2<16><<<dim3(L / TPB, 8, B_SZ), TPB, 0, stream>>>(
      fused, xr, outproj_w, outproj_b, outp, 128);
  k_ln_cf<<<pixB, TPB, 0, stream>>>(outp, outln_w, outln_b, (float*)d_out);
}

// Round 7
// 420.982 us; speedup vs baseline: 1.4569x; 1.0372x over previous
//
#include <hip/hip_runtime.h>
#include <cstdint>
#include <cstddef>

#define TPB 256

namespace {

constexpr int B_SZ = 2;
constexpr int C    = 128;
constexpr int HALF = 64;
constexpr int L    = 4096;   // 64*64
constexpr int N    = 16;
constexpr int HH   = 64;
constexpr int WW   = 64;

__device__ __forceinline__ float softplusf(float x) {
  return fmaxf(x, 0.f) + log1pf(expf(-fabsf(x)));
}
__device__ __forceinline__ float sigm(float x) { return 1.f / (1.f + expf(-x)); }

// ---------- per-pixel channel stats (mean, rsqrt(var+eps)) ----------
__global__ void k_pixstats(const float* __restrict__ X, int bsX, int Cn, float eps,
                           float* __restrict__ mean, float* __restrict__ rinv) {
  const int lp = threadIdx.x & 63;
  const int wv = threadIdx.x >> 6;
  const int p  = blockIdx.x * 64 + lp;
  const int b = p / L, l = p % L;
  const int Cq = Cn >> 2;
  const float* Xp = X + (size_t)b * bsX + l;
  float s = 0.f, s2 = 0.f;
#pragma unroll 8
  for (int i = 0; i < Cq; ++i) {
    float v = Xp[(size_t)(wv * Cq + i) * L];
    s += v; s2 += v * v;
  }
  __shared__ float r1[4][64], r2[4][64];
  r1[wv][lp] = s; r2[wv][lp] = s2;
  __syncthreads();
  if (wv == 0) {
    float st  = r1[0][lp] + r1[1][lp] + r1[2][lp] + r1[3][lp];
    float s2t = r2[0][lp] + r2[1][lp] + r2[2][lp] + r2[3][lp];
    float m = st / Cn;
    float var = s2t / Cn - m * m;
    mean[p] = m;
    rinv[p] = rsqrtf(var + eps);
  }
}

// ---------- inproj: 1x1 conv with INLINE per-pixel LN ----------
template <int O_PB>
__global__ void k_conv_ln(const float* __restrict__ X, int bsX,
                          const float* __restrict__ lnw, const float* __restrict__ lnb,
                          const float* __restrict__ W, const float* __restrict__ bias,
                          float* __restrict__ Y, int I, int O) {
  __shared__ float Wl[O_PB * 128];
  __shared__ float aw[128], ab[128];
  const int o0 = blockIdx.y * O_PB;
  const int b  = blockIdx.z;
  for (int t = threadIdx.x; t < O_PB * I; t += TPB) {
    int i = t / O_PB, k = t % O_PB;
    Wl[t] = W[(size_t)(o0 + k) * I + i];
  }
  for (int t = threadIdx.x; t < I; t += TPB) { aw[t] = lnw[t]; ab[t] = lnb[t]; }
  __syncthreads();
  const int l0 = blockIdx.x * (2 * TPB) + threadIdx.x;
  const int l1 = l0 + TPB;
  const float* X0 = X + (size_t)b * bsX + l0;
  const float* X1 = X + (size_t)b * bsX + l1;
  float s0 = 0.f, q0 = 0.f, s1 = 0.f, q1 = 0.f;
#pragma unroll 8
  for (int i = 0; i < I; ++i) {
    float v0 = X0[(size_t)i * L], v1 = X1[(size_t)i * L];
    s0 += v0; q0 += v0 * v0; s1 += v1; q1 += v1 * v1;
  }
  const float m0 = s0 / I, m1 = s1 / I;
  const float r0 = rsqrtf(q0 / I - m0 * m0 + 1e-6f);
  const float r1 = rsqrtf(q1 / I - m1 * m1 + 1e-6f);
  float acc0[O_PB], acc1[O_PB];
#pragma unroll
  for (int k = 0; k < O_PB; ++k) { acc0[k] = bias[o0 + k]; acc1[k] = acc0[k]; }
#pragma unroll 4
  for (int i = 0; i < I; ++i) {
    float xv0 = (X0[(size_t)i * L] - m0) * r0 * aw[i] + ab[i];
    float xv1 = (X1[(size_t)i * L] - m1) * r1 * aw[i] + ab[i];
#pragma unroll
    for (int k = 0; k < O_PB; ++k) {
      acc0[k] += Wl[i * O_PB + k] * xv0;
      acc1[k] += Wl[i * O_PB + k] * xv1;
    }
  }
#pragma unroll
  for (int k = 0; k < O_PB; ++k) {
    Y[((size_t)b * O + o0 + k) * L + l0] = acc0[k];
    Y[((size_t)b * O + o0 + k) * L + l1] = acc1[k];
  }
}

// ---------- depthwise 3x3 + SiLU via LDS halo tile; mode0 LN on staging ----------
__global__ void k_dwconv_t(const float* __restrict__ xp,
                           const float* __restrict__ mean1, const float* __restrict__ rinv1,
                           const float* __restrict__ lnw, const float* __restrict__ lnb,
                           const float* __restrict__ Wm, const float* __restrict__ bm,
                           const float* __restrict__ Wr, const float* __restrict__ br,
                           float* __restrict__ xm, float* __restrict__ xr) {
  const int c = blockIdx.y;
  const int z = blockIdx.z;
  const int b = z & 1, mode = z >> 1;     // 0: mamba (LN), 1: res
  const int h0 = blockIdx.x * 4;
  __shared__ float T[6][66];
  const float* Xc = xp + ((size_t)b * 2 * C + (mode ? C + c : c)) * L;
  const float lw = mode ? 0.f : lnw[c];
  const float lb2 = mode ? 0.f : lnb[c];
  for (int t = threadIdx.x; t < 6 * 66; t += TPB) {
    int r = t / 66, cc = t % 66 - 1;
    int hh = h0 - 1 + r;
    float v = 0.f;
    if (hh >= 0 && hh < HH && cc >= 0 && cc < WW) {
      int li = hh * WW + cc;
      v = Xc[li];
      if (mode == 0) v = (v - mean1[b * L + li]) * rinv1[b * L + li] * lw + lb2;
    }
    T[r][t % 66] = v;
  }
  __syncthreads();
  const int hl = threadIdx.x >> 6, w = threadIdx.x & 63;
  const float* W9 = (mode ? Wr : Wm) + c * 9;
  float acc = mode ? br[c] : bm[c];
#pragma unroll
  for (int kh = 0; kh < 3; ++kh)
#pragma unroll
    for (int kw = 0; kw < 3; ++kw)
      acc += T[hl + kh][w + kw] * W9[kh * 3 + kw];
  const int l = (h0 + hl) * WW + w;
  float* Yp = mode ? xr : xm;
  Yp[((size_t)b * C + c) * L + l] = acc * sigm(acc);
}

// ---------- uncertainty per pixel (+ zero the BN accumulator) ----------
__global__ void k_unc(const float* __restrict__ xm, float* __restrict__ unc,
                      float* __restrict__ bnsum) {
  if (blockIdx.x == 0) bnsum[threadIdx.x] = 0.f;   // 256 floats
  const int lp = threadIdx.x & 63;
  const int wv = threadIdx.x >> 6;
  const int p  = blockIdx.x * 64 + lp;
  const int b = p / L, l = p % L;
  const float* Xp = xm + (size_t)b * C * L + l;
  float s = 0.f;
#pragma unroll 8
  for (int i = 0; i < 32; ++i) s += Xp[(size_t)(wv * 32 + i) * L];
  __shared__ float r1[4][64];
  r1[wv][lp] = s;
  __syncthreads();
  if (wv == 0) {
    float st = r1[0][lp] + r1[1][lp] + r1[2][lp] + r1[3][lp];
    float sg = sigm(st / C);
    unc[p] = -(sg * logf(sg + 1e-6f));
  }
}

// ---------- stable argsort(-unc): register/shfl bitonic ----------
__global__ void k_sort(const float* __restrict__ unc, int* __restrict__ idx,
                       int* __restrict__ inv) {
  __shared__ unsigned long long S[L];
  const int b = blockIdx.x;
  const int tid = threadIdx.x;
  const int e0 = tid * 4;
  unsigned long long v[4];
  {
    float4 u4 = ((const float4*)(unc + b * L))[tid];
    float uv[4] = {u4.x, u4.y, u4.z, u4.w};
#pragma unroll
    for (int r = 0; r < 4; ++r) {
      unsigned u = __float_as_uint(uv[r]);
      u = (u & 0x80000000u) ? ~u : (u | 0x80000000u);
      v[r] = ((unsigned long long)(~u) << 32) | (unsigned)(e0 + r);
    }
  }
  for (int k = 2; k <= 256; k <<= 1) {
    for (int j = k >> 1; j > 0; j >>= 1) {
      if (j >= 4) {
        int m = j >> 2;
#pragma unroll
        for (int r = 0; r < 4; ++r) {
          unsigned long long p = __shfl_xor(v[r], m);
          int e = e0 + r;
          bool keepmin = (((e & k) == 0) == ((e & j) == 0));
          v[r] = keepmin ? (v[r] < p ? v[r] : p) : (v[r] > p ? v[r] : p);
        }
      } else {
#pragma unroll
        for (int r = 0; r < 4; ++r) {
          int rp = r ^ j;
          if (rp > r) {
            int e = e0 + r;
            bool up = ((e & k) == 0);
            unsigned long long a = v[r], bb = v[rp];
            if ((a > bb) == up) { v[r] = bb; v[rp] = a; }
          }
        }
      }
    }
  }
#pragma unroll
  for (int r = 0; r < 4; ++r) S[e0 + r] = v[r];
  __syncthreads();
  for (int k = 512; k <= L; k <<= 1) {
    for (int j = k >> 1; j >= 256; j >>= 1) {
      for (int q = tid; q < L / 2; q += 1024) {
        int i = ((q & ~(j - 1)) << 1) | (q & (j - 1));
        int ixj = i | j;
        unsigned long long a = S[i], bb = S[ixj];
        bool up = ((i & k) == 0);
        if ((a > bb) == up) { S[i] = bb; S[ixj] = a; }
      }
      __syncthreads();
    }
#pragma unroll
    for (int r = 0; r < 4; ++r) v[r] = S[e0 + r];
    const bool up = ((e0 & k) == 0);
    for (int j = 128; j >= 4; j >>= 1) {
      int m = j >> 2;
#pragma unroll
      for (int r = 0; r < 4; ++r) {
        unsigned long long p = __shfl_xor(v[r], m);
        int e = e0 + r;
        bool keepmin = (up == ((e & j) == 0));
        v[r] = keepmin ? (v[r] < p ? v[r] : p) : (v[r] > p ? v[r] : p);
      }
    }
#pragma unroll
    for (int j = 2; j > 0; j >>= 1) {
#pragma unroll
      for (int r = 0; r < 4; ++r) {
        int rp = r ^ j;
        if (rp > r) {
          unsigned long long a = v[r], bb = v[rp];
          if ((a > bb) == up) { v[r] = bb; v[rp] = a; }
        }
      }
    }
#pragma unroll
    for (int r = 0; r < 4; ++r) S[e0 + r] = v[r];
    __syncthreads();
  }
  for (int i = tid; i < L; i += 1024) {
    int orig = (int)(S[i] & 0xffffffffu);
    idx[b * L + i] = orig;
    inv[b * L + orig] = i;
  }
}

// ---------- unsort ----------
__global__ void k_unsort(const float* __restrict__ yus, const int* __restrict__ inv,
                         float* __restrict__ yu) {
  int t = blockIdx.x * TPB + threadIdx.x;
  int l = t % L, c = (t / L) % C, b = t / (C * L);
  yu[t] = yus[((size_t)b * C + c) * L + inv[b * L + l]];
}

// ---------- merged x-projection conv: z 0..3 = f/b dirs, z 4..5 = u (gathered) ----------
__global__ void k_convx_all(const float* __restrict__ xm, const int* __restrict__ idx,
                            const float* __restrict__ Wf, const float* __restrict__ bf,
                            const float* __restrict__ Wb, const float* __restrict__ bb,
                            const float* __restrict__ Wu, const float* __restrict__ bu,
                            float* __restrict__ XDF, float* __restrict__ XDU) {
  const int z = blockIdx.z;
  const bool isU = z >= 4;
  const int I = isU ? 128 : 64;
  const int O = isU ? 40 : 36;
  const int o0 = blockIdx.y * 4;
  if (o0 >= O) return;                 // block-uniform
  int b, dir;
  const float *W, *bi;
  if (!isU) { dir = z >> 1; b = z & 1; W = dir ? Wb : Wf; bi = dir ? bb : bf; }
  else      { dir = 0; b = z - 4; W = Wu; bi = bu; }
  __shared__ float Wl[4 * 128];
  for (int t = threadIdx.x; t < 4 * I; t += TPB) {
    int i = t / 4, k = t % 4;
    Wl[t] = W[(size_t)(o0 + k) * I + i];
  }
  __syncthreads();
  const int l = blockIdx.x * TPB + threadIdx.x;
  const int ls = isU ? idx[b * L + l] : (dir ? (L - 1 - l) : l);
  const float* Xb = xm + ((size_t)b * C + (isU ? 0 : dir * HALF)) * L;
  float acc[4];
#pragma unroll
  for (int k = 0; k < 4; ++k) acc[k] = bi[o0 + k];
#pragma unroll 4
  for (int i = 0; i < I; ++i) {
    float xv = Xb[(size_t)i * L + ls];
#pragma unroll
    for (int k = 0; k < 4; ++k) acc[k] += Wl[i * 4 + k] * xv;
  }
  float* yp = isU ? (XDU + ((size_t)b * L + l) * 40 + o0)
                  : (XDF + ((size_t)z * L + l) * 36 + o0);
#pragma unroll
  for (int k = 0; k < 4; ++k) yp[k] = acc[k];
}

// ---------- merged B/C scrambled transpose ----------
__global__ void k_bc_all(const float* __restrict__ xdblF, const float* __restrict__ xdblU,
                         float* __restrict__ BmTF, float* __restrict__ CmTF,
                         float* __restrict__ BmTU, float* __restrict__ CmTU) {
  const int z = blockIdx.z;
  const bool isU = z >= 4;
  const int RT = isU ? 8 : 4, OT = isU ? 40 : 36;
  const float* src = isU ? (xdblU + (size_t)(z - 4) * L * 40)
                         : (xdblF + (size_t)z * L * 36);
  float* BT = isU ? (BmTU + (size_t)(z - 4) * L * N) : (BmTF + (size_t)z * L * N);
  float* CT = isU ? (CmTU + (size_t)(z - 4) * L * N) : (CmTF + (size_t)z * L * N);
  const int n = blockIdx.y;
  const int l2 = blockIdx.x * TPB + threadIdx.x;
  int f2 = n * L + l2;
  int lb = f2 >> 4, cb = f2 & 15;
  const float* xr2 = src + (size_t)lb * OT + RT + cb;
  size_t ob = (size_t)l2 * N + n;
  BT[ob] = xr2[0];
  CT[ob] = xr2[N];
}

// ---------- merged fused selective scan (512 blocks: 256 F rows + 256 U rows) ----------
__global__ __launch_bounds__(1024) void
k_scan_all(const float* __restrict__ xdblF, const float* __restrict__ xdblU,
           const float* __restrict__ dtf_w, const float* __restrict__ dtf_b,
           const float* __restrict__ dtb_w, const float* __restrict__ dtb_b,
           const float* __restrict__ dtu_w, const float* __restrict__ dtu_b,
           const float* __restrict__ xm, const int* __restrict__ idx,
           const float* __restrict__ BmTF, const float* __restrict__ CmTF,
           const float* __restrict__ BmTU, const float* __restrict__ CmTU,
           const float* __restrict__ Alog_f, const float* __restrict__ Alog_b,
           const float* __restrict__ Alog_u,
           const float* __restrict__ D_f, const float* __restrict__ D_b,
           const float* __restrict__ D_u,
           float* __restrict__ yf, float* __restrict__ yb, float* __restrict__ yus) {
  const int blk = blockIdx.x;
  const int tid = threadIdx.x;
  const bool isU = blk >= 256;
  int CsT, RT, OT, c, b, dir;
  const float *Wdt, *bdt, *Alog, *Dv, *xdbl, *BT, *CT, *Ub;
  const int* idxb = nullptr;
  float* Y;
  if (!isU) {
    CsT = 64; RT = 4; OT = 36;
    int zb = blk >> 6; c = blk & 63; dir = zb >> 1; b = zb & 1;
    Wdt = dir ? dtb_w : dtf_w; bdt = dir ? dtb_b : dtf_b;
    Alog = dir ? Alog_b : Alog_f; Dv = dir ? D_b : D_f;
    xdbl = xdblF + (size_t)zb * L * 36;
    BT = BmTF + (size_t)zb * L * N; CT = CmTF + (size_t)zb * L * N;
    Ub = xm + ((size_t)b * C + dir * HALF + c) * L;
    Y = (dir ? yb : yf) + ((size_t)b * HALF + c) * L;
  } else {
    CsT = 128; RT = 8; OT = 40;
    int blk2 = blk - 256; b = blk2 >> 7; c = blk2 & 127; dir = 0;
    Wdt = dtu_w; bdt = dtu_b; Alog = Alog_u; Dv = D_u;
    xdbl = xdblU + (size_t)b * L * 40;
    BT = BmTU + (size_t)b * L * N; CT = CmTU + (size_t)b * L * N;
    Ub = xm + ((size_t)b * C + c) * L;
    idxb = idx + b * L;
    Y = yus + ((size_t)b * C + c) * L;
  }
  __shared__ float sW[1024];
  __shared__ float sb2[128];
  __shared__ float dtL[64][65];
  __shared__ float uL[64][65];
  __shared__ float sA[N][65], sH[N][65];
  for (int t = tid; t < CsT * RT; t += 1024) sW[t] = Wdt[t];
  for (int t = tid; t < CsT; t += 1024) sb2[t] = bdt[t];
  __syncthreads();
  // ---- stage 1: dt + u into LDS ----
  {
    const int chunk_d = tid >> 4;
    const int sq = (tid & 15) * 4;
    const int lsrc = isU ? (c * 32 + (chunk_d >> 1)) : (c * 64 + chunk_d);
    const float* xrp = xdbl + (size_t)lsrc * OT;
    float xr[8];
    for (int r = 0; r < RT; ++r) xr[r] = xrp[r];
    const float bcc = sb2[c];
#pragma unroll
    for (int j = 0; j < 4; ++j) {
      int s = sq + j;
      int csrc = isU ? (((chunk_d & 1) << 6) + s) : s;
      float acc = sb2[csrc] + bcc;
      for (int r = 0; r < RT; ++r) acc += sW[csrc * RT + r] * xr[r];
      int l = (chunk_d << 6) + s;
      int lu = isU ? idxb[l] : (dir ? (L - 1 - l) : l);
      dtL[chunk_d][s] = softplusf(acc);
      uL[chunk_d][s] = Ub[lu];
    }
  }
  __syncthreads();
  const int n = tid & 15;
  const int chunk = tid >> 4;
  const float a = -expf(Alog[c * N + n]);
  const float* bp = BT + ((size_t)(chunk << 6)) * N + n;
  const float* cp = CT + ((size_t)(chunk << 6)) * N + n;
  // phase A
  float ap = 1.f, h = 0.f;
#pragma unroll 4
  for (int s = 0; s < 64; ++s) {
    float d = dtL[chunk][s];
    float uv = uL[chunk][s];
    float bn = bp[(size_t)s * N];
    float dA = expf(d * a);
    ap *= dA;
    h = h * dA + d * uv * bn;
  }
  sA[n][chunk] = ap; sH[n][chunk] = h;
  __syncthreads();
  // phase B: wave-parallel cross-chunk exclusive scan (wave w owns n=w)
  {
    const int w = tid >> 6;
    const int k = tid & 63;
    float A = sA[w][k];
    float Bv = sH[w][k];
#pragma unroll
    for (int j = 1; j < 64; j <<= 1) {
      float pa = __shfl_up(A, j);
      float pb = __shfl_up(Bv, j);
      if (k >= j) { Bv = pb * A + Bv; A = pa * A; }
    }
    float hprev = __shfl_up(Bv, 1);
    sH[w][k] = (k == 0) ? 0.f : hprev;
  }
  __syncthreads();
  h = sH[n][chunk];
  // phase C
  const float Dc = Dv[c];
  float ybuf[4];
#pragma unroll 4
  for (int s = 0; s < 64; ++s) {
    float d = dtL[chunk][s];
    float uv = uL[chunk][s];
    float bn = bp[(size_t)s * N];
    float cn = cp[(size_t)s * N];
    float dA = expf(d * a);
    h = h * dA + d * uv * bn;
    float p = h * cn;
    p += __shfl_xor(p, 1);
    p += __shfl_xor(p, 2);
    p += __shfl_xor(p, 4);
    p += __shfl_xor(p, 8);
    if ((s & 15) == n) ybuf[s >> 4] = p + uv * Dc;
  }
  float* Yp = Y + (chunk << 6);
#pragma unroll
  for (int q = 0; q < 4; ++q) Yp[16 * q + n] = ybuf[q];
}

// ---------- gate1: inline cat-LN stats + conv + BN partial sums ----------
template <int O_PB>
__global__ void k_gate1(const float* __restrict__ yf, const float* __restrict__ yb,
                        const float* __restrict__ lncw, const float* __restrict__ lncb,
                        const float* __restrict__ yu,
                        const float* __restrict__ W, const float* __restrict__ bias,
                        float* __restrict__ g1,
                        float* __restrict__ st2m, float* __restrict__ st2r,
                        float* __restrict__ bnsum) {
  __shared__ float Wl[O_PB * 256];
  __shared__ float cw[128], cb2[128];
  __shared__ float part[2][O_PB][4];
  const int o0 = blockIdx.y * O_PB;
  const int b  = blockIdx.z;
  for (int t = threadIdx.x; t < O_PB * 256; t += TPB) {
    int i = t / O_PB, k = t % O_PB;
    Wl[t] = W[(size_t)(o0 + k) * 256 + i];
  }
  for (int t = threadIdx.x; t < 128; t += TPB) { cw[t] = lncw[t]; cb2[t] = lncb[t]; }
  __syncthreads();
  const int l = blockIdx.x * TPB + threadIdx.x;
  const float* f0 = yf + (size_t)b * HALF * L + l;
  const float* b0 = yb + (size_t)b * HALF * L + (L - 1 - l);
  const float* u0 = yu + (size_t)b * C * L + l;
  // inline stats over cat channels
  float s = 0.f, s2 = 0.f;
#pragma unroll 8
  for (int i = 0; i < 64; ++i) { float v = f0[(size_t)i * L]; s += v; s2 += v * v; }
#pragma unroll 8
  for (int i = 0; i < 64; ++i) { float v = b0[(size_t)i * L]; s += v; s2 += v * v; }
  const float m = s / C;
  const float r = rsqrtf(s2 / C - m * m + 1e-6f);
  if (blockIdx.y == 0) { st2m[b * L + l] = m; st2r[b * L + l] = r; }
  float acc[O_PB];
#pragma unroll
  for (int k = 0; k < O_PB; ++k) acc[k] = bias[o0 + k];
#pragma unroll 4
  for (int i = 0; i < 64; ++i) {
    float cv = (f0[(size_t)i * L] - m) * r * cw[i] + cb2[i];
#pragma unroll
    for (int k = 0; k < O_PB; ++k) acc[k] += Wl[i * O_PB + k] * cv;
  }
#pragma unroll 4
  for (int i = 0; i < 64; ++i) {
    float cv = (b0[(size_t)i * L] - m) * r * cw[64 + i] + cb2[64 + i];
#pragma unroll
    for (int k = 0; k < O_PB; ++k) acc[k] += Wl[(64 + i) * O_PB + k] * cv;
  }
#pragma unroll 4
  for (int i = 0; i < 128; ++i) {
    float xv = u0[(size_t)i * L];
#pragma unroll
    for (int k = 0; k < O_PB; ++k) acc[k] += Wl[(128 + i) * O_PB + k] * xv;
  }
#pragma unroll
  for (int k = 0; k < O_PB; ++k)
    g1[((size_t)b * C + o0 + k) * L + l] = acc[k];
  // BN partial sums: shuffle-reduce per wave, then one atomic per channel
  const int wv = threadIdx.x >> 6, lnn = threadIdx.x & 63;
#pragma unroll
  for (int k = 0; k < O_PB; ++k) {
    float v = acc[k];
    v += __shfl_xor(v, 1);  v += __shfl_xor(v, 2);  v += __shfl_xor(v, 4);
    v += __shfl_xor(v, 8);  v += __shfl_xor(v, 16); v += __shfl_xor(v, 32);
    if (lnn == 0) part[0][k][wv] = v;
    float q = acc[k] * acc[k];
    q += __shfl_xor(q, 1);  q += __shfl_xor(q, 2);  q += __shfl_xor(q, 4);
    q += __shfl_xor(q, 8);  q += __shfl_xor(q, 16); q += __shfl_xor(q, 32);
    if (lnn == 0) part[1][k][wv] = q;
  }
  __syncthreads();
  if (threadIdx.x < 2 * O_PB) {
    int which = threadIdx.x >= O_PB, k = threadIdx.x % O_PB;
    float v = part[which][k][0] + part[which][k][1] + part[which][k][2] + part[which][k][3];
    atomicAdd(&bnsum[which * 128 + o0 + k], v);
  }
}

// ---------- gate2: BN(from sums)+relu on loads; epilogue sigmoid+fuse ----------
template <int O_PB>
__global__ void k_gate2_fuse(const float* __restrict__ g1,
                             const float* __restrict__ bnsum,
                             const float* __restrict__ bn_g, const float* __restrict__ bn_b,
                             const float* __restrict__ W, const float* __restrict__ bias,
                             const float* __restrict__ yu,
                             const float* __restrict__ yf, const float* __restrict__ yb,
                             const float* __restrict__ mean2, const float* __restrict__ rinv2,
                             const float* __restrict__ lncw, const float* __restrict__ lncb,
                             float* __restrict__ fused) {
  __shared__ float Wl[O_PB * 128];
  __shared__ float sc[128], sh[128];
  __shared__ float cwo[O_PB], cbo[O_PB];
  const int o0 = blockIdx.y * O_PB;
  const int b  = blockIdx.z;
  for (int t = threadIdx.x; t < O_PB * 128; t += TPB) {
    int i = t / O_PB, k = t % O_PB;
    Wl[t] = W[(size_t)(o0 + k) * 128 + i];
  }
  for (int t = threadIdx.x; t < 128; t += TPB) {
    float sv = bnsum[t], qv = bnsum[128 + t];
    float mean = sv / (B_SZ * L);
    float var  = qv / (B_SZ * L) - mean * mean;
    float scv = bn_g[t] * rsqrtf(var + 1e-5f);
    sc[t] = scv;
    sh[t] = bn_b[t] - mean * scv;
  }
  if (threadIdx.x < O_PB) {
    cwo[threadIdx.x] = lncw[o0 + threadIdx.x];
    cbo[threadIdx.x] = lncb[o0 + threadIdx.x];
  }
  __syncthreads();
  const int l = blockIdx.x * TPB + threadIdx.x;
  const float m = mean2[b * L + l], r = rinv2[b * L + l];
  const float* Xb = g1 + (size_t)b * C * L + l;
  float acc[O_PB];
#pragma unroll
  for (int k = 0; k < O_PB; ++k) acc[k] = bias[o0 + k];
#pragma unroll 4
  for (int i = 0; i < 128; ++i) {
    float v = fmaxf(Xb[(size_t)i * L] * sc[i] + sh[i], 0.f);
#pragma unroll
    for (int k = 0; k < O_PB; ++k) acc[k] += Wl[i * O_PB + k] * v;
  }
#pragma unroll
  for (int k = 0; k < O_PB; ++k) {
    int o = o0 + k;
    float g = sigm(acc[k]);
    float yuv = yu[((size_t)b * C + o) * L + l];
    float yv = (o < 64) ? yf[((size_t)b * HALF + o) * L + l]
                        : yb[((size_t)b * HALF + (o - 64)) * L + (L - 1 - l)];
    float cv = (yv - m) * r * cwo[k] + cbo[k];
    fused[((size_t)b * C + o) * L + l] = g * yuv + (1.f - g) * cv;
  }
}

// ---------- outproj: 1x1 conv over concat([fused, xr]) ----------
template <int O_PB>
__global__ void k_conv1x1_cat2(const float* __restrict__ X1, const float* __restrict__ X2,
                               const float* __restrict__ W, const float* __restrict__ bias,
                               float* __restrict__ Y, int O) {
  __shared__ float Wl[O_PB * 256];
  const int o0 = blockIdx.y * O_PB;
  const int b  = blockIdx.z;
  for (int t = threadIdx.x; t < O_PB * 256; t += TPB) {
    int i = t / O_PB, k = t % O_PB;
    Wl[t] = W[(size_t)(o0 + k) * 256 + i];
  }
  __syncthreads();
  const int l = blockIdx.x * TPB + threadIdx.x;
  const float* Xb1 = X1 + (size_t)b * C * L + l;
  const float* Xb2 = X2 + (size_t)b * C * L + l;
  float acc[O_PB];
#pragma unroll
  for (int k = 0; k < O_PB; ++k) acc[k] = bias[o0 + k];
#pragma unroll 4
  for (int i = 0; i < 128; ++i) {
    float xv = Xb1[(size_t)i * L];
#pragma unroll
    for (int k = 0; k < O_PB; ++k) acc[k] += Wl[i * O_PB + k] * xv;
  }
#pragma unroll 4
  for (int i = 0; i < 128; ++i) {
    float xv = Xb2[(size_t)i * L];
#pragma unroll
    for (int k = 0; k < O_PB; ++k) acc[k] += Wl[(128 + i) * O_PB + k] * xv;
  }
#pragma unroll
  for (int k = 0; k < O_PB; ++k)
    Y[((size_t)b * O + o0 + k) * L + l] = acc[k];
}

// ---------- final channel LN ----------
__global__ void k_ln_cf(const float* __restrict__ X,
                        const float* __restrict__ w, const float* __restrict__ bchan,
                        float* __restrict__ Y) {
  const int lp = threadIdx.x & 63;
  const int wv = threadIdx.x >> 6;
  const int p  = blockIdx.x * 64 + lp;
  const int b = p / L, l = p % L;
  const float* Xp = X + (size_t)b * C * L + l;
  float s = 0.f, s2 = 0.f;
#pragma unroll 8
  for (int i = 0; i < 32; ++i) {
    float v = Xp[(size_t)(wv * 32 + i) * L];
    s += v; s2 += v * v;
  }
  __shared__ float r1[4][64], r2[4][64];
  r1[wv][lp] = s; r2[wv][lp] = s2;
  __syncthreads();
  float st  = r1[0][lp] + r1[1][lp] + r1[2][lp] + r1[3][lp];
  float s2t = r2[0][lp] + r2[1][lp] + r2[2][lp] + r2[3][lp];
  float mean = st / C;
  float rinv = rsqrtf(s2t / C - mean * mean + 1e-6f);
  float* Yp = Y + (size_t)b * C * L + l;
#pragma unroll 8
  for (int i = 0; i < 32; ++i) {
    int c = wv * 32 + i;
    float v = Xp[(size_t)c * L];
    Yp[(size_t)c * L] = w[c] * (v - mean) * rinv + bchan[c];
  }
}

} // namespace

extern "C" void kernel_launch(void* const* d_in, const int* in_sizes, int n_in,
                              void* d_out, int out_size, void* d_ws, size_t ws_size,
                              hipStream_t stream) {
  const float* x         = (const float*)d_in[0];
  const float* ln_in_w   = (const float*)d_in[1];
  const float* ln_in_b   = (const float*)d_in[2];
  const float* inproj_w  = (const float*)d_in[3];
  const float* inproj_b  = (const float*)d_in[4];
  const float* ln_m_w    = (const float*)d_in[5];
  const float* ln_m_b    = (const float*)d_in[6];
  const float* convm_w   = (const float*)d_in[7];
  const float* convm_b   = (const float*)d_in[8];
  const float* convr_w   = (const float*)d_in[9];
  const float* convr_b   = (const float*)d_in[10];
  const float* ln_cat_w  = (const float*)d_in[11];
  const float* ln_cat_b  = (const float*)d_in[12];
  const float* xpf_w     = (const float*)d_in[13];
  const float* xpf_b     = (const float*)d_in[14];
  const float* dtf_w     = (const float*)d_in[15];
  const float* dtf_b     = (const float*)d_in[16];
  const float* Alog_f    = (const float*)d_in[17];
  const float* D_f       = (const float*)d_in[18];
  const float* xpb_w     = (const float*)d_in[19];
  const float* xpb_b     = (const float*)d_in[20];
  const float* dtb_w     = (const float*)d_in[21];
  const float* dtb_b     = (const float*)d_in[22];
  const float* Alog_b    = (const float*)d_in[23];
  const float* D_b       = (const float*)d_in[24];
  const float* xpu_w     = (const float*)d_in[25];
  const float* xpu_b     = (const float*)d_in[26];
  const float* dtu_w     = (const float*)d_in[27];
  const float* dtu_b     = (const float*)d_in[28];
  const float* Alog_u    = (const float*)d_in[29];
  const float* D_u       = (const float*)d_in[30];
  const float* gate1_w   = (const float*)d_in[31];
  const float* gate1_b   = (const float*)d_in[32];
  const float* bn_g      = (const float*)d_in[33];
  const float* bn_b      = (const float*)d_in[34];
  const float* gate2_w   = (const float*)d_in[35];
  const float* gate2_b   = (const float*)d_in[36];
  const float* outproj_w = (const float*)d_in[37];
  const float* outproj_b = (const float*)d_in[38];
  const float* outln_w   = (const float*)d_in[39];
  const float* outln_b   = (const float*)d_in[40];

  float* ws = (float*)d_ws;
  size_t off = 0;
  auto alloc = [&](size_t n) { float* p = ws + off; off += n; return p; };

  const size_t BL = (size_t)B_SZ * L;
  float* xp    = alloc((size_t)B_SZ * 2 * C * L);
  float* st1m  = alloc(BL);
  float* st1r  = alloc(BL);
  float* xm    = alloc((size_t)B_SZ * C * L);
  float* xr    = alloc((size_t)B_SZ * C * L);
  float* unc   = alloc(BL);
  int*   idx   = (int*)alloc(BL);
  int*   inv   = (int*)alloc(BL);
  float* xdblF = alloc((size_t)4 * L * 36);
  float* BmTF  = alloc((size_t)4 * L * N);
  float* CmTF  = alloc((size_t)4 * L * N);
  float* xdblU = alloc((size_t)2 * L * 40);
  float* BmTU  = alloc((size_t)2 * L * N);
  float* CmTU  = alloc((size_t)2 * L * N);
  float* yf    = alloc((size_t)B_SZ * HALF * L);
  float* yb    = alloc((size_t)B_SZ * HALF * L);
  float* yus   = alloc((size_t)B_SZ * C * L);
  float* yu    = alloc((size_t)B_SZ * C * L);
  float* st2m  = alloc(BL);
  float* st2r  = alloc(BL);
  float* g1    = alloc((size_t)B_SZ * C * L);
  float* bnsum = alloc(256);
  float* fused = alloc((size_t)B_SZ * C * L);
  float* outp  = alloc((size_t)B_SZ * C * L);
  (void)ws_size; (void)in_sizes; (void)n_in; (void)out_size;

  const int pixB = B_SZ * L / 64;          // 128 blocks (256 thr)
  const int elemB = B_SZ * C * L / TPB;    // 4096

  // 1) inproj with inline LN
  k_conv_ln<16><<<dim3(L / (2 * TPB), 16, B_SZ), TPB, 0, stream>>>(
      x, C * L, ln_in_w, ln_in_b, inproj_w, inproj_b, xp, 128, 256);
  // 2) stats of xp[:,:128]; 3) tiled dwconv (mamba w/ LN, res plain)
  k_pixstats<<<pixB, TPB, 0, stream>>>(xp, 2 * C * L, C, 1e-6f, st1m, st1r);
  k_dwconv_t<<<dim3(HH / 4, C, 2 * B_SZ), TPB, 0, stream>>>(
      xp, st1m, st1r, ln_m_w, ln_m_b, convm_w, convm_b, convr_w, convr_b, xm, xr);
  // 4) unc (+BN-acc zero), sort
  k_unc<<<pixB, TPB, 0, stream>>>(xm, unc, bnsum);
  k_sort<<<B_SZ, 1024, 0, stream>>>(unc, idx, inv);
  // 5) merged scan pipelines (u gathers via idx inline)
  k_convx_all<<<dim3(L / TPB, 10, 6), TPB, 0, stream>>>(
      xm, idx, xpf_w, xpf_b, xpb_w, xpb_b, xpu_w, xpu_b, xdblF, xdblU);
  k_bc_all<<<dim3(L / TPB, N, 6), TPB, 0, stream>>>(
      xdblF, xdblU, BmTF, CmTF, BmTU, CmTU);
  k_scan_all<<<512, 1024, 0, stream>>>(
      xdblF, xdblU, dtf_w, dtf_b, dtb_w, dtb_b, dtu_w, dtu_b,
      xm, idx, BmTF, CmTF, BmTU, CmTU,
      Alog_f, Alog_b, Alog_u, D_f, D_b, D_u, yf, yb, yus);
  // 6) epilogue
  k_unsort<<<elemB, TPB, 0, stream>>>(yus, inv, yu);
  k_gate1<16><<<dim3(L / TPB, 8, B_SZ), TPB, 0, stream>>>(
      yf, yb, ln_cat_w, ln_cat_b, yu, gate1_w, gate1_b, g1, st2m, st2r, bnsum);
  k_gate2_fuse<16><<<dim3(L / TPB, 8, B_SZ), TPB, 0, stream>>>(
      g1, bnsum, bn_g, bn_b, gate2_w, gate2_b, yu, yf, yb, st2m, st2r,
      ln_cat_w, ln_cat_b, fused);
  k_conv1x1_cat2<16><<<dim3(L / TPB, 8, B_SZ), TPB, 0, stream>>>(
      fused, xr, outproj_w, outproj_b, outp, 128);
  k_ln_cf<<<pixB, TPB, 0, stream>>>(outp, outln_w, outln_b, (float*)d_out);
}

// Round 8
// 389.145 us; speedup vs baseline: 1.5761x; 1.0818x over previous
//
#include <hip/hip_runtime.h>
#include <cstdint>
#include <cstddef>

#define TPB 256

namespace {

constexpr int B_SZ = 2;
constexpr int C    = 128;
constexpr int HALF = 64;
constexpr int L    = 4096;   // 64*64
constexpr int N    = 16;
constexpr int HH   = 64;
constexpr int WW   = 64;

// fast-math versions (hardware v_exp_f32/v_log_f32); ~1e-7 rel err, fine at 9.7e-2 abs threshold
__device__ __forceinline__ float softplusf(float x) {
  return fmaxf(x, 0.f) + __logf(1.f + __expf(-fabsf(x)));
}
__device__ __forceinline__ float sigm(float x) { return 1.f / (1.f + __expf(-x)); }

// ---------- per-pixel channel stats (mean, rsqrt(var+eps)) ----------
__global__ void k_pixstats(const float* __restrict__ X, int bsX, int Cn, float eps,
                           float* __restrict__ mean, float* __restrict__ rinv) {
  const int lp = threadIdx.x & 63;
  const int wv = threadIdx.x >> 6;
  const int p  = blockIdx.x * 64 + lp;
  const int b = p / L, l = p % L;
  const int Cq = Cn >> 2;
  const float* Xp = X + (size_t)b * bsX + l;
  float s = 0.f, s2 = 0.f;
#pragma unroll 8
  for (int i = 0; i < Cq; ++i) {
    float v = Xp[(size_t)(wv * Cq + i) * L];
    s += v; s2 += v * v;
  }
  __shared__ float r1[4][64], r2[4][64];
  r1[wv][lp] = s; r2[wv][lp] = s2;
  __syncthreads();
  if (wv == 0) {
    float st  = r1[0][lp] + r1[1][lp] + r1[2][lp] + r1[3][lp];
    float s2t = r2[0][lp] + r2[1][lp] + r2[2][lp] + r2[3][lp];
    float m = st / Cn;
    float var = s2t / Cn - m * m;
    mean[p] = m;
    rinv[p] = rsqrtf(var + eps);
  }
}

// ---------- inproj: 1x1 conv with INLINE per-pixel LN ----------
template <int O_PB>
__global__ void k_conv_ln(const float* __restrict__ X, int bsX,
                          const float* __restrict__ lnw, const float* __restrict__ lnb,
                          const float* __restrict__ W, const float* __restrict__ bias,
                          float* __restrict__ Y, int I, int O) {
  __shared__ float Wl[O_PB * 128];
  __shared__ float aw[128], ab[128];
  const int o0 = blockIdx.y * O_PB;
  const int b  = blockIdx.z;
  for (int t = threadIdx.x; t < O_PB * I; t += TPB) {
    int i = t / O_PB, k = t % O_PB;
    Wl[t] = W[(size_t)(o0 + k) * I + i];
  }
  for (int t = threadIdx.x; t < I; t += TPB) { aw[t] = lnw[t]; ab[t] = lnb[t]; }
  __syncthreads();
  const int l0 = blockIdx.x * (2 * TPB) + threadIdx.x;
  const int l1 = l0 + TPB;
  const float* X0 = X + (size_t)b * bsX + l0;
  const float* X1 = X + (size_t)b * bsX + l1;
  float s0 = 0.f, q0 = 0.f, s1 = 0.f, q1 = 0.f;
#pragma unroll 8
  for (int i = 0; i < I; ++i) {
    float v0 = X0[(size_t)i * L], v1 = X1[(size_t)i * L];
    s0 += v0; q0 += v0 * v0; s1 += v1; q1 += v1 * v1;
  }
  const float m0 = s0 / I, m1 = s1 / I;
  const float r0 = rsqrtf(q0 / I - m0 * m0 + 1e-6f);
  const float r1 = rsqrtf(q1 / I - m1 * m1 + 1e-6f);
  float acc0[O_PB], acc1[O_PB];
#pragma unroll
  for (int k = 0; k < O_PB; ++k) { acc0[k] = bias[o0 + k]; acc1[k] = acc0[k]; }
#pragma unroll 4
  for (int i = 0; i < I; ++i) {
    float xv0 = (X0[(size_t)i * L] - m0) * r0 * aw[i] + ab[i];
    float xv1 = (X1[(size_t)i * L] - m1) * r1 * aw[i] + ab[i];
#pragma unroll
    for (int k = 0; k < O_PB; ++k) {
      acc0[k] += Wl[i * O_PB + k] * xv0;
      acc1[k] += Wl[i * O_PB + k] * xv1;
    }
  }
#pragma unroll
  for (int k = 0; k < O_PB; ++k) {
    Y[((size_t)b * O + o0 + k) * L + l0] = acc0[k];
    Y[((size_t)b * O + o0 + k) * L + l1] = acc1[k];
  }
}

// ---------- depthwise 3x3 + SiLU via LDS halo tile; mode0 LN on staging ----------
__global__ void k_dwconv_t(const float* __restrict__ xp,
                           const float* __restrict__ mean1, const float* __restrict__ rinv1,
                           const float* __restrict__ lnw, const float* __restrict__ lnb,
                           const float* __restrict__ Wm, const float* __restrict__ bm,
                           const float* __restrict__ Wr, const float* __restrict__ br,
                           float* __restrict__ xm, float* __restrict__ xr) {
  const int c = blockIdx.y;
  const int z = blockIdx.z;
  const int b = z & 1, mode = z >> 1;     // 0: mamba (LN), 1: res
  const int h0 = blockIdx.x * 4;
  __shared__ float T[6][66];
  const float* Xc = xp + ((size_t)b * 2 * C + (mode ? C + c : c)) * L;
  const float lw = mode ? 0.f : lnw[c];
  const float lb2 = mode ? 0.f : lnb[c];
  for (int t = threadIdx.x; t < 6 * 66; t += TPB) {
    int r = t / 66, cc = t % 66 - 1;
    int hh = h0 - 1 + r;
    float v = 0.f;
    if (hh >= 0 && hh < HH && cc >= 0 && cc < WW) {
      int li = hh * WW + cc;
      v = Xc[li];
      if (mode == 0) v = (v - mean1[b * L + li]) * rinv1[b * L + li] * lw + lb2;
    }
    T[r][t % 66] = v;
  }
  __syncthreads();
  const int hl = threadIdx.x >> 6, w = threadIdx.x & 63;
  const float* W9 = (mode ? Wr : Wm) + c * 9;
  float acc = mode ? br[c] : bm[c];
#pragma unroll
  for (int kh = 0; kh < 3; ++kh)
#pragma unroll
    for (int kw = 0; kw < 3; ++kw)
      acc += T[hl + kh][w + kw] * W9[kh * 3 + kw];
  const int l = (h0 + hl) * WW + w;
  float* Yp = mode ? xr : xm;
  Yp[((size_t)b * C + c) * L + l] = acc * sigm(acc);
}

// ---------- uncertainty per pixel (+ zero the BN accumulator) ----------
__global__ void k_unc(const float* __restrict__ xm, float* __restrict__ unc,
                      float* __restrict__ bnsum) {
  if (blockIdx.x == 0) bnsum[threadIdx.x] = 0.f;   // 256 floats
  const int lp = threadIdx.x & 63;
  const int wv = threadIdx.x >> 6;
  const int p  = blockIdx.x * 64 + lp;
  const int b = p / L, l = p % L;
  const float* Xp = xm + (size_t)b * C * L + l;
  float s = 0.f;
#pragma unroll 8
  for (int i = 0; i < 32; ++i) s += Xp[(size_t)(wv * 32 + i) * L];
  __shared__ float r1[4][64];
  r1[wv][lp] = s;
  __syncthreads();
  if (wv == 0) {
    float st = r1[0][lp] + r1[1][lp] + r1[2][lp] + r1[3][lp];
    float sg = sigm(st / C);
    unc[p] = -(sg * __logf(sg + 1e-6f));
  }
}

// ---------- stable argsort(-unc): register/shfl bitonic ----------
__global__ void k_sort(const float* __restrict__ unc, int* __restrict__ idx,
                       int* __restrict__ inv) {
  __shared__ unsigned long long S[L];
  const int b = blockIdx.x;
  const int tid = threadIdx.x;
  const int e0 = tid * 4;
  unsigned long long v[4];
  {
    float4 u4 = ((const float4*)(unc + b * L))[tid];
    float uv[4] = {u4.x, u4.y, u4.z, u4.w};
#pragma unroll
    for (int r = 0; r < 4; ++r) {
      unsigned u = __float_as_uint(uv[r]);
      u = (u & 0x80000000u) ? ~u : (u | 0x80000000u);
      v[r] = ((unsigned long long)(~u) << 32) | (unsigned)(e0 + r);
    }
  }
  for (int k = 2; k <= 256; k <<= 1) {
    for (int j = k >> 1; j > 0; j >>= 1) {
      if (j >= 4) {
        int m = j >> 2;
#pragma unroll
        for (int r = 0; r < 4; ++r) {
          unsigned long long p = __shfl_xor(v[r], m);
          int e = e0 + r;
          bool keepmin = (((e & k) == 0) == ((e & j) == 0));
          v[r] = keepmin ? (v[r] < p ? v[r] : p) : (v[r] > p ? v[r] : p);
        }
      } else {
#pragma unroll
        for (int r = 0; r < 4; ++r) {
          int rp = r ^ j;
          if (rp > r) {
            int e = e0 + r;
            bool up = ((e & k) == 0);
            unsigned long long a = v[r], bb = v[rp];
            if ((a > bb) == up) { v[r] = bb; v[rp] = a; }
          }
        }
      }
    }
  }
#pragma unroll
  for (int r = 0; r < 4; ++r) S[e0 + r] = v[r];
  __syncthreads();
  for (int k = 512; k <= L; k <<= 1) {
    for (int j = k >> 1; j >= 256; j >>= 1) {
      for (int q = tid; q < L / 2; q += 1024) {
        int i = ((q & ~(j - 1)) << 1) | (q & (j - 1));
        int ixj = i | j;
        unsigned long long a = S[i], bb = S[ixj];
        bool up = ((i & k) == 0);
        if ((a > bb) == up) { S[i] = bb; S[ixj] = a; }
      }
      __syncthreads();
    }
#pragma unroll
    for (int r = 0; r < 4; ++r) v[r] = S[e0 + r];
    const bool up = ((e0 & k) == 0);
    for (int j = 128; j >= 4; j >>= 1) {
      int m = j >> 2;
#pragma unroll
      for (int r = 0; r < 4; ++r) {
        unsigned long long p = __shfl_xor(v[r], m);
        int e = e0 + r;
        bool keepmin = (up == ((e & j) == 0));
        v[r] = keepmin ? (v[r] < p ? v[r] : p) : (v[r] > p ? v[r] : p);
      }
    }
#pragma unroll
    for (int j = 2; j > 0; j >>= 1) {
#pragma unroll
      for (int r = 0; r < 4; ++r) {
        int rp = r ^ j;
        if (rp > r) {
          unsigned long long a = v[r], bb = v[rp];
          if ((a > bb) == up) { v[r] = bb; v[rp] = a; }
        }
      }
    }
#pragma unroll
    for (int r = 0; r < 4; ++r) S[e0 + r] = v[r];
    __syncthreads();
  }
  for (int i = tid; i < L; i += 1024) {
    int orig = (int)(S[i] & 0xffffffffu);
    idx[b * L + i] = orig;
    inv[b * L + orig] = i;
  }
}

// ---------- gather / unsort ----------
__global__ void k_gather(const float* __restrict__ xm, const int* __restrict__ idx,
                         float* __restrict__ xs) {
  int t = blockIdx.x * TPB + threadIdx.x;
  int k = t % L, c = (t / L) % C, b = t / (C * L);
  xs[t] = xm[((size_t)b * C + c) * L + idx[b * L + k]];
}

__global__ void k_unsort(const float* __restrict__ yus, const int* __restrict__ inv,
                         float* __restrict__ yu) {
  int t = blockIdx.x * TPB + threadIdx.x;
  int l = t % L, c = (t / L) % C, b = t / (C * L);
  yu[t] = yus[((size_t)b * C + c) * L + inv[b * L + l]];
}

// ---------- merged x-projection conv: z 0..3 = f/b dirs, z 4..5 = u (reads xs) ----------
__global__ void k_convx_all(const float* __restrict__ xm, const float* __restrict__ xs,
                            const float* __restrict__ Wf, const float* __restrict__ bf,
                            const float* __restrict__ Wb, const float* __restrict__ bb,
                            const float* __restrict__ Wu, const float* __restrict__ bu,
                            float* __restrict__ XDF, float* __restrict__ XDU) {
  const int z = blockIdx.z;
  const bool isU = z >= 4;
  const int I = isU ? 128 : 64;
  const int O = isU ? 40 : 36;
  const int o0 = blockIdx.y * 4;
  if (o0 >= O) return;                 // block-uniform
  int b, dir;
  const float *W, *bi;
  if (!isU) { dir = z >> 1; b = z & 1; W = dir ? Wb : Wf; bi = dir ? bb : bf; }
  else      { dir = 0; b = z - 4; W = Wu; bi = bu; }
  __shared__ float Wl[4 * 128];
  for (int t = threadIdx.x; t < 4 * I; t += TPB) {
    int i = t / 4, k = t % 4;
    Wl[t] = W[(size_t)(o0 + k) * I + i];
  }
  __syncthreads();
  const int l = blockIdx.x * TPB + threadIdx.x;
  const int ls = isU ? l : (dir ? (L - 1 - l) : l);
  const float* Xb = isU ? (xs + (size_t)b * C * L)
                        : (xm + ((size_t)b * C + dir * HALF) * L);
  float acc[4];
#pragma unroll
  for (int k = 0; k < 4; ++k) acc[k] = bi[o0 + k];
#pragma unroll 4
  for (int i = 0; i < I; ++i) {
    float xv = Xb[(size_t)i * L + ls];
#pragma unroll
    for (int k = 0; k < 4; ++k) acc[k] += Wl[i * 4 + k] * xv;
  }
  float* yp = isU ? (XDU + ((size_t)b * L + l) * 40 + o0)
                  : (XDF + ((size_t)z * L + l) * 36 + o0);
#pragma unroll
  for (int k = 0; k < 4; ++k) yp[k] = acc[k];
}

// ---------- merged B/C scrambled transpose ----------
__global__ void k_bc_all(const float* __restrict__ xdblF, const float* __restrict__ xdblU,
                         float* __restrict__ BmTF, float* __restrict__ CmTF,
                         float* __restrict__ BmTU, float* __restrict__ CmTU) {
  const int z = blockIdx.z;
  const bool isU = z >= 4;
  const int RT = isU ? 8 : 4, OT = isU ? 40 : 36;
  const float* src = isU ? (xdblU + (size_t)(z - 4) * L * 40)
                         : (xdblF + (size_t)z * L * 36);
  float* BT = isU ? (BmTU + (size_t)(z - 4) * L * N) : (BmTF + (size_t)z * L * N);
  float* CT = isU ? (CmTU + (size_t)(z - 4) * L * N) : (CmTF + (size_t)z * L * N);
  const int n = blockIdx.y;
  const int l2 = blockIdx.x * TPB + threadIdx.x;
  int f2 = n * L + l2;
  int lb = f2 >> 4, cb = f2 & 15;
  const float* xr2 = src + (size_t)lb * OT + RT + cb;
  size_t ob = (size_t)l2 * N + n;
  BT[ob] = xr2[0];
  CT[ob] = xr2[N];
}

// ---------- merged fused selective scan (512 blocks: 256 F rows + 256 U rows) ----------
__global__ __launch_bounds__(1024) void
k_scan_all(const float* __restrict__ xdblF, const float* __restrict__ xdblU,
           const float* __restrict__ dtf_w, const float* __restrict__ dtf_b,
           const float* __restrict__ dtb_w, const float* __restrict__ dtb_b,
           const float* __restrict__ dtu_w, const float* __restrict__ dtu_b,
           const float* __restrict__ xm, const float* __restrict__ xs,
           const float* __restrict__ BmTF, const float* __restrict__ CmTF,
           const float* __restrict__ BmTU, const float* __restrict__ CmTU,
           const float* __restrict__ Alog_f, const float* __restrict__ Alog_b,
           const float* __restrict__ Alog_u,
           const float* __restrict__ D_f, const float* __restrict__ D_b,
           const float* __restrict__ D_u,
           float* __restrict__ yf, float* __restrict__ yb, float* __restrict__ yus) {
  const int blk = blockIdx.x;
  const int tid = threadIdx.x;
  const bool isU = blk >= 256;
  int CsT, RT, c, b, dir;
  const float *Wdt, *bdt, *Alog, *Dv, *xdbl, *BT, *CT, *Ub;
  float* Y;
  int OT;
  if (!isU) {
    CsT = 64; RT = 4; OT = 36;
    int zb = blk >> 6; c = blk & 63; dir = zb >> 1; b = zb & 1;
    Wdt = dir ? dtb_w : dtf_w; bdt = dir ? dtb_b : dtf_b;
    Alog = dir ? Alog_b : Alog_f; Dv = dir ? D_b : D_f;
    xdbl = xdblF + (size_t)zb * L * 36;
    BT = BmTF + (size_t)zb * L * N; CT = CmTF + (size_t)zb * L * N;
    Ub = xm + ((size_t)b * C + dir * HALF + c) * L;
    Y = (dir ? yb : yf) + ((size_t)b * HALF + c) * L;
  } else {
    CsT = 128; RT = 8; OT = 40;
    int blk2 = blk - 256; b = blk2 >> 7; c = blk2 & 127; dir = 0;
    Wdt = dtu_w; bdt = dtu_b; Alog = Alog_u; Dv = D_u;
    xdbl = xdblU + (size_t)b * L * 40;
    BT = BmTU + (size_t)b * L * N; CT = CmTU + (size_t)b * L * N;
    Ub = xs + ((size_t)b * C + c) * L;
    Y = yus + ((size_t)b * C + c) * L;
  }
  __shared__ float sW[1024];          // TRANSPOSED: sW[r*CsT + csrc]
  __shared__ float sb2[128];
  __shared__ float dtL[64][65];
  __shared__ float uL[64][65];
  __shared__ float sA[N][65], sH[N][65];
  for (int t = tid; t < CsT * RT; t += 1024) {
    int csrc = t / RT, r = t % RT;
    sW[r * CsT + csrc] = Wdt[t];
  }
  for (int t = tid; t < CsT; t += 1024) sb2[t] = bdt[t];
  __syncthreads();
  // ---- stage 1: dt + u into LDS ----
  {
    const int chunk_d = tid >> 4;
    const int sq = (tid & 15) * 4;
    const int lsrc = isU ? (c * 32 + (chunk_d >> 1)) : (c * 64 + chunk_d);
    const float* xrp = xdbl + (size_t)lsrc * OT;
    float xr[8];
    for (int r = 0; r < RT; ++r) xr[r] = xrp[r];
    const float bcc = sb2[c];
#pragma unroll
    for (int j = 0; j < 4; ++j) {
      int s = sq + j;
      int csrc = isU ? (((chunk_d & 1) << 6) + s) : s;
      float acc = sb2[csrc] + bcc;
      for (int r = 0; r < RT; ++r) acc += sW[r * CsT + csrc] * xr[r];
      int l = (chunk_d << 6) + s;
      dtL[chunk_d][s] = softplusf(acc);
      uL[chunk_d][s] = Ub[isU ? l : (dir ? (L - 1 - l) : l)];
    }
  }
  __syncthreads();
  const int n = tid & 15;
  const int chunk = tid >> 4;
  const float a = -__expf(Alog[c * N + n]);
  const float* bp = BT + ((size_t)(chunk << 6)) * N + n;
  const float* cp = CT + ((size_t)(chunk << 6)) * N + n;
  // phase A
  float ap = 1.f, h = 0.f;
#pragma unroll 4
  for (int s = 0; s < 64; ++s) {
    float d = dtL[chunk][s];
    float uv = uL[chunk][s];
    float bn = bp[(size_t)s * N];
    float dA = __expf(d * a);
    ap *= dA;
    h = h * dA + d * uv * bn;
  }
  sA[n][chunk] = ap; sH[n][chunk] = h;
  __syncthreads();
  // phase B: wave-parallel cross-chunk exclusive scan (wave w owns n=w)
  {
    const int w = tid >> 6;
    const int k = tid & 63;
    float A = sA[w][k];
    float Bv = sH[w][k];
#pragma unroll
    for (int j = 1; j < 64; j <<= 1) {
      float pa = __shfl_up(A, j);
      float pb = __shfl_up(Bv, j);
      if (k >= j) { Bv = pb * A + Bv; A = pa * A; }
    }
    float hprev = __shfl_up(Bv, 1);
    sH[w][k] = (k == 0) ? 0.f : hprev;
  }
  __syncthreads();
  h = sH[n][chunk];
  // phase C
  const float Dc = Dv[c];
  float ybuf[4];
#pragma unroll 4
  for (int s = 0; s < 64; ++s) {
    float d = dtL[chunk][s];
    float uv = uL[chunk][s];
    float bn = bp[(size_t)s * N];
    float cn = cp[(size_t)s * N];
    float dA = __expf(d * a);
    h = h * dA + d * uv * bn;
    float p = h * cn;
    p += __shfl_xor(p, 1);
    p += __shfl_xor(p, 2);
    p += __shfl_xor(p, 4);
    p += __shfl_xor(p, 8);
    if ((s & 15) == n) ybuf[s >> 4] = p + uv * Dc;
  }
  float* Yp = Y + (chunk << 6);
#pragma unroll
  for (int q = 0; q < 4; ++q) Yp[16 * q + n] = ybuf[q];
}

// ---------- gate1: inline cat-LN stats + conv + BN partial sums ----------
template <int O_PB>
__global__ void k_gate1(const float* __restrict__ yf, const float* __restrict__ yb,
                        const float* __restrict__ lncw, const float* __restrict__ lncb,
                        const float* __restrict__ yu,
                        const float* __restrict__ W, const float* __restrict__ bias,
                        float* __restrict__ g1,
                        float* __restrict__ st2m, float* __restrict__ st2r,
                        float* __restrict__ bnsum) {
  __shared__ float Wl[O_PB * 256];
  __shared__ float cw[128], cb2[128];
  __shared__ float part[2][O_PB][4];
  const int o0 = blockIdx.y * O_PB;
  const int b  = blockIdx.z;
  for (int t = threadIdx.x; t < O_PB * 256; t += TPB) {
    int i = t / O_PB, k = t % O_PB;
    Wl[t] = W[(size_t)(o0 + k) * 256 + i];
  }
  for (int t = threadIdx.x; t < 128; t += TPB) { cw[t] = lncw[t]; cb2[t] = lncb[t]; }
  __syncthreads();
  const int l = blockIdx.x * TPB + threadIdx.x;
  const float* f0 = yf + (size_t)b * HALF * L + l;
  const float* b0 = yb + (size_t)b * HALF * L + (L - 1 - l);
  const float* u0 = yu + (size_t)b * C * L + l;
  float s = 0.f, s2 = 0.f;
#pragma unroll 8
  for (int i = 0; i < 64; ++i) { float v = f0[(size_t)i * L]; s += v; s2 += v * v; }
#pragma unroll 8
  for (int i = 0; i < 64; ++i) { float v = b0[(size_t)i * L]; s += v; s2 += v * v; }
  const float m = s / C;
  const float r = rsqrtf(s2 / C - m * m + 1e-6f);
  if (blockIdx.y == 0) { st2m[b * L + l] = m; st2r[b * L + l] = r; }
  float acc[O_PB];
#pragma unroll
  for (int k = 0; k < O_PB; ++k) acc[k] = bias[o0 + k];
#pragma unroll 4
  for (int i = 0; i < 64; ++i) {
    float cv = (f0[(size_t)i * L] - m) * r * cw[i] + cb2[i];
#pragma unroll
    for (int k = 0; k < O_PB; ++k) acc[k] += Wl[i * O_PB + k] * cv;
  }
#pragma unroll 4
  for (int i = 0; i < 64; ++i) {
    float cv = (b0[(size_t)i * L] - m) * r * cw[64 + i] + cb2[64 + i];
#pragma unroll
    for (int k = 0; k < O_PB; ++k) acc[k] += Wl[(64 + i) * O_PB + k] * cv;
  }
#pragma unroll 4
  for (int i = 0; i < 128; ++i) {
    float xv = u0[(size_t)i * L];
#pragma unroll
    for (int k = 0; k < O_PB; ++k) acc[k] += Wl[(128 + i) * O_PB + k] * xv;
  }
#pragma unroll
  for (int k = 0; k < O_PB; ++k)
    g1[((size_t)b * C + o0 + k) * L + l] = acc[k];
  const int wv = threadIdx.x >> 6, lnn = threadIdx.x & 63;
#pragma unroll
  for (int k = 0; k < O_PB; ++k) {
    float v = acc[k];
    v += __shfl_xor(v, 1);  v += __shfl_xor(v, 2);  v += __shfl_xor(v, 4);
    v += __shfl_xor(v, 8);  v += __shfl_xor(v, 16); v += __shfl_xor(v, 32);
    if (lnn == 0) part[0][k][wv] = v;
    float q = acc[k] * acc[k];
    q += __shfl_xor(q, 1);  q += __shfl_xor(q, 2);  q += __shfl_xor(q, 4);
    q += __shfl_xor(q, 8);  q += __shfl_xor(q, 16); q += __shfl_xor(q, 32);
    if (lnn == 0) part[1][k][wv] = q;
  }
  __syncthreads();
  if (threadIdx.x < 2 * O_PB) {
    int which = threadIdx.x >= O_PB, k = threadIdx.x % O_PB;
    float v = part[which][k][0] + part[which][k][1] + part[which][k][2] + part[which][k][3];
    atomicAdd(&bnsum[which * 128 + o0 + k], v);
  }
}

// ---------- gate2: BN(from sums)+relu on loads; epilogue sigmoid+fuse ----------
template <int O_PB>
__global__ void k_gate2_fuse(const float* __restrict__ g1,
                             const float* __restrict__ bnsum,
                             const float* __restrict__ bn_g, const float* __restrict__ bn_b,
                             const float* __restrict__ W, const float* __restrict__ bias,
                             const float* __restrict__ yu,
                             const float* __restrict__ yf, const float* __restrict__ yb,
                             const float* __restrict__ mean2, const float* __restrict__ rinv2,
                             const float* __restrict__ lncw, const float* __restrict__ lncb,
                             float* __restrict__ fused) {
  __shared__ float Wl[O_PB * 128];
  __shared__ float sc[128], sh[128];
  __shared__ float cwo[O_PB], cbo[O_PB];
  const int o0 = blockIdx.y * O_PB;
  const int b  = blockIdx.z;
  for (int t = threadIdx.x; t < O_PB * 128; t += TPB) {
    int i = t / O_PB, k = t % O_PB;
    Wl[t] = W[(size_t)(o0 + k) * 128 + i];
  }
  for (int t = threadIdx.x; t < 128; t += TPB) {
    float sv = bnsum[t], qv = bnsum[128 + t];
    float mean = sv / (B_SZ * L);
    float var  = qv / (B_SZ * L) - mean * mean;
    float scv = bn_g[t] * rsqrtf(var + 1e-5f);
    sc[t] = scv;
    sh[t] = bn_b[t] - mean * scv;
  }
  if (threadIdx.x < O_PB) {
    cwo[threadIdx.x] = lncw[o0 + threadIdx.x];
    cbo[threadIdx.x] = lncb[o0 + threadIdx.x];
  }
  __syncthreads();
  const int l = blockIdx.x * TPB + threadIdx.x;
  const float m = mean2[b * L + l], r = rinv2[b * L + l];
  const float* Xb = g1 + (size_t)b * C * L + l;
  float acc[O_PB];
#pragma unroll
  for (int k = 0; k < O_PB; ++k) acc[k] = bias[o0 + k];
#pragma unroll 4
  for (int i = 0; i < 128; ++i) {
    float v = fmaxf(Xb[(size_t)i * L] * sc[i] + sh[i], 0.f);
#pragma unroll
    for (int k = 0; k < O_PB; ++k) acc[k] += Wl[i * O_PB + k] * v;
  }
#pragma unroll
  for (int k = 0; k < O_PB; ++k) {
    int o = o0 + k;
    float g = sigm(acc[k]);
    float yuv = yu[((size_t)b * C + o) * L + l];
    float yv = (o < 64) ? yf[((size_t)b * HALF + o) * L + l]
                        : yb[((size_t)b * HALF + (o - 64)) * L + (L - 1 - l)];
    float cv = (yv - m) * r * cwo[k] + cbo[k];
    fused[((size_t)b * C + o) * L + l] = g * yuv + (1.f - g) * cv;
  }
}

// ---------- outproj: 1x1 conv over concat([fused, xr]) ----------
template <int O_PB>
__global__ void k_conv1x1_cat2(const float* __restrict__ X1, const float* __restrict__ X2,
                               const float* __restrict__ W, const float* __restrict__ bias,
                               float* __restrict__ Y, int O) {
  __shared__ float Wl[O_PB * 256];
  const int o0 = blockIdx.y * O_PB;
  const int b  = blockIdx.z;
  for (int t = threadIdx.x; t < O_PB * 256; t += TPB) {
    int i = t / O_PB, k = t % O_PB;
    Wl[t] = W[(size_t)(o0 + k) * 256 + i];
  }
  __syncthreads();
  const int l = blockIdx.x * TPB + threadIdx.x;
  const float* Xb1 = X1 + (size_t)b * C * L + l;
  const float* Xb2 = X2 + (size_t)b * C * L + l;
  float acc[O_PB];
#pragma unroll
  for (int k = 0; k < O_PB; ++k) acc[k] = bias[o0 + k];
#pragma unroll 4
  for (int i = 0; i < 128; ++i) {
    float xv = Xb1[(size_t)i * L];
#pragma unroll
    for (int k = 0; k < O_PB; ++k) acc[k] += Wl[i * O_PB + k] * xv;
  }
#pragma unroll 4
  for (int i = 0; i < 128; ++i) {
    float xv = Xb2[(size_t)i * L];
#pragma unroll
    for (int k = 0; k < O_PB; ++k) acc[k] += Wl[(128 + i) * O_PB + k] * xv;
  }
#pragma unroll
  for (int k = 0; k < O_PB; ++k)
    Y[((size_t)b * O + o0 + k) * L + l] = acc[k];
}

// ---------- final channel LN ----------
__global__ void k_ln_cf(const float* __restrict__ X,
                        const float* __restrict__ w, const float* __restrict__ bchan,
                        float* __restrict__ Y) {
  const int lp = threadIdx.x & 63;
  const int wv = threadIdx.x >> 6;
  const int p  = blockIdx.x * 64 + lp;
  const int b = p / L, l = p % L;
  const float* Xp = X + (size_t)b * C * L + l;
  float s = 0.f, s2 = 0.f;
#pragma unroll 8
  for (int i = 0; i < 32; ++i) {
    float v = Xp[(size_t)(wv * 32 + i) * L];
    s += v; s2 += v * v;
  }
  __shared__ float r1[4][64], r2[4][64];
  r1[wv][lp] = s; r2[wv][lp] = s2;
  __syncthreads();
  float st  = r1[0][lp] + r1[1][lp] + r1[2][lp] + r1[3][lp];
  float s2t = r2[0][lp] + r2[1][lp] + r2[2][lp] + r2[3][lp];
  float mean = st / C;
  float rinv = rsqrtf(s2t / C - mean * mean + 1e-6f);
  float* Yp = Y + (size_t)b * C * L + l;
#pragma unroll 8
  for (int i = 0; i < 32; ++i) {
    int c = wv * 32 + i;
    float v = Xp[(size_t)c * L];
    Yp[(size_t)c * L] = w[c] * (v - mean) * rinv + bchan[c];
  }
}

} // namespace

extern "C" void kernel_launch(void* const* d_in, const int* in_sizes, int n_in,
                              void* d_out, int out_size, void* d_ws, size_t ws_size,
                              hipStream_t stream) {
  const float* x         = (const float*)d_in[0];
  const float* ln_in_w   = (const float*)d_in[1];
  const float* ln_in_b   = (const float*)d_in[2];
  const float* inproj_w  = (const float*)d_in[3];
  const float* inproj_b  = (const float*)d_in[4];
  const float* ln_m_w    = (const float*)d_in[5];
  const float* ln_m_b    = (const float*)d_in[6];
  const float* convm_w   = (const float*)d_in[7];
  const float* convm_b   = (const float*)d_in[8];
  const float* convr_w   = (const float*)d_in[9];
  const float* convr_b   = (const float*)d_in[10];
  const float* ln_cat_w  = (const float*)d_in[11];
  const float* ln_cat_b  = (const float*)d_in[12];
  const float* xpf_w     = (const float*)d_in[13];
  const float* xpf_b     = (const float*)d_in[14];
  const float* dtf_w     = (const float*)d_in[15];
  const float* dtf_b     = (const float*)d_in[16];
  const float* Alog_f    = (const float*)d_in[17];
  const float* D_f       = (const float*)d_in[18];
  const float* xpb_w     = (const float*)d_in[19];
  const float* xpb_b     = (const float*)d_in[20];
  const float* dtb_w     = (const float*)d_in[21];
  const float* dtb_b     = (const float*)d_in[22];
  const float* Alog_b    = (const float*)d_in[23];
  const float* D_b       = (const float*)d_in[24];
  const float* xpu_w     = (const float*)d_in[25];
  const float* xpu_b     = (const float*)d_in[26];
  const float* dtu_w     = (const float*)d_in[27];
  const float* dtu_b     = (const float*)d_in[28];
  const float* Alog_u    = (const float*)d_in[29];
  const float* D_u       = (const float*)d_in[30];
  const float* gate1_w   = (const float*)d_in[31];
  const float* gate1_b   = (const float*)d_in[32];
  const float* bn_g      = (const float*)d_in[33];
  const float* bn_b      = (const float*)d_in[34];
  const float* gate2_w   = (const float*)d_in[35];
  const float* gate2_b   = (const float*)d_in[36];
  const float* outproj_w = (const float*)d_in[37];
  const float* outproj_b = (const float*)d_in[38];
  const float* outln_w   = (const float*)d_in[39];
  const float* outln_b   = (const float*)d_in[40];

  float* ws = (float*)d_ws;
  size_t off = 0;
  auto alloc = [&](size_t n) { float* p = ws + off; off += n; return p; };

  const size_t BL = (size_t)B_SZ * L;
  float* xp    = alloc((size_t)B_SZ * 2 * C * L);
  float* st1m  = alloc(BL);
  float* st1r  = alloc(BL);
  float* xm    = alloc((size_t)B_SZ * C * L);
  float* xr    = alloc((size_t)B_SZ * C * L);
  float* unc   = alloc(BL);
  int*   idx   = (int*)alloc(BL);
  int*   inv   = (int*)alloc(BL);
  float* xs    = alloc((size_t)B_SZ * C * L);
  float* xdblF = alloc((size_t)4 * L * 36);
  float* BmTF  = alloc((size_t)4 * L * N);
  float* CmTF  = alloc((size_t)4 * L * N);
  float* xdblU = alloc((size_t)2 * L * 40);
  float* BmTU  = alloc((size_t)2 * L * N);
  float* CmTU  = alloc((size_t)2 * L * N);
  float* yf    = alloc((size_t)B_SZ * HALF * L);
  float* yb    = alloc((size_t)B_SZ * HALF * L);
  float* yus   = alloc((size_t)B_SZ * C * L);
  float* yu    = alloc((size_t)B_SZ * C * L);
  float* st2m  = alloc(BL);
  float* st2r  = alloc(BL);
  float* g1    = alloc((size_t)B_SZ * C * L);
  float* bnsum = alloc(256);
  float* fused = alloc((size_t)B_SZ * C * L);
  float* outp  = alloc((size_t)B_SZ * C * L);
  (void)ws_size; (void)in_sizes; (void)n_in; (void)out_size;

  const int pixB = B_SZ * L / 64;          // 128 blocks (256 thr)
  const int elemB = B_SZ * C * L / TPB;    // 4096

  // 1) inproj with inline LN
  k_conv_ln<16><<<dim3(L / (2 * TPB), 16, B_SZ), TPB, 0, stream>>>(
      x, C * L, ln_in_w, ln_in_b, inproj_w, inproj_b, xp, 128, 256);
  // 2) stats of xp[:,:128]; 3) tiled dwconv
  k_pixstats<<<pixB, TPB, 0, stream>>>(xp, 2 * C * L, C, 1e-6f, st1m, st1r);
  k_dwconv_t<<<dim3(HH / 4, C, 2 * B_SZ), TPB, 0, stream>>>(
      xp, st1m, st1r, ln_m_w, ln_m_b, convm_w, convm_b, convr_w, convr_b, xm, xr);
  // 4) unc (+BN-acc zero), sort, gather
  k_unc<<<pixB, TPB, 0, stream>>>(xm, unc, bnsum);
  k_sort<<<B_SZ, 1024, 0, stream>>>(unc, idx, inv);
  k_gather<<<elemB, TPB, 0, stream>>>(xm, idx, xs);
  // 5) merged scan pipelines (U path reads coalesced xs)
  k_convx_all<<<dim3(L / TPB, 10, 6), TPB, 0, stream>>>(
      xm, xs, xpf_w, xpf_b, xpb_w, xpb_b, xpu_w, xpu_b, xdblF, xdblU);
  k_bc_all<<<dim3(L / TPB, N, 6), TPB, 0, stream>>>(
      xdblF, xdblU, BmTF, CmTF, BmTU, CmTU);
  k_scan_all<<<512, 1024, 0, stream>>>(
      xdblF, xdblU, dtf_w, dtf_b, dtb_w, dtb_b, dtu_w, dtu_b,
      xm, xs, BmTF, CmTF, BmTU, CmTU,
      Alog_f, Alog_b, Alog_u, D_f, D_b, D_u, yf, yb, yus);
  // 6) epilogue
  k_unsort<<<elemB, TPB, 0, stream>>>(yus, inv, yu);
  k_gate1<16><<<dim3(L / TPB, 8, B_SZ), TPB, 0, stream>>>(
      yf, yb, ln_cat_w, ln_cat_b, yu, gate1_w, gate1_b, g1, st2m, st2r, bnsum);
  k_gate2_fuse<16><<<dim3(L / TPB, 8, B_SZ), TPB, 0, stream>>>(
      g1, bnsum, bn_g, bn_b, gate2_w, gate2_b, yu, yf, yb, st2m, st2r,
      ln_cat_w, ln_cat_b, fused);
  k_conv1x1_cat2<16><<<dim3(L / TPB, 8, B_SZ), TPB, 0, stream>>>(
      fused, xr, outproj_w, outproj_b, outp, 128);
  k_ln_cf<<<pixB, TPB, 0, stream>>>(outp, outln_w, outln_b, (float*)d_out);
}

// Round 9
// 358.422 us; speedup vs baseline: 1.7111x; 1.0857x over previous
//
#include <hip/hip_runtime.h>
#include <cstdint>
#include <cstddef>

#define TPB 256

namespace {

constexpr int B_SZ = 2;
constexpr int C    = 128;
constexpr int HALF = 64;
constexpr int L    = 4096;   // 64*64
constexpr int N    = 16;
constexpr int HH   = 64;
constexpr int WW   = 64;

// fast-math (hardware v_exp_f32/v_log_f32); ~1e-7 rel err, fine at 9.7e-2 threshold
__device__ __forceinline__ float softplusf(float x) {
  return fmaxf(x, 0.f) + __logf(1.f + __expf(-fabsf(x)));
}
__device__ __forceinline__ float sigm(float x) { return 1.f / (1.f + __expf(-x)); }

__device__ __forceinline__ unsigned long long unc_key(float u, int i) {
  unsigned m = __float_as_uint(u);
  m = (m & 0x80000000u) ? ~m : (m | 0x80000000u);   // monotone ascending map
  return ((unsigned long long)(~m) << 32) | (unsigned)i;  // ascending = descending unc, stable
}

// ---------- per-pixel channel stats (mean, rsqrt(var+eps)) ----------
__global__ void k_pixstats(const float* __restrict__ X, int bsX, int Cn, float eps,
                           float* __restrict__ mean, float* __restrict__ rinv) {
  const int lp = threadIdx.x & 63;
  const int wv = threadIdx.x >> 6;
  const int p  = blockIdx.x * 64 + lp;
  const int b = p / L, l = p % L;
  const int Cq = Cn >> 2;
  const float* Xp = X + (size_t)b * bsX + l;
  float s = 0.f, s2 = 0.f;
#pragma unroll 8
  for (int i = 0; i < Cq; ++i) {
    float v = Xp[(size_t)(wv * Cq + i) * L];
    s += v; s2 += v * v;
  }
  __shared__ float r1[4][64], r2[4][64];
  r1[wv][lp] = s; r2[wv][lp] = s2;
  __syncthreads();
  if (wv == 0) {
    float st  = r1[0][lp] + r1[1][lp] + r1[2][lp] + r1[3][lp];
    float s2t = r2[0][lp] + r2[1][lp] + r2[2][lp] + r2[3][lp];
    float m = st / Cn;
    float var = s2t / Cn - m * m;
    mean[p] = m;
    rinv[p] = rsqrtf(var + eps);
  }
}

// ---------- inproj: 1x1 conv with INLINE per-pixel LN ----------
template <int O_PB>
__global__ void k_conv_ln(const float* __restrict__ X, int bsX,
                          const float* __restrict__ lnw, const float* __restrict__ lnb,
                          const float* __restrict__ W, const float* __restrict__ bias,
                          float* __restrict__ Y, int I, int O) {
  __shared__ float Wl[O_PB * 128];
  __shared__ float aw[128], ab[128];
  const int o0 = blockIdx.y * O_PB;
  const int b  = blockIdx.z;
  for (int t = threadIdx.x; t < O_PB * I; t += TPB) {
    int i = t / O_PB, k = t % O_PB;
    Wl[t] = W[(size_t)(o0 + k) * I + i];
  }
  for (int t = threadIdx.x; t < I; t += TPB) { aw[t] = lnw[t]; ab[t] = lnb[t]; }
  __syncthreads();
  const int l0 = blockIdx.x * (2 * TPB) + threadIdx.x;
  const int l1 = l0 + TPB;
  const float* X0 = X + (size_t)b * bsX + l0;
  const float* X1 = X + (size_t)b * bsX + l1;
  float s0 = 0.f, q0 = 0.f, s1 = 0.f, q1 = 0.f;
#pragma unroll 8
  for (int i = 0; i < I; ++i) {
    float v0 = X0[(size_t)i * L], v1 = X1[(size_t)i * L];
    s0 += v0; q0 += v0 * v0; s1 += v1; q1 += v1 * v1;
  }
  const float m0 = s0 / I, m1 = s1 / I;
  const float r0 = rsqrtf(q0 / I - m0 * m0 + 1e-6f);
  const float r1 = rsqrtf(q1 / I - m1 * m1 + 1e-6f);
  float acc0[O_PB], acc1[O_PB];
#pragma unroll
  for (int k = 0; k < O_PB; ++k) { acc0[k] = bias[o0 + k]; acc1[k] = acc0[k]; }
#pragma unroll 4
  for (int i = 0; i < I; ++i) {
    float xv0 = (X0[(size_t)i * L] - m0) * r0 * aw[i] + ab[i];
    float xv1 = (X1[(size_t)i * L] - m1) * r1 * aw[i] + ab[i];
#pragma unroll
    for (int k = 0; k < O_PB; ++k) {
      acc0[k] += Wl[i * O_PB + k] * xv0;
      acc1[k] += Wl[i * O_PB + k] * xv1;
    }
  }
#pragma unroll
  for (int k = 0; k < O_PB; ++k) {
    Y[((size_t)b * O + o0 + k) * L + l0] = acc0[k];
    Y[((size_t)b * O + o0 + k) * L + l1] = acc1[k];
  }
}

// ---------- depthwise 3x3 + SiLU via LDS halo tile; mode0 LN on staging ----------
__global__ void k_dwconv_t(const float* __restrict__ xp,
                           const float* __restrict__ mean1, const float* __restrict__ rinv1,
                           const float* __restrict__ lnw, const float* __restrict__ lnb,
                           const float* __restrict__ Wm, const float* __restrict__ bm,
                           const float* __restrict__ Wr, const float* __restrict__ br,
                           float* __restrict__ xm, float* __restrict__ xr) {
  const int c = blockIdx.y;
  const int z = blockIdx.z;
  const int b = z & 1, mode = z >> 1;     // 0: mamba (LN), 1: res
  const int h0 = blockIdx.x * 4;
  __shared__ float T[6][66];
  const float* Xc = xp + ((size_t)b * 2 * C + (mode ? C + c : c)) * L;
  const float lw = mode ? 0.f : lnw[c];
  const float lb2 = mode ? 0.f : lnb[c];
  for (int t = threadIdx.x; t < 6 * 66; t += TPB) {
    int r = t / 66, cc = t % 66 - 1;
    int hh = h0 - 1 + r;
    float v = 0.f;
    if (hh >= 0 && hh < HH && cc >= 0 && cc < WW) {
      int li = hh * WW + cc;
      v = Xc[li];
      if (mode == 0) v = (v - mean1[b * L + li]) * rinv1[b * L + li] * lw + lb2;
    }
    T[r][t % 66] = v;
  }
  __syncthreads();
  const int hl = threadIdx.x >> 6, w = threadIdx.x & 63;
  const float* W9 = (mode ? Wr : Wm) + c * 9;
  float acc = mode ? br[c] : bm[c];
#pragma unroll
  for (int kh = 0; kh < 3; ++kh)
#pragma unroll
    for (int kw = 0; kw < 3; ++kw)
      acc += T[hl + kh][w + kw] * W9[kh * 3 + kw];
  const int l = (h0 + hl) * WW + w;
  float* Yp = mode ? xr : xm;
  Yp[((size_t)b * C + c) * L + l] = acc * sigm(acc);
}

// ---------- uncertainty per pixel (+ zero BN accumulator and rank buffer) ----------
__global__ void k_unc(const float* __restrict__ xm, float* __restrict__ unc,
                      float* __restrict__ bnsum, int* __restrict__ rankbuf) {
  if (blockIdx.x == 0) bnsum[threadIdx.x] = 0.f;       // 256 floats
  const int gt = blockIdx.x * TPB + threadIdx.x;
  if (gt < B_SZ * L) rankbuf[gt] = 0;                  // 8192 ints
  const int lp = threadIdx.x & 63;
  const int wv = threadIdx.x >> 6;
  const int p  = blockIdx.x * 64 + lp;
  const int b = p / L, l = p % L;
  const float* Xp = xm + (size_t)b * C * L + l;
  float s = 0.f;
#pragma unroll 8
  for (int i = 0; i < 32; ++i) s += Xp[(size_t)(wv * 32 + i) * L];
  __shared__ float r1[4][64];
  r1[wv][lp] = s;
  __syncthreads();
  if (wv == 0) {
    float st = r1[0][lp] + r1[1][lp] + r1[2][lp] + r1[3][lp];
    float sg = sigm(st / C);
    unc[p] = -(sg * __logf(sg + 1e-6f));
  }
}

// ---------- stable rank of descending unc: rank_i = #{j: ckey_j < ckey_i} ----------
// grid (L/TPB, NJ=8, B); each block counts its 512-key j-chunk vs 256 i's.
__global__ void k_rank(const float* __restrict__ unc, int* __restrict__ rankbuf) {
  constexpr int JC = 512;
  __shared__ unsigned long long K[JC];
  const int b  = blockIdx.z;
  const int j0 = blockIdx.y * JC;
  const int i  = blockIdx.x * TPB + threadIdx.x;
  for (int t = threadIdx.x; t < JC; t += TPB)
    K[t] = unc_key(unc[b * L + j0 + t], j0 + t);
  __syncthreads();
  const unsigned long long my = unc_key(unc[b * L + i], i);
  int cnt = 0;
#pragma unroll 8
  for (int j = 0; j < JC; ++j) cnt += (K[j] < my) ? 1 : 0;
  atomicAdd(&rankbuf[b * L + i], cnt);
}

// ---------- scatter-gather: xs[b,c,rank_l] = xm[b,c,l]; inv[b,l] = rank_l ----------
__global__ void k_scatgath(const float* __restrict__ xm, const int* __restrict__ rankbuf,
                           float* __restrict__ xs, int* __restrict__ inv) {
  int t = blockIdx.x * TPB + threadIdx.x;
  int l = t % L, c = (t / L) % C, b = t / (C * L);
  int r = rankbuf[b * L + l];
  xs[((size_t)b * C + c) * L + r] = xm[t];
  if (c == 0) inv[b * L + l] = r;
}

// ---------- unsort ----------
__global__ void k_unsort(const float* __restrict__ yus, const int* __restrict__ inv,
                         float* __restrict__ yu) {
  int t = blockIdx.x * TPB + threadIdx.x;
  int l = t % L, c = (t / L) % C, b = t / (C * L);
  yu[t] = yus[((size_t)b * C + c) * L + inv[b * L + l]];
}

// ---------- merged x-projection conv: z 0..3 = f/b dirs, z 4..5 = u (reads xs) ----------
__global__ void k_convx_all(const float* __restrict__ xm, const float* __restrict__ xs,
                            const float* __restrict__ Wf, const float* __restrict__ bf,
                            const float* __restrict__ Wb, const float* __restrict__ bb,
                            const float* __restrict__ Wu, const float* __restrict__ bu,
                            float* __restrict__ XDF, float* __restrict__ XDU) {
  const int z = blockIdx.z;
  const bool isU = z >= 4;
  const int I = isU ? 128 : 64;
  const int O = isU ? 40 : 36;
  const int o0 = blockIdx.y * 4;
  if (o0 >= O) return;                 // block-uniform
  int b, dir;
  const float *W, *bi;
  if (!isU) { dir = z >> 1; b = z & 1; W = dir ? Wb : Wf; bi = dir ? bb : bf; }
  else      { dir = 0; b = z - 4; W = Wu; bi = bu; }
  __shared__ float Wl[4 * 128];
  for (int t = threadIdx.x; t < 4 * I; t += TPB) {
    int i = t / 4, k = t % 4;
    Wl[t] = W[(size_t)(o0 + k) * I + i];
  }
  __syncthreads();
  const int l = blockIdx.x * TPB + threadIdx.x;
  const int ls = isU ? l : (dir ? (L - 1 - l) : l);
  const float* Xb = isU ? (xs + (size_t)b * C * L)
                        : (xm + ((size_t)b * C + dir * HALF) * L);
  float acc[4];
#pragma unroll
  for (int k = 0; k < 4; ++k) acc[k] = bi[o0 + k];
#pragma unroll 4
  for (int i = 0; i < I; ++i) {
    float xv = Xb[(size_t)i * L + ls];
#pragma unroll
    for (int k = 0; k < 4; ++k) acc[k] += Wl[i * 4 + k] * xv;
  }
  float* yp = isU ? (XDU + ((size_t)b * L + l) * 40 + o0)
                  : (XDF + ((size_t)z * L + l) * 36 + o0);
#pragma unroll
  for (int k = 0; k < 4; ++k) yp[k] = acc[k];
}

// ---------- merged B/C scrambled transpose ----------
__global__ void k_bc_all(const float* __restrict__ xdblF, const float* __restrict__ xdblU,
                         float* __restrict__ BmTF, float* __restrict__ CmTF,
                         float* __restrict__ BmTU, float* __restrict__ CmTU) {
  const int z = blockIdx.z;
  const bool isU = z >= 4;
  const int RT = isU ? 8 : 4, OT = isU ? 40 : 36;
  const float* src = isU ? (xdblU + (size_t)(z - 4) * L * 40)
                         : (xdblF + (size_t)z * L * 36);
  float* BT = isU ? (BmTU + (size_t)(z - 4) * L * N) : (BmTF + (size_t)z * L * N);
  float* CT = isU ? (CmTU + (size_t)(z - 4) * L * N) : (CmTF + (size_t)z * L * N);
  const int n = blockIdx.y;
  const int l2 = blockIdx.x * TPB + threadIdx.x;
  int f2 = n * L + l2;
  int lb = f2 >> 4, cb = f2 & 15;
  const float* xr2 = src + (size_t)lb * OT + RT + cb;
  size_t ob = (size_t)l2 * N + n;
  BT[ob] = xr2[0];
  CT[ob] = xr2[N];
}

// ---------- merged fused selective scan (512 blocks: 256 F rows + 256 U rows) ----------
__global__ __launch_bounds__(1024) void
k_scan_all(const float* __restrict__ xdblF, const float* __restrict__ xdblU,
           const float* __restrict__ dtf_w, const float* __restrict__ dtf_b,
           const float* __restrict__ dtb_w, const float* __restrict__ dtb_b,
           const float* __restrict__ dtu_w, const float* __restrict__ dtu_b,
           const float* __restrict__ xm, const float* __restrict__ xs,
           const float* __restrict__ BmTF, const float* __restrict__ CmTF,
           const float* __restrict__ BmTU, const float* __restrict__ CmTU,
           const float* __restrict__ Alog_f, const float* __restrict__ Alog_b,
           const float* __restrict__ Alog_u,
           const float* __restrict__ D_f, const float* __restrict__ D_b,
           const float* __restrict__ D_u,
           float* __restrict__ yf, float* __restrict__ yb, float* __restrict__ yus) {
  const int blk = blockIdx.x;
  const int tid = threadIdx.x;
  const bool isU = blk >= 256;
  int CsT, RT, c, b, dir;
  const float *Wdt, *bdt, *Alog, *Dv, *xdbl, *BT, *CT, *Ub;
  float* Y;
  int OT;
  if (!isU) {
    CsT = 64; RT = 4; OT = 36;
    int zb = blk >> 6; c = blk & 63; dir = zb >> 1; b = zb & 1;
    Wdt = dir ? dtb_w : dtf_w; bdt = dir ? dtb_b : dtf_b;
    Alog = dir ? Alog_b : Alog_f; Dv = dir ? D_b : D_f;
    xdbl = xdblF + (size_t)zb * L * 36;
    BT = BmTF + (size_t)zb * L * N; CT = CmTF + (size_t)zb * L * N;
    Ub = xm + ((size_t)b * C + dir * HALF + c) * L;
    Y = (dir ? yb : yf) + ((size_t)b * HALF + c) * L;
  } else {
    CsT = 128; RT = 8; OT = 40;
    int blk2 = blk - 256; b = blk2 >> 7; c = blk2 & 127; dir = 0;
    Wdt = dtu_w; bdt = dtu_b; Alog = Alog_u; Dv = D_u;
    xdbl = xdblU + (size_t)b * L * 40;
    BT = BmTU + (size_t)b * L * N; CT = CmTU + (size_t)b * L * N;
    Ub = xs + ((size_t)b * C + c) * L;
    Y = yus + ((size_t)b * C + c) * L;
  }
  __shared__ float sW[1024];          // transposed: sW[r*CsT + csrc]
  __shared__ float sb2[128];
  __shared__ float dtL[64][65];       // d
  __shared__ float duL[64][65];       // d*u
  __shared__ float SdL[64];           // per-chunk sum of d
  __shared__ float sA[N][65], sH[N][65];
  for (int t = tid; t < CsT * RT; t += 1024) {
    int csrc = t / RT, r = t % RT;
    sW[r * CsT + csrc] = Wdt[t];
  }
  for (int t = tid; t < CsT; t += 1024) sb2[t] = bdt[t];
  __syncthreads();
  // ---- stage 1: d, d*u into LDS; per-chunk d-sum via 16-lane shfl reduce ----
  {
    const int chunk_d = tid >> 4;
    const int sq = (tid & 15) * 4;
    const int lsrc = isU ? (c * 32 + (chunk_d >> 1)) : (c * 64 + chunk_d);
    const float* xrp = xdbl + (size_t)lsrc * OT;
    float xr[8];
    for (int r = 0; r < RT; ++r) xr[r] = xrp[r];
    const float bcc = sb2[c];
    float dpart = 0.f;
#pragma unroll
    for (int j = 0; j < 4; ++j) {
      int s = sq + j;
      int csrc = isU ? (((chunk_d & 1) << 6) + s) : s;
      float acc = sb2[csrc] + bcc;
      for (int r = 0; r < RT; ++r) acc += sW[r * CsT + csrc] * xr[r];
      int l = (chunk_d << 6) + s;
      float d = softplusf(acc);
      float uv = Ub[isU ? l : (dir ? (L - 1 - l) : l)];
      dtL[chunk_d][s] = d;
      duL[chunk_d][s] = d * uv;
      dpart += d;
    }
    dpart += __shfl_xor(dpart, 1);
    dpart += __shfl_xor(dpart, 2);
    dpart += __shfl_xor(dpart, 4);
    dpart += __shfl_xor(dpart, 8);
    if ((tid & 15) == 0) SdL[chunk_d] = dpart;
  }
  __syncthreads();
  const int n = tid & 15;
  const int chunk = tid >> 4;
  const float a = -__expf(Alog[c * N + n]);
  const float* bp = BT + ((size_t)(chunk << 6)) * N + n;
  const float* cp = CT + ((size_t)(chunk << 6)) * N + n;
  // phase A: chunk-local h (ap via exp of the d-sum: product of exps)
  float h = 0.f;
#pragma unroll 4
  for (int s = 0; s < 64; ++s) {
    float d = dtL[chunk][s];
    float du = duL[chunk][s];
    float bn = bp[(size_t)s * N];
    h = h * __expf(d * a) + du * bn;
  }
  sA[n][chunk] = __expf(a * SdL[chunk]);
  sH[n][chunk] = h;
  __syncthreads();
  // phase B: wave-parallel cross-chunk exclusive scan (wave w owns n=w)
  {
    const int w = tid >> 6;
    const int k = tid & 63;
    float A = sA[w][k];
    float Bv = sH[w][k];
#pragma unroll
    for (int j = 1; j < 64; j <<= 1) {
      float pa = __shfl_up(A, j);
      float pb = __shfl_up(Bv, j);
      if (k >= j) { Bv = pb * A + Bv; A = pa * A; }
    }
    float hprev = __shfl_up(Bv, 1);
    sH[w][k] = (k == 0) ? 0.f : hprev;
  }
  __syncthreads();
  h = sH[n][chunk];
  // phase C: replay; y = sum_n h*C + u*D  (u recovered as du/d)
  const float Dc = Dv[c];
  float ybuf[4];
#pragma unroll 4
  for (int s = 0; s < 64; ++s) {
    float d = dtL[chunk][s];
    float du = duL[chunk][s];
    float bn = bp[(size_t)s * N];
    float cn = cp[(size_t)s * N];
    h = h * __expf(d * a) + du * bn;
    float p = h * cn;
    p += __shfl_xor(p, 1);
    p += __shfl_xor(p, 2);
    p += __shfl_xor(p, 4);
    p += __shfl_xor(p, 8);
    if ((s & 15) == n) {
      float uv = du / fmaxf(d, 1e-30f);
      ybuf[s >> 4] = p + uv * Dc;
    }
  }
  float* Yp = Y + (chunk << 6);
#pragma unroll
  for (int q = 0; q < 4; ++q) Yp[16 * q + n] = ybuf[q];
}

// ---------- gate1: inline cat-LN stats + conv + BN partial sums ----------
template <int O_PB>
__global__ void k_gate1(const float* __restrict__ yf, const float* __restrict__ yb,
                        const float* __restrict__ lncw, const float* __restrict__ lncb,
                        const float* __restrict__ yu,
                        const float* __restrict__ W, const float* __restrict__ bias,
                        float* __restrict__ g1,
                        float* __restrict__ st2m, float* __restrict__ st2r,
                        float* __restrict__ bnsum) {
  __shared__ float Wl[O_PB * 256];
  __shared__ float cw[128], cb2[128];
  __shared__ float part[2][O_PB][4];
  const int o0 = blockIdx.y * O_PB;
  const int b  = blockIdx.z;
  for (int t = threadIdx.x; t < O_PB * 256; t += TPB) {
    int i = t / O_PB, k = t % O_PB;
    Wl[t] = W[(size_t)(o0 + k) * 256 + i];
  }
  for (int t = threadIdx.x; t < 128; t += TPB) { cw[t] = lncw[t]; cb2[t] = lncb[t]; }
  __syncthreads();
  const int l = blockIdx.x * TPB + threadIdx.x;
  const float* f0 = yf + (size_t)b * HALF * L + l;
  const float* b0 = yb + (size_t)b * HALF * L + (L - 1 - l);
  const float* u0 = yu + (size_t)b * C * L + l;
  float s = 0.f, s2 = 0.f;
#pragma unroll 8
  for (int i = 0; i < 64; ++i) { float v = f0[(size_t)i * L]; s += v; s2 += v * v; }
#pragma unroll 8
  for (int i = 0; i < 64; ++i) { float v = b0[(size_t)i * L]; s += v; s2 += v * v; }
  const float m = s / C;
  const float r = rsqrtf(s2 / C - m * m + 1e-6f);
  if (blockIdx.y == 0) { st2m[b * L + l] = m; st2r[b * L + l] = r; }
  float acc[O_PB];
#pragma unroll
  for (int k = 0; k < O_PB; ++k) acc[k] = bias[o0 + k];
#pragma unroll 4
  for (int i = 0; i < 64; ++i) {
    float cv = (f0[(size_t)i * L] - m) * r * cw[i] + cb2[i];
#pragma unroll
    for (int k = 0; k < O_PB; ++k) acc[k] += Wl[i * O_PB + k] * cv;
  }
#pragma unroll 4
  for (int i = 0; i < 64; ++i) {
    float cv = (b0[(size_t)i * L] - m) * r * cw[64 + i] + cb2[64 + i];
#pragma unroll
    for (int k = 0; k < O_PB; ++k) acc[k] += Wl[(64 + i) * O_PB + k] * cv;
  }
#pragma unroll 4
  for (int i = 0; i < 128; ++i) {
    float xv = u0[(size_t)i * L];
#pragma unroll
    for (int k = 0; k < O_PB; ++k) acc[k] += Wl[(128 + i) * O_PB + k] * xv;
  }
#pragma unroll
  for (int k = 0; k < O_PB; ++k)
    g1[((size_t)b * C + o0 + k) * L + l] = acc[k];
  const int wv = threadIdx.x >> 6, lnn = threadIdx.x & 63;
#pragma unroll
  for (int k = 0; k < O_PB; ++k) {
    float v = acc[k];
    v += __shfl_xor(v, 1);  v += __shfl_xor(v, 2);  v += __shfl_xor(v, 4);
    v += __shfl_xor(v, 8);  v += __shfl_xor(v, 16); v += __shfl_xor(v, 32);
    if (lnn == 0) part[0][k][wv] = v;
    float q = acc[k] * acc[k];
    q += __shfl_xor(q, 1);  q += __shfl_xor(q, 2);  q += __shfl_xor(q, 4);
    q += __shfl_xor(q, 8);  q += __shfl_xor(q, 16); q += __shfl_xor(q, 32);
    if (lnn == 0) part[1][k][wv] = q;
  }
  __syncthreads();
  if (threadIdx.x < 2 * O_PB) {
    int which = threadIdx.x >= O_PB, k = threadIdx.x % O_PB;
    float v = part[which][k][0] + part[which][k][1] + part[which][k][2] + part[which][k][3];
    atomicAdd(&bnsum[which * 128 + o0 + k], v);
  }
}

// ---------- gate2: BN(from sums)+relu on loads; epilogue sigmoid+fuse ----------
template <int O_PB>
__global__ void k_gate2_fuse(const float* __restrict__ g1,
                             const float* __restrict__ bnsum,
                             const float* __restrict__ bn_g, const float* __restrict__ bn_b,
                             const float* __restrict__ W, const float* __restrict__ bias,
                             const float* __restrict__ yu,
                             const float* __restrict__ yf, const float* __restrict__ yb,
                             const float* __restrict__ mean2, const float* __restrict__ rinv2,
                             const float* __restrict__ lncw, const float* __restrict__ lncb,
                             float* __restrict__ fused) {
  __shared__ float Wl[O_PB * 128];
  __shared__ float sc[128], sh[128];
  __shared__ float cwo[O_PB], cbo[O_PB];
  const int o0 = blockIdx.y * O_PB;
  const int b  = blockIdx.z;
  for (int t = threadIdx.x; t < O_PB * 128; t += TPB) {
    int i = t / O_PB, k = t % O_PB;
    Wl[t] = W[(size_t)(o0 + k) * 128 + i];
  }
  for (int t = threadIdx.x; t < 128; t += TPB) {
    float sv = bnsum[t], qv = bnsum[128 + t];
    float mean = sv / (B_SZ * L);
    float var  = qv / (B_SZ * L) - mean * mean;
    float scv = bn_g[t] * rsqrtf(var + 1e-5f);
    sc[t] = scv;
    sh[t] = bn_b[t] - mean * scv;
  }
  if (threadIdx.x < O_PB) {
    cwo[threadIdx.x] = lncw[o0 + threadIdx.x];
    cbo[threadIdx.x] = lncb[o0 + threadIdx.x];
  }
  __syncthreads();
  const int l = blockIdx.x * TPB + threadIdx.x;
  const float m = mean2[b * L + l], r = rinv2[b * L + l];
  const float* Xb = g1 + (size_t)b * C * L + l;
  float acc[O_PB];
#pragma unroll
  for (int k = 0; k < O_PB; ++k) acc[k] = bias[o0 + k];
#pragma unroll 4
  for (int i = 0; i < 128; ++i) {
    float v = fmaxf(Xb[(size_t)i * L] * sc[i] + sh[i], 0.f);
#pragma unroll
    for (int k = 0; k < O_PB; ++k) acc[k] += Wl[i * O_PB + k] * v;
  }
#pragma unroll
  for (int k = 0; k < O_PB; ++k) {
    int o = o0 + k;
    float g = sigm(acc[k]);
    float yuv = yu[((size_t)b * C + o) * L + l];
    float yv = (o < 64) ? yf[((size_t)b * HALF + o) * L + l]
                        : yb[((size_t)b * HALF + (o - 64)) * L + (L - 1 - l)];
    float cv = (yv - m) * r * cwo[k] + cbo[k];
    fused[((size_t)b * C + o) * L + l] = g * yuv + (1.f - g) * cv;
  }
}

// ---------- outproj: 1x1 conv over concat([fused, xr]) ----------
template <int O_PB>
__global__ void k_conv1x1_cat2(const float* __restrict__ X1, const float* __restrict__ X2,
                               const float* __restrict__ W, const float* __restrict__ bias,
                               float* __restrict__ Y, int O) {
  __shared__ float Wl[O_PB * 256];
  const int o0 = blockIdx.y * O_PB;
  const int b  = blockIdx.z;
  for (int t = threadIdx.x; t < O_PB * 256; t += TPB) {
    int i = t / O_PB, k = t % O_PB;
    Wl[t] = W[(size_t)(o0 + k) * 256 + i];
  }
  __syncthreads();
  const int l = blockIdx.x * TPB + threadIdx.x;
  const float* Xb1 = X1 + (size_t)b * C * L + l;
  const float* Xb2 = X2 + (size_t)b * C * L + l;
  float acc[O_PB];
#pragma unroll
  for (int k = 0; k < O_PB; ++k) acc[k] = bias[o0 + k];
#pragma unroll 4
  for (int i = 0; i < 128; ++i) {
    float xv = Xb1[(size_t)i * L];
#pragma unroll
    for (int k = 0; k < O_PB; ++k) acc[k] += Wl[i * O_PB + k] * xv;
  }
#pragma unroll 4
  for (int i = 0; i < 128; ++i) {
    float xv = Xb2[(size_t)i * L];
#pragma unroll
    for (int k = 0; k < O_PB; ++k) acc[k] += Wl[(128 + i) * O_PB + k] * xv;
  }
#pragma unroll
  for (int k = 0; k < O_PB; ++k)
    Y[((size_t)b * O + o0 + k) * L + l] = acc[k];
}

// ---------- final channel LN ----------
__global__ void k_ln_cf(const float* __restrict__ X,
                        const float* __restrict__ w, const float* __restrict__ bchan,
                        float* __restrict__ Y) {
  const int lp = threadIdx.x & 63;
  const int wv = threadIdx.x >> 6;
  const int p  = blockIdx.x * 64 + lp;
  const int b = p / L, l = p % L;
  const float* Xp = X + (size_t)b * C * L + l;
  float s = 0.f, s2 = 0.f;
#pragma unroll 8
  for (int i = 0; i < 32; ++i) {
    float v = Xp[(size_t)(wv * 32 + i) * L];
    s += v; s2 += v * v;
  }
  __shared__ float r1[4][64], r2[4][64];
  r1[wv][lp] = s; r2[wv][lp] = s2;
  __syncthreads();
  float st  = r1[0][lp] + r1[1][lp] + r1[2][lp] + r1[3][lp];
  float s2t = r2[0][lp] + r2[1][lp] + r2[2][lp] + r2[3][lp];
  float mean = st / C;
  float rinv = rsqrtf(s2t / C - mean * mean + 1e-6f);
  float* Yp = Y + (size_t)b * C * L + l;
#pragma unroll 8
  for (int i = 0; i < 32; ++i) {
    int c = wv * 32 + i;
    float v = Xp[(size_t)c * L];
    Yp[(size_t)c * L] = w[c] * (v - mean) * rinv + bchan[c];
  }
}

} // namespace

extern "C" void kernel_launch(void* const* d_in, const int* in_sizes, int n_in,
                              void* d_out, int out_size, void* d_ws, size_t ws_size,
                              hipStream_t stream) {
  const float* x         = (const float*)d_in[0];
  const float* ln_in_w   = (const float*)d_in[1];
  const float* ln_in_b   = (const float*)d_in[2];
  const float* inproj_w  = (const float*)d_in[3];
  const float* inproj_b  = (const float*)d_in[4];
  const float* ln_m_w    = (const float*)d_in[5];
  const float* ln_m_b    = (const float*)d_in[6];
  const float* convm_w   = (const float*)d_in[7];
  const float* convm_b   = (const float*)d_in[8];
  const float* convr_w   = (const float*)d_in[9];
  const float* convr_b   = (const float*)d_in[10];
  const float* ln_cat_w  = (const float*)d_in[11];
  const float* ln_cat_b  = (const float*)d_in[12];
  const float* xpf_w     = (const float*)d_in[13];
  const float* xpf_b     = (const float*)d_in[14];
  const float* dtf_w     = (const float*)d_in[15];
  const float* dtf_b     = (const float*)d_in[16];
  const float* Alog_f    = (const float*)d_in[17];
  const float* D_f       = (const float*)d_in[18];
  const float* xpb_w     = (const float*)d_in[19];
  const float* xpb_b     = (const float*)d_in[20];
  const float* dtb_w     = (const float*)d_in[21];
  const float* dtb_b     = (const float*)d_in[22];
  const float* Alog_b    = (const float*)d_in[23];
  const float* D_b       = (const float*)d_in[24];
  const float* xpu_w     = (const float*)d_in[25];
  const float* xpu_b     = (const float*)d_in[26];
  const float* dtu_w     = (const float*)d_in[27];
  const float* dtu_b     = (const float*)d_in[28];
  const float* Alog_u    = (const float*)d_in[29];
  const float* D_u       = (const float*)d_in[30];
  const float* gate1_w   = (const float*)d_in[31];
  const float* gate1_b   = (const float*)d_in[32];
  const float* bn_g      = (const float*)d_in[33];
  const float* bn_b      = (const float*)d_in[34];
  const float* gate2_w   = (const float*)d_in[35];
  const float* gate2_b   = (const float*)d_in[36];
  const float* outproj_w = (const float*)d_in[37];
  const float* outproj_b = (const float*)d_in[38];
  const float* outln_w   = (const float*)d_in[39];
  const float* outln_b   = (const float*)d_in[40];

  float* ws = (float*)d_ws;
  size_t off = 0;
  auto alloc = [&](size_t n) { float* p = ws + off; off += n; return p; };

  const size_t BL = (size_t)B_SZ * L;
  float* xp    = alloc((size_t)B_SZ * 2 * C * L);
  float* st1m  = alloc(BL);
  float* st1r  = alloc(BL);
  float* xm    = alloc((size_t)B_SZ * C * L);
  float* xr    = alloc((size_t)B_SZ * C * L);
  float* unc   = alloc(BL);
  int*   rank  = (int*)alloc(BL);
  int*   inv   = (int*)alloc(BL);
  float* xs    = alloc((size_t)B_SZ * C * L);
  float* xdblF = alloc((size_t)4 * L * 36);
  float* BmTF  = alloc((size_t)4 * L * N);
  float* CmTF  = alloc((size_t)4 * L * N);
  float* xdblU = alloc((size_t)2 * L * 40);
  float* BmTU  = alloc((size_t)2 * L * N);
  float* CmTU  = alloc((size_t)2 * L * N);
  float* yf    = alloc((size_t)B_SZ * HALF * L);
  float* yb    = alloc((size_t)B_SZ * HALF * L);
  float* yus   = alloc((size_t)B_SZ * C * L);
  float* yu    = alloc((size_t)B_SZ * C * L);
  float* st2m  = alloc(BL);
  float* st2r  = alloc(BL);
  float* g1    = alloc((size_t)B_SZ * C * L);
  float* bnsum = alloc(256);
  float* fused = alloc((size_t)B_SZ * C * L);
  float* outp  = alloc((size_t)B_SZ * C * L);
  (void)ws_size; (void)in_sizes; (void)n_in; (void)out_size;

  const int pixB = B_SZ * L / 64;          // 128 blocks (256 thr)
  const int elemB = B_SZ * C * L / TPB;    // 4096

  // 1) inproj with inline LN
  k_conv_ln<16><<<dim3(L / (2 * TPB), 16, B_SZ), TPB, 0, stream>>>(
      x, C * L, ln_in_w, ln_in_b, inproj_w, inproj_b, xp, 128, 256);
  // 2) stats of xp[:,:128]; 3) tiled dwconv
  k_pixstats<<<pixB, TPB, 0, stream>>>(xp, 2 * C * L, C, 1e-6f, st1m, st1r);
  k_dwconv_t<<<dim3(HH / 4, C, 2 * B_SZ), TPB, 0, stream>>>(
      xp, st1m, st1r, ln_m_w, ln_m_b, convm_w, convm_b, convr_w, convr_b, xm, xr);
  // 4) unc (+zero bnsum/rank), rank-count, scatter-gather
  k_unc<<<pixB, TPB, 0, stream>>>(xm, unc, bnsum, rank);
  k_rank<<<dim3(L / TPB, 8, B_SZ), TPB, 0, stream>>>(unc, rank);
  k_scatgath<<<elemB, TPB, 0, stream>>>(xm, rank, xs, inv);
  // 5) merged scan pipelines
  k_convx_all<<<dim3(L / TPB, 10, 6), TPB, 0, stream>>>(
      xm, xs, xpf_w, xpf_b, xpb_w, xpb_b, xpu_w, xpu_b, xdblF, xdblU);
  k_bc_all<<<dim3(L / TPB, N, 6), TPB, 0, stream>>>(
      xdblF, xdblU, BmTF, CmTF, BmTU, CmTU);
  k_scan_all<<<512, 1024, 0, stream>>>(
      xdblF, xdblU, dtf_w, dtf_b, dtb_w, dtb_b, dtu_w, dtu_b,
      xm, xs, BmTF, CmTF, BmTU, CmTU,
      Alog_f, Alog_b, Alog_u, D_f, D_b, D_u, yf, yb, yus);
  // 6) epilogue (O_PB=8 -> 512-block grids for 2 blocks/CU)
  k_unsort<<<elemB, TPB, 0, stream>>>(yus, inv, yu);
  k_gate1<8><<<dim3(L / TPB, 16, B_SZ), TPB, 0, stream>>>(
      yf, yb, ln_cat_w, ln_cat_b, yu, gate1_w, gate1_b, g1, st2m, st2r, bnsum);
  k_gate2_fuse<8><<<dim3(L / TPB, 16, B_SZ), TPB, 0, stream>>>(
      g1, bnsum, bn_g, bn_b, gate2_w, gate2_b, yu, yf, yb, st2m, st2r,
      ln_cat_w, ln_cat_b, fused);
  k_conv1x1_cat2<8><<<dim3(L / TPB, 16, B_SZ), TPB, 0, stream>>>(
      fused, xr, outproj_w, outproj_b, outp, 128);
  k_ln_cf<<<pixB, TPB, 0, stream>>>(outp, outln_w, outln_b, (float*)d_out);
}

// Round 10
// 343.505 us; speedup vs baseline: 1.7855x; 1.0434x over previous
//
#include <hip/hip_runtime.h>
#include <cstdint>
#include <cstddef>

#define TPB 256

namespace {

constexpr int B_SZ = 2;
constexpr int C    = 128;
constexpr int HALF = 64;
constexpr int L    = 4096;   // 64*64
constexpr int N    = 16;
constexpr int HH   = 64;
constexpr int WW   = 64;

// fast-math (hardware v_exp_f32/v_log_f32); ~1e-7 rel err, fine at 9.7e-2 threshold
__device__ __forceinline__ float softplusf(float x) {
  return fmaxf(x, 0.f) + __logf(1.f + __expf(-fabsf(x)));
}
__device__ __forceinline__ float sigm(float x) { return 1.f / (1.f + __expf(-x)); }

__device__ __forceinline__ unsigned long long unc_key(float u, int i) {
  unsigned m = __float_as_uint(u);
  m = (m & 0x80000000u) ? ~m : (m | 0x80000000u);   // monotone ascending map
  return ((unsigned long long)(~m) << 32) | (unsigned)i;  // ascending = descending unc, stable
}

// ---------- inproj: 1x1 conv with INLINE per-pixel LN + atomic stats of xp[:,:128] ----------
// O_PB=8 -> 512 blocks (2/CU). 2 pixels per thread.
__global__ void k_conv_ln(const float* __restrict__ X, int bsX,
                          const float* __restrict__ lnw, const float* __restrict__ lnb,
                          const float* __restrict__ W, const float* __restrict__ bias,
                          float* __restrict__ Y, int I, int O,
                          float* __restrict__ st1s, float* __restrict__ st1q) {
  constexpr int O_PB = 8;
  __shared__ float Wl[O_PB * 128];
  __shared__ float aw[128], ab[128];
  const int o0 = blockIdx.y * O_PB;
  const int b  = blockIdx.z;
  for (int t = threadIdx.x; t < O_PB * I; t += TPB) {
    int i = t / O_PB, k = t % O_PB;
    Wl[t] = W[(size_t)(o0 + k) * I + i];
  }
  for (int t = threadIdx.x; t < I; t += TPB) { aw[t] = lnw[t]; ab[t] = lnb[t]; }
  __syncthreads();
  const int l0 = blockIdx.x * (2 * TPB) + threadIdx.x;
  const int l1 = l0 + TPB;
  const float* X0 = X + (size_t)b * bsX + l0;
  const float* X1 = X + (size_t)b * bsX + l1;
  float s0 = 0.f, q0 = 0.f, s1 = 0.f, q1 = 0.f;
#pragma unroll 8
  for (int i = 0; i < I; ++i) {
    float v0 = X0[(size_t)i * L], v1 = X1[(size_t)i * L];
    s0 += v0; q0 += v0 * v0; s1 += v1; q1 += v1 * v1;
  }
  const float m0 = s0 / I, m1 = s1 / I;
  const float r0 = rsqrtf(q0 / I - m0 * m0 + 1e-6f);
  const float r1 = rsqrtf(q1 / I - m1 * m1 + 1e-6f);
  float acc0[O_PB], acc1[O_PB];
#pragma unroll
  for (int k = 0; k < O_PB; ++k) { acc0[k] = bias[o0 + k]; acc1[k] = acc0[k]; }
#pragma unroll 4
  for (int i = 0; i < I; ++i) {
    float xv0 = (X0[(size_t)i * L] - m0) * r0 * aw[i] + ab[i];
    float xv1 = (X1[(size_t)i * L] - m1) * r1 * aw[i] + ab[i];
#pragma unroll
    for (int k = 0; k < O_PB; ++k) {
      acc0[k] += Wl[i * O_PB + k] * xv0;
      acc1[k] += Wl[i * O_PB + k] * xv1;
    }
  }
#pragma unroll
  for (int k = 0; k < O_PB; ++k) {
    Y[((size_t)b * O + o0 + k) * L + l0] = acc0[k];
    Y[((size_t)b * O + o0 + k) * L + l1] = acc1[k];
  }
  // atomic partial stats of the first 128 output channels (feeds LN-mamba)
  if (o0 < 128) {
    float ss0 = 0.f, qq0 = 0.f, ss1 = 0.f, qq1 = 0.f;
#pragma unroll
    for (int k = 0; k < O_PB; ++k) {
      ss0 += acc0[k]; qq0 += acc0[k] * acc0[k];
      ss1 += acc1[k]; qq1 += acc1[k] * acc1[k];
    }
    atomicAdd(&st1s[b * L + l0], ss0);
    atomicAdd(&st1q[b * L + l0], qq0);
    atomicAdd(&st1s[b * L + l1], ss1);
    atomicAdd(&st1q[b * L + l1], qq1);
  }
}

// ---------- depthwise 3x3 + SiLU via LDS halo tile; mode0 LN (from sum/sumsq) ----------
__global__ void k_dwconv_t(const float* __restrict__ xp,
                           const float* __restrict__ st1s, const float* __restrict__ st1q,
                           const float* __restrict__ lnw, const float* __restrict__ lnb,
                           const float* __restrict__ Wm, const float* __restrict__ bm,
                           const float* __restrict__ Wr, const float* __restrict__ br,
                           float* __restrict__ xm, float* __restrict__ xr) {
  const int c = blockIdx.y;
  const int z = blockIdx.z;
  const int b = z & 1, mode = z >> 1;     // 0: mamba (LN), 1: res
  const int h0 = blockIdx.x * 4;
  __shared__ float T[6][66];
  const float* Xc = xp + ((size_t)b * 2 * C + (mode ? C + c : c)) * L;
  const float lw = mode ? 0.f : lnw[c];
  const float lb2 = mode ? 0.f : lnb[c];
  for (int t = threadIdx.x; t < 6 * 66; t += TPB) {
    int r = t / 66, cc = t % 66 - 1;
    int hh = h0 - 1 + r;
    float v = 0.f;
    if (hh >= 0 && hh < HH && cc >= 0 && cc < WW) {
      int li = hh * WW + cc;
      v = Xc[li];
      if (mode == 0) {
        float sv = st1s[b * L + li], qv = st1q[b * L + li];
        float m = sv * (1.f / 128.f);
        float rr = rsqrtf(qv * (1.f / 128.f) - m * m + 1e-6f);
        v = (v - m) * rr * lw + lb2;
      }
    }
    T[r][t % 66] = v;
  }
  __syncthreads();
  const int hl = threadIdx.x >> 6, w = threadIdx.x & 63;
  const float* W9 = (mode ? Wr : Wm) + c * 9;
  float acc = mode ? br[c] : bm[c];
#pragma unroll
  for (int kh = 0; kh < 3; ++kh)
#pragma unroll
    for (int kw = 0; kw < 3; ++kw)
      acc += T[hl + kh][w + kw] * W9[kh * 3 + kw];
  const int l = (h0 + hl) * WW + w;
  float* Yp = mode ? xr : xm;
  Yp[((size_t)b * C + c) * L + l] = acc * sigm(acc);
}

// ---------- uncertainty per pixel ----------
__global__ void k_unc(const float* __restrict__ xm, float* __restrict__ unc) {
  const int lp = threadIdx.x & 63;
  const int wv = threadIdx.x >> 6;
  const int p  = blockIdx.x * 64 + lp;
  const int b = p / L, l = p % L;
  const float* Xp = xm + (size_t)b * C * L + l;
  float s = 0.f;
#pragma unroll 8
  for (int i = 0; i < 32; ++i) s += Xp[(size_t)(wv * 32 + i) * L];
  __shared__ float r1[4][64];
  r1[wv][lp] = s;
  __syncthreads();
  if (wv == 0) {
    float st = r1[0][lp] + r1[1][lp] + r1[2][lp] + r1[3][lp];
    float sg = sigm(st / C);
    unc[p] = -(sg * __logf(sg + 1e-6f));
  }
}

// ---------- stable rank of descending unc: rank_i = #{j: ckey_j < ckey_i} ----------
__global__ void k_rank(const float* __restrict__ unc, int* __restrict__ rankbuf) {
  constexpr int JC = 512;
  __shared__ unsigned long long K[JC];
  const int b  = blockIdx.z;
  const int j0 = blockIdx.y * JC;
  const int i  = blockIdx.x * TPB + threadIdx.x;
  for (int t = threadIdx.x; t < JC; t += TPB)
    K[t] = unc_key(unc[b * L + j0 + t], j0 + t);
  __syncthreads();
  const unsigned long long my = unc_key(unc[b * L + i], i);
  int cnt = 0;
#pragma unroll 8
  for (int j = 0; j < JC; ++j) cnt += (K[j] < my) ? 1 : 0;
  atomicAdd(&rankbuf[b * L + i], cnt);
}

// ---------- scatter-gather: xs[b,c,rank_l] = xm[b,c,l]; inv[l]=r; idx[r]=l ----------
__global__ void k_scatgath(const float* __restrict__ xm, const int* __restrict__ rankbuf,
                           float* __restrict__ xs, int* __restrict__ inv,
                           int* __restrict__ idx) {
  int t = blockIdx.x * TPB + threadIdx.x;
  int l = t % L, c = (t / L) % C, b = t / (C * L);
  int r = rankbuf[b * L + l];
  xs[((size_t)b * C + c) * L + r] = xm[t];
  if (c == 0) { inv[b * L + l] = r; idx[b * L + r] = l; }
}

// ---------- merged x-projection conv: z 0..3 = f/b dirs, z 4..5 = u (reads xs) ----------
__global__ void k_convx_all(const float* __restrict__ xm, const float* __restrict__ xs,
                            const float* __restrict__ Wf, const float* __restrict__ bf,
                            const float* __restrict__ Wb, const float* __restrict__ bb,
                            const float* __restrict__ Wu, const float* __restrict__ bu,
                            float* __restrict__ XDF, float* __restrict__ XDU) {
  const int z = blockIdx.z;
  const bool isU = z >= 4;
  const int I = isU ? 128 : 64;
  const int O = isU ? 40 : 36;
  const int o0 = blockIdx.y * 4;
  if (o0 >= O) return;                 // block-uniform
  int b, dir;
  const float *W, *bi;
  if (!isU) { dir = z >> 1; b = z & 1; W = dir ? Wb : Wf; bi = dir ? bb : bf; }
  else      { dir = 0; b = z - 4; W = Wu; bi = bu; }
  __shared__ float Wl[4 * 128];
  for (int t = threadIdx.x; t < 4 * I; t += TPB) {
    int i = t / 4, k = t % 4;
    Wl[t] = W[(size_t)(o0 + k) * I + i];
  }
  __syncthreads();
  const int l = blockIdx.x * TPB + threadIdx.x;
  const int ls = isU ? l : (dir ? (L - 1 - l) : l);
  const float* Xb = isU ? (xs + (size_t)b * C * L)
                        : (xm + ((size_t)b * C + dir * HALF) * L);
  float acc[4];
#pragma unroll
  for (int k = 0; k < 4; ++k) acc[k] = bi[o0 + k];
#pragma unroll 4
  for (int i = 0; i < I; ++i) {
    float xv = Xb[(size_t)i * L + ls];
#pragma unroll
    for (int k = 0; k < 4; ++k) acc[k] += Wl[i * 4 + k] * xv;
  }
  float* yp = isU ? (XDU + ((size_t)b * L + l) * 40 + o0)
                  : (XDF + ((size_t)z * L + l) * 36 + o0);
#pragma unroll
  for (int k = 0; k < 4; ++k) yp[k] = acc[k];
}

// ---------- merged B/C scrambled transpose ----------
__global__ void k_bc_all(const float* __restrict__ xdblF, const float* __restrict__ xdblU,
                         float* __restrict__ BmTF, float* __restrict__ CmTF,
                         float* __restrict__ BmTU, float* __restrict__ CmTU) {
  const int z = blockIdx.z;
  const bool isU = z >= 4;
  const int RT = isU ? 8 : 4, OT = isU ? 40 : 36;
  const float* src = isU ? (xdblU + (size_t)(z - 4) * L * 40)
                         : (xdblF + (size_t)z * L * 36);
  float* BT = isU ? (BmTU + (size_t)(z - 4) * L * N) : (BmTF + (size_t)z * L * N);
  float* CT = isU ? (CmTU + (size_t)(z - 4) * L * N) : (CmTF + (size_t)z * L * N);
  const int n = blockIdx.y;
  const int l2 = blockIdx.x * TPB + threadIdx.x;
  int f2 = n * L + l2;
  int lb = f2 >> 4, cb = f2 & 15;
  const float* xr2 = src + (size_t)lb * OT + RT + cb;
  size_t ob = (size_t)l2 * N + n;
  BT[ob] = xr2[0];
  CT[ob] = xr2[N];
}

// ---------- merged fused selective scan (512 blocks); U writes UNSORTED via idx ----------
__global__ __launch_bounds__(1024) void
k_scan_all(const float* __restrict__ xdblF, const float* __restrict__ xdblU,
           const float* __restrict__ dtf_w, const float* __restrict__ dtf_b,
           const float* __restrict__ dtb_w, const float* __restrict__ dtb_b,
           const float* __restrict__ dtu_w, const float* __restrict__ dtu_b,
           const float* __restrict__ xm, const float* __restrict__ xs,
           const int* __restrict__ idx,
           const float* __restrict__ BmTF, const float* __restrict__ CmTF,
           const float* __restrict__ BmTU, const float* __restrict__ CmTU,
           const float* __restrict__ Alog_f, const float* __restrict__ Alog_b,
           const float* __restrict__ Alog_u,
           const float* __restrict__ D_f, const float* __restrict__ D_b,
           const float* __restrict__ D_u,
           float* __restrict__ yf, float* __restrict__ yb, float* __restrict__ yu) {
  const int blk = blockIdx.x;
  const int tid = threadIdx.x;
  const bool isU = blk >= 256;
  int CsT, RT, c, b, dir;
  const float *Wdt, *bdt, *Alog, *Dv, *xdbl, *BT, *CT, *Ub;
  const int* idxb = nullptr;
  float* Y;
  int OT;
  if (!isU) {
    CsT = 64; RT = 4; OT = 36;
    int zb = blk >> 6; c = blk & 63; dir = zb >> 1; b = zb & 1;
    Wdt = dir ? dtb_w : dtf_w; bdt = dir ? dtb_b : dtf_b;
    Alog = dir ? Alog_b : Alog_f; Dv = dir ? D_b : D_f;
    xdbl = xdblF + (size_t)zb * L * 36;
    BT = BmTF + (size_t)zb * L * N; CT = CmTF + (size_t)zb * L * N;
    Ub = xm + ((size_t)b * C + dir * HALF + c) * L;
    Y = (dir ? yb : yf) + ((size_t)b * HALF + c) * L;
  } else {
    CsT = 128; RT = 8; OT = 40;
    int blk2 = blk - 256; b = blk2 >> 7; c = blk2 & 127; dir = 0;
    Wdt = dtu_w; bdt = dtu_b; Alog = Alog_u; Dv = D_u;
    xdbl = xdblU + (size_t)b * L * 40;
    BT = BmTU + (size_t)b * L * N; CT = CmTU + (size_t)b * L * N;
    Ub = xs + ((size_t)b * C + c) * L;
    idxb = idx + b * L;
    Y = yu + ((size_t)b * C + c) * L;
  }
  __shared__ float sW[1024];          // transposed: sW[r*CsT + csrc]
  __shared__ float sb2[128];
  __shared__ float dtL[64][65];       // d
  __shared__ float uL[64][65];        // u
  __shared__ float sA[N][65], sH[N][65];
  for (int t = tid; t < CsT * RT; t += 1024) {
    int csrc = t / RT, r = t % RT;
    sW[r * CsT + csrc] = Wdt[t];
  }
  for (int t = tid; t < CsT; t += 1024) sb2[t] = bdt[t];
  __syncthreads();
  // ---- stage 1: dt + u into LDS ----
  {
    const int chunk_d = tid >> 4;
    const int sq = (tid & 15) * 4;
    const int lsrc = isU ? (c * 32 + (chunk_d >> 1)) : (c * 64 + chunk_d);
    const float* xrp = xdbl + (size_t)lsrc * OT;
    float xr[8];
    for (int r = 0; r < RT; ++r) xr[r] = xrp[r];
    const float bcc = sb2[c];
#pragma unroll
    for (int j = 0; j < 4; ++j) {
      int s = sq + j;
      int csrc = isU ? (((chunk_d & 1) << 6) + s) : s;
      float acc = sb2[csrc] + bcc;
      for (int r = 0; r < RT; ++r) acc += sW[r * CsT + csrc] * xr[r];
      int l = (chunk_d << 6) + s;
      dtL[chunk_d][s] = softplusf(acc);
      uL[chunk_d][s] = Ub[isU ? l : (dir ? (L - 1 - l) : l)];
    }
  }
  __syncthreads();
  const int n = tid & 15;
  const int chunk = tid >> 4;
  const float a = -__expf(Alog[c * N + n]);
  const float* bp = BT + ((size_t)(chunk << 6)) * N + n;
  const float* cp = CT + ((size_t)(chunk << 6)) * N + n;
  // phase A
  float ap = 1.f, h = 0.f;
#pragma unroll 4
  for (int s = 0; s < 64; ++s) {
    float d = dtL[chunk][s];
    float uv = uL[chunk][s];
    float bn = bp[(size_t)s * N];
    float dA = __expf(d * a);
    ap *= dA;
    h = h * dA + d * uv * bn;
  }
  sA[n][chunk] = ap; sH[n][chunk] = h;
  __syncthreads();
  // phase B: wave-parallel cross-chunk exclusive scan (wave w owns n=w)
  {
    const int w = tid >> 6;
    const int k = tid & 63;
    float A = sA[w][k];
    float Bv = sH[w][k];
#pragma unroll
    for (int j = 1; j < 64; j <<= 1) {
      float pa = __shfl_up(A, j);
      float pb = __shfl_up(Bv, j);
      if (k >= j) { Bv = pb * A + Bv; A = pa * A; }
    }
    float hprev = __shfl_up(Bv, 1);
    sH[w][k] = (k == 0) ? 0.f : hprev;
  }
  __syncthreads();
  h = sH[n][chunk];
  // phase C
  const float Dc = Dv[c];
  float ybuf[4];
#pragma unroll 4
  for (int s = 0; s < 64; ++s) {
    float d = dtL[chunk][s];
    float uv = uL[chunk][s];
    float bn = bp[(size_t)s * N];
    float cn = cp[(size_t)s * N];
    float dA = __expf(d * a);
    h = h * dA + d * uv * bn;
    float p = h * cn;
    p += __shfl_xor(p, 1);
    p += __shfl_xor(p, 2);
    p += __shfl_xor(p, 4);
    p += __shfl_xor(p, 8);
    if ((s & 15) == n) ybuf[s >> 4] = p + uv * Dc;
  }
  if (!isU) {
    float* Yp = Y + (chunk << 6);
#pragma unroll
    for (int q = 0; q < 4; ++q) Yp[16 * q + n] = ybuf[q];
  } else {
    const int s0 = chunk << 6;
#pragma unroll
    for (int q = 0; q < 4; ++q) Y[idxb[s0 + 16 * q + n]] = ybuf[q];
  }
}

// ---------- gate1: inline cat-LN stats + conv + BN partial sums ----------
template <int O_PB>
__global__ void k_gate1(const float* __restrict__ yf, const float* __restrict__ yb,
                        const float* __restrict__ lncw, const float* __restrict__ lncb,
                        const float* __restrict__ yu,
                        const float* __restrict__ W, const float* __restrict__ bias,
                        float* __restrict__ g1,
                        float* __restrict__ st2m, float* __restrict__ st2r,
                        float* __restrict__ bnsum) {
  __shared__ float Wl[O_PB * 256];
  __shared__ float cw[128], cb2[128];
  __shared__ float part[2][O_PB][4];
  const int o0 = blockIdx.y * O_PB;
  const int b  = blockIdx.z;
  for (int t = threadIdx.x; t < O_PB * 256; t += TPB) {
    int i = t / O_PB, k = t % O_PB;
    Wl[t] = W[(size_t)(o0 + k) * 256 + i];
  }
  for (int t = threadIdx.x; t < 128; t += TPB) { cw[t] = lncw[t]; cb2[t] = lncb[t]; }
  __syncthreads();
  const int l = blockIdx.x * TPB + threadIdx.x;
  const float* f0 = yf + (size_t)b * HALF * L + l;
  const float* b0 = yb + (size_t)b * HALF * L + (L - 1 - l);
  const float* u0 = yu + (size_t)b * C * L + l;
  float s = 0.f, s2 = 0.f;
#pragma unroll 8
  for (int i = 0; i < 64; ++i) { float v = f0[(size_t)i * L]; s += v; s2 += v * v; }
#pragma unroll 8
  for (int i = 0; i < 64; ++i) { float v = b0[(size_t)i * L]; s += v; s2 += v * v; }
  const float m = s / C;
  const float r = rsqrtf(s2 / C - m * m + 1e-6f);
  if (blockIdx.y == 0) { st2m[b * L + l] = m; st2r[b * L + l] = r; }
  float acc[O_PB];
#pragma unroll
  for (int k = 0; k < O_PB; ++k) acc[k] = bias[o0 + k];
#pragma unroll 4
  for (int i = 0; i < 64; ++i) {
    float cv = (f0[(size_t)i * L] - m) * r * cw[i] + cb2[i];
#pragma unroll
    for (int k = 0; k < O_PB; ++k) acc[k] += Wl[i * O_PB + k] * cv;
  }
#pragma unroll 4
  for (int i = 0; i < 64; ++i) {
    float cv = (b0[(size_t)i * L] - m) * r * cw[64 + i] + cb2[64 + i];
#pragma unroll
    for (int k = 0; k < O_PB; ++k) acc[k] += Wl[(64 + i) * O_PB + k] * cv;
  }
#pragma unroll 4
  for (int i = 0; i < 128; ++i) {
    float xv = u0[(size_t)i * L];
#pragma unroll
    for (int k = 0; k < O_PB; ++k) acc[k] += Wl[(128 + i) * O_PB + k] * xv;
  }
#pragma unroll
  for (int k = 0; k < O_PB; ++k)
    g1[((size_t)b * C + o0 + k) * L + l] = acc[k];
  const int wv = threadIdx.x >> 6, lnn = threadIdx.x & 63;
#pragma unroll
  for (int k = 0; k < O_PB; ++k) {
    float v = acc[k];
    v += __shfl_xor(v, 1);  v += __shfl_xor(v, 2);  v += __shfl_xor(v, 4);
    v += __shfl_xor(v, 8);  v += __shfl_xor(v, 16); v += __shfl_xor(v, 32);
    if (lnn == 0) part[0][k][wv] = v;
    float q = acc[k] * acc[k];
    q += __shfl_xor(q, 1);  q += __shfl_xor(q, 2);  q += __shfl_xor(q, 4);
    q += __shfl_xor(q, 8);  q += __shfl_xor(q, 16); q += __shfl_xor(q, 32);
    if (lnn == 0) part[1][k][wv] = q;
  }
  __syncthreads();
  if (threadIdx.x < 2 * O_PB) {
    int which = threadIdx.x >= O_PB, k = threadIdx.x % O_PB;
    float v = part[which][k][0] + part[which][k][1] + part[which][k][2] + part[which][k][3];
    atomicAdd(&bnsum[which * 128 + o0 + k], v);
  }
}

// ---------- gate2: BN(from sums)+relu on loads; epilogue sigmoid+fuse ----------
template <int O_PB>
__global__ void k_gate2_fuse(const float* __restrict__ g1,
                             const float* __restrict__ bnsum,
                             const float* __restrict__ bn_g, const float* __restrict__ bn_b,
                             const float* __restrict__ W, const float* __restrict__ bias,
                             const float* __restrict__ yu,
                             const float* __restrict__ yf, const float* __restrict__ yb,
                             const float* __restrict__ mean2, const float* __restrict__ rinv2,
                             const float* __restrict__ lncw, const float* __restrict__ lncb,
                             float* __restrict__ fused) {
  __shared__ float Wl[O_PB * 128];
  __shared__ float sc[128], sh[128];
  __shared__ float cwo[O_PB], cbo[O_PB];
  const int o0 = blockIdx.y * O_PB;
  const int b  = blockIdx.z;
  for (int t = threadIdx.x; t < O_PB * 128; t += TPB) {
    int i = t / O_PB, k = t % O_PB;
    Wl[t] = W[(size_t)(o0 + k) * 128 + i];
  }
  for (int t = threadIdx.x; t < 128; t += TPB) {
    float sv = bnsum[t], qv = bnsum[128 + t];
    float mean = sv / (B_SZ * L);
    float var  = qv / (B_SZ * L) - mean * mean;
    float scv = bn_g[t] * rsqrtf(var + 1e-5f);
    sc[t] = scv;
    sh[t] = bn_b[t] - mean * scv;
  }
  if (threadIdx.x < O_PB) {
    cwo[threadIdx.x] = lncw[o0 + threadIdx.x];
    cbo[threadIdx.x] = lncb[o0 + threadIdx.x];
  }
  __syncthreads();
  const int l = blockIdx.x * TPB + threadIdx.x;
  const float m = mean2[b * L + l], r = rinv2[b * L + l];
  const float* Xb = g1 + (size_t)b * C * L + l;
  float acc[O_PB];
#pragma unroll
  for (int k = 0; k < O_PB; ++k) acc[k] = bias[o0 + k];
#pragma unroll 4
  for (int i = 0; i < 128; ++i) {
    float v = fmaxf(Xb[(size_t)i * L] * sc[i] + sh[i], 0.f);
#pragma unroll
    for (int k = 0; k < O_PB; ++k) acc[k] += Wl[i * O_PB + k] * v;
  }
#pragma unroll
  for (int k = 0; k < O_PB; ++k) {
    int o = o0 + k;
    float g = sigm(acc[k]);
    float yuv = yu[((size_t)b * C + o) * L + l];
    float yv = (o < 64) ? yf[((size_t)b * HALF + o) * L + l]
                        : yb[((size_t)b * HALF + (o - 64)) * L + (L - 1 - l)];
    float cv = (yv - m) * r * cwo[k] + cbo[k];
    fused[((size_t)b * C + o) * L + l] = g * yuv + (1.f - g) * cv;
  }
}

// ---------- outproj: 1x1 conv over concat([fused, xr]) ----------
template <int O_PB>
__global__ void k_conv1x1_cat2(const float* __restrict__ X1, const float* __restrict__ X2,
                               const float* __restrict__ W, const float* __restrict__ bias,
                               float* __restrict__ Y, int O) {
  __shared__ float Wl[O_PB * 256];
  const int o0 = blockIdx.y * O_PB;
  const int b  = blockIdx.z;
  for (int t = threadIdx.x; t < O_PB * 256; t += TPB) {
    int i = t / O_PB, k = t % O_PB;
    Wl[t] = W[(size_t)(o0 + k) * 256 + i];
  }
  __syncthreads();
  const int l = blockIdx.x * TPB + threadIdx.x;
  const float* Xb1 = X1 + (size_t)b * C * L + l;
  const float* Xb2 = X2 + (size_t)b * C * L + l;
  float acc[O_PB];
#pragma unroll
  for (int k = 0; k < O_PB; ++k) acc[k] = bias[o0 + k];
#pragma unroll 4
  for (int i = 0; i < 128; ++i) {
    float xv = Xb1[(size_t)i * L];
#pragma unroll
    for (int k = 0; k < O_PB; ++k) acc[k] += Wl[i * O_PB + k] * xv;
  }
#pragma unroll 4
  for (int i = 0; i < 128; ++i) {
    float xv = Xb2[(size_t)i * L];
#pragma unroll
    for (int k = 0; k < O_PB; ++k) acc[k] += Wl[(128 + i) * O_PB + k] * xv;
  }
#pragma unroll
  for (int k = 0; k < O_PB; ++k)
    Y[((size_t)b * O + o0 + k) * L + l] = acc[k];
}

// ---------- final channel LN ----------
__global__ void k_ln_cf(const float* __restrict__ X,
                        const float* __restrict__ w, const float* __restrict__ bchan,
                        float* __restrict__ Y) {
  const int lp = threadIdx.x & 63;
  const int wv = threadIdx.x >> 6;
  const int p  = blockIdx.x * 64 + lp;
  const int b = p / L, l = p % L;
  const float* Xp = X + (size_t)b * C * L + l;
  float s = 0.f, s2 = 0.f;
#pragma unroll 8
  for (int i = 0; i < 32; ++i) {
    float v = Xp[(size_t)(wv * 32 + i) * L];
    s += v; s2 += v * v;
  }
  __shared__ float r1[4][64], r2[4][64];
  r1[wv][lp] = s; r2[wv][lp] = s2;
  __syncthreads();
  float st  = r1[0][lp] + r1[1][lp] + r1[2][lp] + r1[3][lp];
  float s2t = r2[0][lp] + r2[1][lp] + r2[2][lp] + r2[3][lp];
  float mean = st / C;
  float rinv = rsqrtf(s2t / C - mean * mean + 1e-6f);
  float* Yp = Y + (size_t)b * C * L + l;
#pragma unroll 8
  for (int i = 0; i < 32; ++i) {
    int c = wv * 32 + i;
    float v = Xp[(size_t)c * L];
    Yp[(size_t)c * L] = w[c] * (v - mean) * rinv + bchan[c];
  }
}

} // namespace

extern "C" void kernel_launch(void* const* d_in, const int* in_sizes, int n_in,
                              void* d_out, int out_size, void* d_ws, size_t ws_size,
                              hipStream_t stream) {
  const float* x         = (const float*)d_in[0];
  const float* ln_in_w   = (const float*)d_in[1];
  const float* ln_in_b   = (const float*)d_in[2];
  const float* inproj_w  = (const float*)d_in[3];
  const float* inproj_b  = (const float*)d_in[4];
  const float* ln_m_w    = (const float*)d_in[5];
  const float* ln_m_b    = (const float*)d_in[6];
  const float* convm_w   = (const float*)d_in[7];
  const float* convm_b   = (const float*)d_in[8];
  const float* convr_w   = (const float*)d_in[9];
  const float* convr_b   = (const float*)d_in[10];
  const float* ln_cat_w  = (const float*)d_in[11];
  const float* ln_cat_b  = (const float*)d_in[12];
  const float* xpf_w     = (const float*)d_in[13];
  const float* xpf_b     = (const float*)d_in[14];
  const float* dtf_w     = (const float*)d_in[15];
  const float* dtf_b     = (const float*)d_in[16];
  const float* Alog_f    = (const float*)d_in[17];
  const float* D_f       = (const float*)d_in[18];
  const float* xpb_w     = (const float*)d_in[19];
  const float* xpb_b     = (const float*)d_in[20];
  const float* dtb_w     = (const float*)d_in[21];
  const float* dtb_b     = (const float*)d_in[22];
  const float* Alog_b    = (const float*)d_in[23];
  const float* D_b       = (const float*)d_in[24];
  const float* xpu_w     = (const float*)d_in[25];
  const float* xpu_b     = (const float*)d_in[26];
  const float* dtu_w     = (const float*)d_in[27];
  const float* dtu_b     = (const float*)d_in[28];
  const float* Alog_u    = (const float*)d_in[29];
  const float* D_u       = (const float*)d_in[30];
  const float* gate1_w   = (const float*)d_in[31];
  const float* gate1_b   = (const float*)d_in[32];
  const float* bn_g      = (const float*)d_in[33];
  const float* bn_b      = (const float*)d_in[34];
  const float* gate2_w   = (const float*)d_in[35];
  const float* gate2_b   = (const float*)d_in[36];
  const float* outproj_w = (const float*)d_in[37];
  const float* outproj_b = (const float*)d_in[38];
  const float* outln_w   = (const float*)d_in[39];
  const float* outln_b   = (const float*)d_in[40];

  float* ws = (float*)d_ws;
  size_t off = 0;
  auto alloc = [&](size_t n) { float* p = ws + off; off += n; return p; };

  const size_t BL = (size_t)B_SZ * L;
  // zero-initialized region (one memset): st1s, st1q, rank, bnsum — contiguous
  float* st1s  = alloc(BL);
  float* st1q  = alloc(BL);
  int*   rank  = (int*)alloc(BL);
  float* bnsum = alloc(256);
  const size_t zeroBytes = (3 * BL + 256) * sizeof(float);

  float* xp    = alloc((size_t)B_SZ * 2 * C * L);
  float* xm    = alloc((size_t)B_SZ * C * L);
  float* xr    = alloc((size_t)B_SZ * C * L);
  float* unc   = alloc(BL);
  int*   inv   = (int*)alloc(BL);
  int*   idx   = (int*)alloc(BL);
  float* xs    = alloc((size_t)B_SZ * C * L);
  float* xdblF = alloc((size_t)4 * L * 36);
  float* BmTF  = alloc((size_t)4 * L * N);
  float* CmTF  = alloc((size_t)4 * L * N);
  float* xdblU = alloc((size_t)2 * L * 40);
  float* BmTU  = alloc((size_t)2 * L * N);
  float* CmTU  = alloc((size_t)2 * L * N);
  float* yf    = alloc((size_t)B_SZ * HALF * L);
  float* yb    = alloc((size_t)B_SZ * HALF * L);
  float* yu    = alloc((size_t)B_SZ * C * L);
  float* st2m  = alloc(BL);
  float* st2r  = alloc(BL);
  float* g1    = alloc((size_t)B_SZ * C * L);
  float* fused = alloc((size_t)B_SZ * C * L);
  float* outp  = alloc((size_t)B_SZ * C * L);
  (void)ws_size; (void)in_sizes; (void)n_in; (void)out_size;

  const int pixB = B_SZ * L / 64;          // 128 blocks (256 thr)
  const int elemB = B_SZ * C * L / TPB;    // 4096

  // 0) zero the accumulators (st1 sums, rank, bnsum) — one small async fill
  hipMemsetAsync(st1s, 0, zeroBytes, stream);
  // 1) inproj with inline LN + atomic stats of xp[:,:128]
  k_conv_ln<<<dim3(L / (2 * TPB), 32, B_SZ), TPB, 0, stream>>>(
      x, C * L, ln_in_w, ln_in_b, inproj_w, inproj_b, xp, 128, 256, st1s, st1q);
  // 2) tiled dwconv (mamba LN from sums, res plain)
  k_dwconv_t<<<dim3(HH / 4, C, 2 * B_SZ), TPB, 0, stream>>>(
      xp, st1s, st1q, ln_m_w, ln_m_b, convm_w, convm_b, convr_w, convr_b, xm, xr);
  // 3) unc, rank-count, scatter-gather (also emits idx)
  k_unc<<<pixB, TPB, 0, stream>>>(xm, unc);
  k_rank<<<dim3(L / TPB, 8, B_SZ), TPB, 0, stream>>>(unc, rank);
  k_scatgath<<<elemB, TPB, 0, stream>>>(xm, rank, xs, inv, idx);
  // 4) merged scan pipelines (U writes unsorted yu directly)
  k_convx_all<<<dim3(L / TPB, 10, 6), TPB, 0, stream>>>(
      xm, xs, xpf_w, xpf_b, xpb_w, xpb_b, xpu_w, xpu_b, xdblF, xdblU);
  k_bc_all<<<dim3(L / TPB, N, 6), TPB, 0, stream>>>(
      xdblF, xdblU, BmTF, CmTF, BmTU, CmTU);
  k_scan_all<<<512, 1024, 0, stream>>>(
      xdblF, xdblU, dtf_w, dtf_b, dtb_w, dtb_b, dtu_w, dtu_b,
      xm, xs, idx, BmTF, CmTF, BmTU, CmTU,
      Alog_f, Alog_b, Alog_u, D_f, D_b, D_u, yf, yb, yu);
  // 5) epilogue
  k_gate1<8><<<dim3(L / TPB, 16, B_SZ), TPB, 0, stream>>>(
      yf, yb, ln_cat_w, ln_cat_b, yu, gate1_w, gate1_b, g1, st2m, st2r, bnsum);
  k_gate2_fuse<8><<<dim3(L / TPB, 16, B_SZ), TPB, 0, stream>>>(
      g1, bnsum, bn_g, bn_b, gate2_w, gate2_b, yu, yf, yb, st2m, st2r,
      ln_cat_w, ln_cat_b, fused);
  k_conv1x1_cat2<8><<<dim3(L / TPB, 16, B_SZ), TPB, 0, stream>>>(
      fused, xr, outproj_w, outproj_b, outp, 128);
  k_ln_cf<<<pixB, TPB, 0, stream>>>(outp, outln_w, outln_b, (float*)d_out);
}